// Round 15
// baseline (907.187 us; speedup 1.0000x reference)
//
#include <hip/hip_runtime.h>
#include <math.h>

// ---- problem constants (from reference) ----
#define N_   8192
#define E_   131072
#define T_   262144
#define H_   128
#define IND_ 64
#define G_   32
#define L_   2

// generic fp32 GEMM tiling (node_in only)
#define CW 64
#define RB 16

// MFMA fused MLP tiling
#define MROWS 32     // rows per wave
#define HSTRIDE 136  // LDS hidden row stride (bf16 elems)
#define WSTRIDE 36   // LDS weight col stride (bf16 elems) - spreads banks

// RBF constants
#define STEP_E  ((float)(5.0/31.0))
#define GAMMA_E ((float)(1.0/(2.0*((5.0/31.0)*(5.0/31.0) + 1e-12))))
#define PI_D    3.14159265358979323846
#define STEP_A  ((float)(PI_D/15.0))
#define GAMMA_A ((float)(1.0/(2.0*((PI_D/15.0)*(PI_D/15.0) + 1e-12))))

typedef __attribute__((ext_vector_type(8))) short short8;
typedef __attribute__((ext_vector_type(4))) float f32x4;
typedef unsigned short ushort_t;

static __device__ __forceinline__ float silu_f(float x){ return x / (1.f + expf(-x)); }
static __device__ __forceinline__ float sigmoid_f(float x){ return 1.f / (1.f + expf(-x)); }

static __device__ __forceinline__ ushort_t f2bf(float x){
  unsigned int u = __builtin_bit_cast(unsigned int, x);
  u += 0x7FFFu + ((u >> 16) & 1u);
  return (ushort_t)(u >> 16);
}
static __device__ __forceinline__ float bf2f(ushort_t h){
  unsigned int u = ((unsigned int)h) << 16;
  return __builtin_bit_cast(float, u);
}

// ---------------- small utility kernels ----------------

__global__ void k_zero(float* __restrict__ p, long n){
  long stride = (long)gridDim.x*256;
  long n4 = n >> 2;
  float4* p4 = (float4*)p;
  for (long i = (long)blockIdx.x*256 + threadIdx.x; i < n4; i += stride)
    p4[i] = make_float4(0.f,0.f,0.f,0.f);
  for (long i = (n4<<2) + (long)blockIdx.x*256 + threadIdx.x; i < n; i += stride)
    p[i] = 0.f;
}

__global__ void k_sentinel(float* __restrict__ p, int n){
  int i = blockIdx.x*256 + threadIdx.x;
  if (i < n) p[i] = 1.0e30f;
}

__global__ void k_init_vn(float* __restrict__ vn, const float* __restrict__ vn_init){
  int i = blockIdx.x*256 + threadIdx.x;
  if (i < G_*H_) vn[i] = vn_init[i & 127];
}

// batch histogram (bends pre-zeroed), then tiny scan -> segment ENDS
__global__ void k_bhist(const int* __restrict__ batch, int* __restrict__ bh){
  int i = blockIdx.x*256 + threadIdx.x;
  if (i < N_) atomicAdd(&bh[batch[i]], 1);
}
__global__ void k_bscan(int* __restrict__ bh){
  if (threadIdx.x == 0 && blockIdx.x == 0){
    int a = 0;
    for (int g=0; g<G_; g++){ a += bh[g]; bh[g] = a; }
  }
}

// ---- fused weight convert+transpose for ALL weights of one layer ----
__global__ void k_wt_all(const float* __restrict__ tm_w1, const float* __restrict__ tm_w2,
                         const float* __restrict__ mm_w1, const float* __restrict__ mm_w2,
                         const float* __restrict__ us_w1, const float* __restrict__ us_w2,
                         const float* __restrict__ gv_w1, const float* __restrict__ gv_w2,
                         ushort_t* __restrict__ wtbuf){
  const int l = blockIdx.y;
  int i = blockIdx.x*256 + threadIdx.x;
  if (i >= 245760) return;
  ushort_t* base = wtbuf + (size_t)l*376832;
  if (i < 12288){                    // tm1: K=80, C=128, Kpad=96 (hi only)
    int c = i/96, k = i%96;
    base[i] = (k < 80) ? f2bf(tm_w1[(size_t)l*10240 + (size_t)k*128 + c]) : (ushort_t)0;
  } else if (i < 28672){             // tm2: 128x128 (hi only)
    int j = i - 12288; int c = j >> 7, k = j & 127;
    base[12288 + j] = f2bf(tm_w2[(size_t)l*16384 + (size_t)k*128 + c]);
  } else if (i < 81920){             // mm1: K=416, C=128 (hi only)
    int j = i - 28672; int c = j/416, k = j%416;
    base[28672 + j] = f2bf(mm_w1[(size_t)l*53248 + (size_t)k*128 + c]);
  } else if (i < 114688){            // mm2: K=128, C=256 (hi only)
    int j = i - 81920; int c = j >> 7, k = j & 127;
    base[81920 + j] = f2bf(mm_w2[(size_t)l*32768 + (size_t)k*256 + c]);
  } else if (i < 163840){            // us1: K=384, C=128 (hi+lo)
    int j = i - 114688; int c = j/384, k = j%384;
    float w = us_w1[(size_t)l*49152 + (size_t)k*128 + c];
    ushort_t h = f2bf(w);
    base[114688 + j] = h; base[163840 + j] = f2bf(w - bf2f(h));
  } else if (i < 180224){            // us2: 128x128 (hi+lo)
    int j = i - 163840; int c = j >> 7, k = j & 127;
    float w = us_w2[(size_t)l*16384 + (size_t)k*128 + c];
    ushort_t h = f2bf(w);
    base[212992 + j] = h; base[229376 + j] = f2bf(w - bf2f(h));
  } else if (i < 229376){            // gv1: K=384, C=128 (hi+lo)
    int j = i - 180224; int c = j/384, k = j%384;
    float w = gv_w1[(size_t)l*49152 + (size_t)k*128 + c];
    ushort_t h = f2bf(w);
    base[245760 + j] = h; base[294912 + j] = f2bf(w - bf2f(h));
  } else {                           // gv2: 128x128 (hi+lo)
    int j = i - 229376; int c = j >> 7, k = j & 127;
    float w = gv_w2[(size_t)l*16384 + (size_t)k*128 + c];
    ushort_t h = f2bf(w);
    base[344064 + j] = h; base[360448 + j] = f2bf(w - bf2f(h));
  }
}

// per-edge: vec, dir, edge RBF(32) in bf16
__global__ void k_geom(const float* __restrict__ pos, const float* __restrict__ dist,
                       const int* __restrict__ ei,
                       float* __restrict__ vec, float* __restrict__ dir,
                       ushort_t* __restrict__ rbf16){
  int e = blockIdx.x*256 + threadIdx.x;
  if (e >= E_) return;
  int s = ei[e], d = ei[E_ + e];
  float vx = pos[d*3+0] - pos[s*3+0];
  float vy = pos[d*3+1] - pos[s*3+1];
  float vz = pos[d*3+2] - pos[s*3+2];
  vec[e*3+0]=vx; vec[e*3+1]=vy; vec[e*3+2]=vz;
  float dd = dist[e];
  float inv = 1.f / (dd + 1e-9f);
  dir[e*3+0]=vx*inv; dir[e*3+1]=vy*inv; dir[e*3+2]=vz*inv;
  #pragma unroll
  for (int i=0;i<32;i++){
    float df = dd - i*STEP_E;
    rbf16[e*32+i] = f2bf(expf(-GAMMA_E*df*df));
  }
}

// gather dir into sorted-edge order: dir_s[p] = dir[perm_e[p]]
__global__ void k_dirs(const float* __restrict__ dir, const int* __restrict__ perm_e,
                       float* __restrict__ dir_s){
  int p = blockIdx.x*256 + threadIdx.x;
  if (p >= E_) return;
  int e = perm_e[p];
  dir_s[p*3+0] = dir[e*3+0];
  dir_s[p*3+1] = dir[e*3+1];
  dir_s[p*3+2] = dir[e*3+2];
}

// per-triplet angle
__global__ void k_angle(const float* __restrict__ vec,
                        const int* __restrict__ kj, const int* __restrict__ ji,
                        float* __restrict__ angle){
  int t = blockIdx.x*256 + threadIdx.x;
  if (t >= T_) return;
  int ea = ji[t], eb = kj[t];
  float ax=vec[ea*3+0], ay=vec[ea*3+1], az=vec[ea*3+2];
  float bx=vec[eb*3+0], by=vec[eb*3+1], bz=vec[eb*3+2];
  float dot = ax*bx + ay*by + az*bz;
  float na = sqrtf(ax*ax+ay*ay+az*az + 1e-12f);
  float nb = sqrtf(bx*bx+by*by+bz*bz + 1e-12f);
  float c = dot / (na*nb + 1e-9f);
  c = fminf(fmaxf(c, -1.f + 1e-7f), 1.f - 1e-7f);
  angle[t] = acosf(c);
}

// ---------------- counting-sort kernels ----------------

__global__ void k_hist(const int* __restrict__ keys, int M, int* __restrict__ hist){
  int i = blockIdx.x*256 + threadIdx.x;
  if (i < M) atomicAdd(&hist[keys[i]], 1);
}

__global__ void k_hist2(const int* __restrict__ keys, const int* __restrict__ map,
                        int M, int* __restrict__ hist){
  int i = blockIdx.x*256 + threadIdx.x;
  if (i < M) atomicAdd(&hist[map[keys[i]]], 1);
}

__global__ void k_scan1(const int* __restrict__ in, int* __restrict__ out,
                        int* __restrict__ sums, int B){
  __shared__ int sh[1024];
  int base = blockIdx.x*1024, t = threadIdx.x;
  for (int j=t;j<1024;j+=256) sh[j] = (base+j<B) ? in[base+j] : 0;
  __syncthreads();
  for (int o=1;o<1024;o<<=1){
    int v[4];
    #pragma unroll
    for (int q=0;q<4;q++){ int idx=t+q*256; v[q]=(idx>=o)? sh[idx-o]:0; }
    __syncthreads();
    #pragma unroll
    for (int q=0;q<4;q++){ int idx=t+q*256; sh[idx]+=v[q]; }
    __syncthreads();
  }
  for (int j=t;j<1024;j+=256) if (base+j<B) out[base+j] = (j==0)?0:sh[j-1];
  if (t==0) sums[blockIdx.x] = sh[1023];
}

__global__ void k_scan2(int* __restrict__ sums, int nb){
  if (threadIdx.x==0 && blockIdx.x==0){
    int a=0;
    for (int i=0;i<nb;i++){ int x=sums[i]; sums[i]=a; a+=x; }
  }
}

__global__ void k_scan3(int* __restrict__ out, const int* __restrict__ sums, int B){
  int i = blockIdx.x*256+threadIdx.x;
  if (i<B) out[i] += sums[i>>10];
}

__global__ void k_fill(const int* __restrict__ keys, int M, int* __restrict__ cur,
                       int* __restrict__ perm){
  int i = blockIdx.x*256+threadIdx.x;
  if (i<M){ int p = atomicAdd(&cur[keys[i]],1); perm[p]=i; }
}

__global__ void k_fill2(const int* __restrict__ keys, const int* __restrict__ map,
                        int M, int* __restrict__ cur, int* __restrict__ perm){
  int i = blockIdx.x*256+threadIdx.x;
  if (i<M){ int p = atomicAdd(&cur[map[keys[i]]],1); perm[p]=i; }
}

__global__ void k_invert(const int* __restrict__ perm, int* __restrict__ rank, int M){
  int i = blockIdx.x*256+threadIdx.x;
  if (i<M) rank[perm[i]] = i;
}

// ---------------- MFMA first-layer MLP (4-wave block, LDS-shared weights) ----------------
// 256 threads = 4 waves, each wave owns 32 rows (128 rows/block). Per 32-k chunk:
// gathers issued first (overlap staging+barrier), then W1 slice staged in LDS, MFMA.
// LDS UNION: the weight chunk aliases the start of the hid staging region — lw is
// dead after the k-loop's closing barrier; hid is only written after it.
// 34.8 KB total -> 4 blocks/CU.
template<int SM, int K1PAD>
__launch_bounds__(256, 4)
__global__ void k_mlp1(
    const int* __restrict__ perm,
    const int* __restrict__ idx1, const int* __restrict__ idx2,
    const ushort_t* __restrict__ rbf16, const float* __restrict__ angle,
    const ushort_t* __restrict__ s16, const ushort_t* __restrict__ eagg_in,
    const ushort_t* __restrict__ W1t, const float* __restrict__ b1,
    ushort_t* __restrict__ outbuf)
{
  __shared__ ushort_t hid[4*MROWS*HSTRIDE];     // 34816 B (weights alias the front)
  ushort_t* lw = hid;                           // 9216 B weight chunk (dead before hid writes)
  const int tid  = threadIdx.x;
  const int wave = tid >> 6;
  const int lane = tid & 63;
  const int n    = lane & 15;
  const int quad = lane >> 4;
  const int kq   = quad*8;
  const int wrow = blockIdx.x*128 + wave*MROWS;
  ushort_t* myhid = hid + wave*MROWS*HSTRIDE;

  const int e0 = perm[wrow + n];
  const int e1 = perm[wrow + 16 + n];

  int i1a = idx1[e0], i1b = idx1[e1];
  int i2a = idx2[e0], i2b = idx2[e1];
  float ang0 = 0.f, ang1 = 0.f;
  if (SM == 1){ ang0 = angle[e0]; ang1 = angle[e1]; }

  f32x4 acc[2][8];
  #pragma unroll
  for (int rh=0;rh<2;rh++)
    #pragma unroll
    for (int ct=0;ct<8;ct++) acc[rh][ct] = (f32x4){0.f,0.f,0.f,0.f};

  #pragma unroll
  for (int k0 = 0; k0 < K1PAD; k0 += 32){
    // ---- issue this chunk's gather loads FIRST (overlap with staging+barrier) ----
    short8 a0, a1;
    if (SM == 1){
      if (k0 == 0){
        a0 = *(const short8*)&rbf16[(size_t)i1a*32 + kq];
        a1 = *(const short8*)&rbf16[(size_t)i1b*32 + kq];
      } else if (k0 == 32){
        a0 = *(const short8*)&rbf16[(size_t)i2a*32 + kq];
        a1 = *(const short8*)&rbf16[(size_t)i2b*32 + kq];
      } else {
        #pragma unroll
        for (int j=0;j<8;j++){
          int kk = kq + j;
          float v0 = 0.f, v1 = 0.f;
          if (kk < 16){
            float c = (float)kk*STEP_A;
            float d0 = ang0 - c, d1 = ang1 - c;
            v0 = expf(-GAMMA_A*d0*d0); v1 = expf(-GAMMA_A*d1*d1);
          }
          a0[j] = (short)f2bf(v0); a1[j] = (short)f2bf(v1);
        }
      }
    } else {
      const int k = k0 + kq;
      if (k0 < 128){
        a0 = *(const short8*)&s16[(size_t)i1a*128 + k];
        a1 = *(const short8*)&s16[(size_t)i1b*128 + k];
      } else if (k0 < 256){
        a0 = *(const short8*)&s16[(size_t)i2a*128 + (k-128)];
        a1 = *(const short8*)&s16[(size_t)i2b*128 + (k-128)];
      } else if (k0 < 288){
        a0 = *(const short8*)&rbf16[(size_t)e0*32 + (k-256)];
        a1 = *(const short8*)&rbf16[(size_t)e1*32 + (k-256)];
      } else {
        // eagg (post-W2) bf16 in sorted-edge-position order -> sequential rows
        a0 = *(const short8*)&eagg_in[(size_t)(wrow + n)*128 + (k-288)];
        a1 = *(const short8*)&eagg_in[(size_t)(wrow + 16 + n)*128 + (k-288)];
      }
    }

    // ---- cooperative stage of the 128x32 weight slice (hi only) ----
    #pragma unroll
    for (int it=0; it<2; it++){
      int idx = tid + it*256;           // 0..511
      int col = idx >> 2, seg = idx & 3;
      *(short8*)&lw[col*WSTRIDE + seg*8] = *(const short8*)&W1t[(size_t)col*K1PAD + k0 + seg*8];
    }
    __syncthreads();

    #pragma unroll
    for (int ct=0;ct<8;ct++){
      short8 b = *(const short8*)&lw[(ct*16 + n)*WSTRIDE + kq];
      acc[0][ct] = __builtin_amdgcn_mfma_f32_16x16x32_bf16(a0, b, acc[0][ct], 0,0,0);
      acc[1][ct] = __builtin_amdgcn_mfma_f32_16x16x32_bf16(a1, b, acc[1][ct], 0,0,0);
    }
    __syncthreads();
  }

  // bias + silu -> LDS staging (wave-private; lw is dead now), coalesced 16B stores
  #pragma unroll
  for (int rh=0;rh<2;rh++){
    #pragma unroll
    for (int ct=0;ct<8;ct++){
      int col = ct*16 + n;
      float bv = b1[col];
      #pragma unroll
      for (int reg=0;reg<4;reg++){
        int rloc = rh*16 + quad*4 + reg;
        float h = acc[rh][ct][reg] + bv;
        myhid[rloc*HSTRIDE + col] = f2bf(silu_f(h));
      }
    }
  }
  const int rsub = lane >> 4;
  const int c8   = (lane & 15) * 8;
  #pragma unroll
  for (int i=0;i<8;i++){
    int rloc = i*4 + rsub;
    int grow = wrow + rloc;
    short8 vv = *(const short8*)&myhid[(size_t)rloc*HSTRIDE + c8];
    *(short8*)&outbuf[(size_t)grow*128 + c8] = vv;
  }
}

// ---------------- FUSED triplet aggregate + W2 GEMM ----------------
__launch_bounds__(64, 4)
__global__ void k_aggemm_t(const ushort_t* __restrict__ tmsg, const int* __restrict__ tends,
                           const ushort_t* __restrict__ W2t, const float* __restrict__ b2,
                           ushort_t* __restrict__ eagg2){
  __shared__ ushort_t hid[MROWS*HSTRIDE];
  const int lane = threadIdx.x;
  const int n    = lane & 15;
  const int quad = lane >> 4;
  const int kq   = quad*8;
  const int wrow = blockIdx.x*MROWS;
  const int r0 = wrow + n, r1 = wrow + 16 + n;
  const int s0 = r0 ? tends[r0-1] : 0;
  const int e0 = tends[r0];
  const int s1 = tends[r1-1];
  const int e1 = tends[r1];

  f32x4 acc[2][8];
  #pragma unroll
  for (int rh=0;rh<2;rh++)
    #pragma unroll
    for (int ct=0;ct<8;ct++) acc[rh][ct] = (f32x4){0.f,0.f,0.f,0.f};

  #pragma unroll
  for (int k0=0;k0<128;k0+=32){
    float sum0[8], sum1[8];
    #pragma unroll
    for (int j=0;j<8;j++){ sum0[j]=0.f; sum1[j]=0.f; }
    for (int p=s0;p<e0;p++){
      short8 w = *(const short8*)&tmsg[(size_t)p*128 + k0 + kq];
      #pragma unroll
      for (int j=0;j<8;j++) sum0[j] += bf2f((ushort_t)w[j]);
    }
    for (int p=s1;p<e1;p++){
      short8 w = *(const short8*)&tmsg[(size_t)p*128 + k0 + kq];
      #pragma unroll
      for (int j=0;j<8;j++) sum1[j] += bf2f((ushort_t)w[j]);
    }
    short8 a0, a1;
    #pragma unroll
    for (int j=0;j<8;j++){
      a0[j] = (short)f2bf(sum0[j]);
      a1[j] = (short)f2bf(sum1[j]);
    }
    #pragma unroll
    for (int ct=0;ct<8;ct++){
      short8 b = *(const short8*)&W2t[(size_t)(ct*16 + n)*128 + k0 + kq];
      acc[0][ct] = __builtin_amdgcn_mfma_f32_16x16x32_bf16(a0, b, acc[0][ct], 0,0,0);
      acc[1][ct] = __builtin_amdgcn_mfma_f32_16x16x32_bf16(a1, b, acc[1][ct], 0,0,0);
    }
  }

  // per-row segment counts for the bias
  float cnts[2][4];
  #pragma unroll
  for (int rh=0;rh<2;rh++)
    #pragma unroll
    for (int reg=0;reg<4;reg++){
      int row = wrow + rh*16 + quad*4 + reg;
      cnts[rh][reg] = (float)(tends[row] - (row ? tends[row-1] : 0));
    }

  #pragma unroll
  for (int rh=0;rh<2;rh++){
    #pragma unroll
    for (int ct=0;ct<8;ct++){
      int col = ct*16 + n;
      float bv = b2[col];
      #pragma unroll
      for (int reg=0;reg<4;reg++){
        int rloc = rh*16 + quad*4 + reg;
        hid[rloc*HSTRIDE + col] = f2bf(acc[rh][ct][reg] + cnts[rh][reg]*bv);
      }
    }
  }
  const int rsub = lane >> 4;
  const int c8   = (lane & 15) * 8;
  #pragma unroll
  for (int i=0;i<8;i++){
    int rloc = i*4 + rsub;
    int grow = wrow + rloc;
    short8 vv = *(const short8*)&hid[(size_t)rloc*HSTRIDE + c8];
    *(short8*)&eagg2[(size_t)grow*128 + c8] = vv;
  }
}

// edge moment reducer
__global__ void k_agg_e(const ushort_t* __restrict__ hbuf, const int* __restrict__ eends,
                        const float* __restrict__ dir_s, float* __restrict__ mom){
  int i = blockIdx.x*256 + threadIdx.x;
  int d = i >> 6, c2 = (i & 63)*2;
  if (d >= N_) return;
  int s = (d == 0) ? 0 : eends[d-1];
  int e = eends[d];
  float hs0=0.f,hs1=0.f, hx0=0.f,hx1=0.f, hy0=0.f,hy1=0.f, hz0=0.f,hz1=0.f;
  float sdx=0.f, sdy=0.f, sdz=0.f;
  for (int q=s;q<e;q++){
    unsigned int w = *(const unsigned int*)&hbuf[(size_t)q*128 + c2];
    float h0 = bf2f((ushort_t)(w & 0xFFFFu));
    float h1 = bf2f((ushort_t)(w >> 16));
    float dx = dir_s[q*3+0], dy = dir_s[q*3+1], dz = dir_s[q*3+2];
    hs0 += h0; hs1 += h1;
    hx0 += h0*dx; hx1 += h1*dx;
    hy0 += h0*dy; hy1 += h1*dy;
    hz0 += h0*dz; hz1 += h1*dz;
    sdx += dx; sdy += dy; sdz += dz;
  }
  size_t base = (size_t)d*128 + c2;
  *(float2*)&mom[base]                        = make_float2(hs0, hs1);
  *(float2*)&mom[(size_t)N_*128   + base]     = make_float2(hx0, hx1);
  *(float2*)&mom[(size_t)N_*256   + base]     = make_float2(hy0, hy1);
  *(float2*)&mom[(size_t)N_*384   + base]     = make_float2(hz0, hz1);
  if (c2 == 0){
    mom[(size_t)N_*512 + d*4+0] = sdx;
    mom[(size_t)N_*512 + d*4+1] = sdy;
    mom[(size_t)N_*512 + d*4+2] = sdz;
  }
}

// edge: moment GEMM per og = blockIdx.y (0: Ms -> a16 + vn; 1..3: Mx/My/Mz -> aggv plane).
__launch_bounds__(64, 4)
__global__ void k_gemm_e(const float* __restrict__ mom, const int* __restrict__ eends,
                         const ushort_t* __restrict__ W2t /*[256][128]*/,
                         const float* __restrict__ b2 /*[256]*/,
                         const float* __restrict__ v /*[3][N][128]*/,
                         ushort_t* __restrict__ a16h, ushort_t* __restrict__ a16l,
                         ushort_t* __restrict__ vnh,  ushort_t* __restrict__ vnl,
                         float* __restrict__ aggv /*[3][N][128]*/){
  __shared__ float sbuf[MROWS*130];   // 16640 B staging
  const int lane = threadIdx.x;
  const int n    = lane & 15;
  const int quad = lane >> 4;
  const int kq   = quad*8;
  const int wrow = blockIdx.x*MROWS;
  const int og   = blockIdx.y;

  const float* M = mom + (size_t)og*((size_t)N_*128);
  const ushort_t* W = W2t + (og ? (size_t)128*128 : 0);

  f32x4 acc[2][8];
  #pragma unroll
  for (int rh=0;rh<2;rh++)
    #pragma unroll
    for (int ct=0;ct<8;ct++) acc[rh][ct] = (f32x4){0.f,0.f,0.f,0.f};

  #pragma unroll
  for (int k0=0;k0<128;k0+=32){
    const int k = k0 + kq;
    const float* p0 = &M[(size_t)(wrow + n)*128 + k];
    const float* p1 = &M[(size_t)(wrow + 16 + n)*128 + k];
    f32x4 x0 = *(const f32x4*)p0, x1 = *(const f32x4*)(p0+4);
    f32x4 y0 = *(const f32x4*)p1, y1 = *(const f32x4*)(p1+4);
    short8 ah0, al0, ah1, al1;
    #pragma unroll
    for (int j=0;j<4;j++){
      ushort_t h;
      h = f2bf(x0[j]); ah0[j]   = (short)h; al0[j]   = (short)f2bf(x0[j] - bf2f(h));
      h = f2bf(x1[j]); ah0[4+j] = (short)h; al0[4+j] = (short)f2bf(x1[j] - bf2f(h));
      h = f2bf(y0[j]); ah1[j]   = (short)h; al1[j]   = (short)f2bf(y0[j] - bf2f(h));
      h = f2bf(y1[j]); ah1[4+j] = (short)h; al1[4+j] = (short)f2bf(y1[j] - bf2f(h));
    }
    #pragma unroll
    for (int ct=0;ct<8;ct++){
      short8 b = *(const short8*)&W[(size_t)(ct*16 + n)*128 + k0 + kq];
      acc[0][ct] = __builtin_amdgcn_mfma_f32_16x16x32_bf16(ah0, b, acc[0][ct], 0,0,0);
      acc[0][ct] = __builtin_amdgcn_mfma_f32_16x16x32_bf16(al0, b, acc[0][ct], 0,0,0);
      acc[1][ct] = __builtin_amdgcn_mfma_f32_16x16x32_bf16(ah1, b, acc[1][ct], 0,0,0);
      acc[1][ct] = __builtin_amdgcn_mfma_f32_16x16x32_bf16(al1, b, acc[1][ct], 0,0,0);
    }
  }

  const int rsub = lane >> 4;
  const int c8   = (lane & 15) * 8;

  if (og == 0){
    float cnts[2][4];
    #pragma unroll
    for (int rh=0;rh<2;rh++)
      #pragma unroll
      for (int reg=0;reg<4;reg++){
        int row = wrow + rh*16 + quad*4 + reg;
        cnts[rh][reg] = (float)(eends[row] - (row ? eends[row-1] : 0));
      }
    ushort_t* us = (ushort_t*)sbuf;
    // pass 1: hi
    #pragma unroll
    for (int rh=0;rh<2;rh++)
      #pragma unroll
      for (int ct=0;ct<8;ct++){
        int col = ct*16 + n;
        float bv = b2[col];
        #pragma unroll
        for (int reg=0;reg<4;reg++){
          int rloc = rh*16 + quad*4 + reg;
          float val = acc[rh][ct][reg] + cnts[rh][reg]*bv;
          us[rloc*HSTRIDE + col] = f2bf(val);
        }
      }
    #pragma unroll
    for (int i=0;i<8;i++){
      int rloc = i*4 + rsub;
      short8 vv = *(const short8*)&us[(size_t)rloc*HSTRIDE + c8];
      *(short8*)&a16h[(size_t)(wrow + rloc)*128 + c8] = vv;
    }
    // pass 2: lo
    #pragma unroll
    for (int rh=0;rh<2;rh++)
      #pragma unroll
      for (int ct=0;ct<8;ct++){
        int col = ct*16 + n;
        float bv = b2[col];
        #pragma unroll
        for (int reg=0;reg<4;reg++){
          int rloc = rh*16 + quad*4 + reg;
          float val = acc[rh][ct][reg] + cnts[rh][reg]*bv;
          ushort_t h = f2bf(val);
          us[rloc*HSTRIDE + col] = f2bf(val - bf2f(h));
        }
      }
    #pragma unroll
    for (int i=0;i<8;i++){
      int rloc = i*4 + rsub;
      short8 vv = *(const short8*)&us[(size_t)rloc*HSTRIDE + c8];
      *(short8*)&a16l[(size_t)(wrow + rloc)*128 + c8] = vv;
    }
    // vn norms, linear sweep (planar v)
    #pragma unroll 4
    for (int j=0;j<32;j++){
      size_t idx = (size_t)wrow*128 + (size_t)j*128 + lane*2;
      float2 a = *(const float2*)&v[idx];
      float2 b = *(const float2*)&v[(size_t)N_*128 + idx];
      float2 c = *(const float2*)&v[(size_t)N_*256 + idx];
      float n0 = sqrtf(a.x*a.x + b.x*b.x + c.x*c.x + 1e-12f);
      float n1 = sqrtf(a.y*a.y + b.y*b.y + c.y*c.y + 1e-12f);
      ushort_t h0 = f2bf(n0), h1 = f2bf(n1);
      *(unsigned int*)&vnh[idx] = (unsigned int)h0 | ((unsigned int)h1 << 16);
      *(unsigned int*)&vnl[idx] = (unsigned int)f2bf(n0 - bf2f(h0))
                                | ((unsigned int)f2bf(n1 - bf2f(h1)) << 16);
    }
  } else {
    const int x = og - 1;
    #pragma unroll
    for (int rh=0;rh<2;rh++)
      #pragma unroll
      for (int ct=0;ct<8;ct++){
        int col = ct*16 + n;
        float bv = b2[128 + col];
        #pragma unroll
        for (int reg=0;reg<4;reg++){
          int rloc = rh*16 + quad*4 + reg;
          int row = wrow + rloc;
          float sd = mom[(size_t)N_*512 + row*4 + x];
          sbuf[rloc*130 + col] = acc[rh][ct][reg] + sd*bv;
        }
      }
    float* plane = aggv + (size_t)x*((size_t)N_*128);
    #pragma unroll
    for (int i=0;i<8;i++){
      int rloc = i*4 + rsub;
      f32x4 v0 = *(const f32x4*)&sbuf[rloc*130 + c8];
      f32x4 v1 = *(const f32x4*)&sbuf[rloc*130 + c8 + 4];
      *(f32x4*)&plane[(size_t)(wrow + rloc)*128 + c8] = v0;
      *(f32x4*)&plane[(size_t)(wrow + rloc)*128 + c8 + 4] = v1;
    }
  }
}

// ---------------- MFMA node-update kernel (4-wave block, LDS-shared weights) ----------------
__launch_bounds__(256, 3)
__global__ void k_node_mfma(
    const float* __restrict__ s_in,
    const ushort_t* __restrict__ a16h, const ushort_t* __restrict__ a16l,
    const ushort_t* __restrict__ vnh,  const ushort_t* __restrict__ vnl,
    float* __restrict__ s2, float* __restrict__ v_out /*[3][N][128]*/,
    const float* __restrict__ aggv /*[3][N][128]*/,
    const ushort_t* __restrict__ us1h, const ushort_t* __restrict__ us1l, const float* __restrict__ us_b1,
    const ushort_t* __restrict__ us2h, const ushort_t* __restrict__ us2l, const float* __restrict__ us_b2,
    const ushort_t* __restrict__ gv1h, const ushort_t* __restrict__ gv1l, const float* __restrict__ gv_b1,
    const ushort_t* __restrict__ gv2h, const ushort_t* __restrict__ gv2l, const float* __restrict__ gv_b2)
{
  __shared__ ushort_t lwh[128*WSTRIDE];       // 9216 B weight chunk (hi)
  __shared__ ushort_t lwl[128*WSTRIDE];       // 9216 B weight chunk (lo)
  __shared__ ushort_t hidh[4][16*HSTRIDE];    // 17408 B
  __shared__ ushort_t hidl[4][16*HSTRIDE];    // 17408 B  (total 53248 B)
  const int tid  = threadIdx.x;
  const int wave = tid >> 6;
  const int lane = tid & 63;
  const int n    = lane & 15;
  const int quad = lane >> 4;
  const int kq   = quad*8;
  const int og   = blockIdx.y;
  const int wrow = blockIdx.x*64 + wave*16;
  const int r0 = wrow + n;

  const ushort_t* W1h = og ? gv1h : us1h;
  const ushort_t* W1l = og ? gv1l : us1l;
  const float*    B1  = og ? gv_b1 : us_b1;
  const ushort_t* W2h = og ? gv2h : us2h;
  const ushort_t* W2l = og ? gv2l : us2l;
  const float*    B2  = og ? gv_b2 : us_b2;

  // ---------- phase A ----------
  f32x4 acc[8];
  #pragma unroll
  for (int ct=0;ct<8;ct++) acc[ct] = (f32x4){0.f,0.f,0.f,0.f};

  #pragma unroll
  for (int k0=0; k0<384; k0+=32){
    #pragma unroll
    for (int it = 0; it < 2; it++){
      int idx = tid + it*256;          // 0..511
      int col = idx >> 2, seg = idx & 3;
      *(short8*)&lwh[col*WSTRIDE + seg*8] = *(const short8*)&W1h[(size_t)col*384 + k0 + seg*8];
      *(short8*)&lwl[col*WSTRIDE + seg*8] = *(const short8*)&W1l[(size_t)col*384 + k0 + seg*8];
    }
    __syncthreads();

    short8 ah0, al0;
    const int k = k0 + kq;
    if (k0 < 128){
      const float* p0 = &s_in[(size_t)r0*128 + k];
      f32x4 x0 = *(const f32x4*)p0, x1 = *(const f32x4*)(p0+4);
      #pragma unroll
      for (int j=0;j<4;j++){
        ushort_t h;
        h = f2bf(x0[j]); ah0[j]   = (short)h; al0[j]   = (short)f2bf(x0[j] - bf2f(h));
        h = f2bf(x1[j]); ah0[4+j] = (short)h; al0[4+j] = (short)f2bf(x1[j] - bf2f(h));
      }
    } else if (k0 < 256){
      int kk = k - 128;
      ah0 = *(const short8*)&a16h[(size_t)r0*128 + kk];
      al0 = *(const short8*)&a16l[(size_t)r0*128 + kk];
    } else {
      int kk = k - 256;
      ah0 = *(const short8*)&vnh[(size_t)r0*128 + kk];
      al0 = *(const short8*)&vnl[(size_t)r0*128 + kk];
    }
    #pragma unroll
    for (int ct=0;ct<8;ct++){
      short8 bh = *(const short8*)&lwh[(ct*16 + n)*WSTRIDE + kq];
      short8 bl = *(const short8*)&lwl[(ct*16 + n)*WSTRIDE + kq];
      acc[ct] = __builtin_amdgcn_mfma_f32_16x16x32_bf16(ah0, bh, acc[ct], 0,0,0);
      acc[ct] = __builtin_amdgcn_mfma_f32_16x16x32_bf16(al0, bh, acc[ct], 0,0,0);
      acc[ct] = __builtin_amdgcn_mfma_f32_16x16x32_bf16(ah0, bl, acc[ct], 0,0,0);
    }
    __syncthreads();
  }

  #pragma unroll
  for (int ct=0;ct<8;ct++){
    int col = ct*16 + n;
    float bv = B1[col];
    #pragma unroll
    for (int reg=0;reg<4;reg++){
      int rloc = quad*4 + reg;
      float h = silu_f(acc[ct][reg] + bv);
      ushort_t hh = f2bf(h);
      hidh[wave][rloc*HSTRIDE + col] = hh;
      hidl[wave][rloc*HSTRIDE + col] = f2bf(h - bf2f(hh));
    }
  }

  // ---------- phase B ----------
  f32x4 acc2[8];
  #pragma unroll
  for (int ct=0;ct<8;ct++) acc2[ct] = (f32x4){0.f,0.f,0.f,0.f};

  #pragma unroll
  for (int k0=0;k0<128;k0+=32){
    #pragma unroll
    for (int it = 0; it < 2; it++){
      int idx = tid + it*256;
      int col = idx >> 2, seg = idx & 3;
      *(short8*)&lwh[col*WSTRIDE + seg*8] = *(const short8*)&W2h[(size_t)col*128 + k0 + seg*8];
      *(short8*)&lwl[col*WSTRIDE + seg*8] = *(const short8*)&W2l[(size_t)col*128 + k0 + seg*8];
    }
    __syncthreads();

    short8 ah0 = *(const short8*)&hidh[wave][(size_t)(n)*HSTRIDE + k0 + kq];
    short8 al0 = *(const short8*)&hidl[wave][(size_t)(n)*HSTRIDE + k0 + kq];
    #pragma unroll
    for (int ct=0;ct<8;ct++){
      short8 bh = *(const short8*)&lwh[(ct*16 + n)*WSTRIDE + kq];
      short8 bl = *(const short8*)&lwl[(ct*16 + n)*WSTRIDE + kq];
      acc2[ct] = __builtin_amdgcn_mfma_f32_16x16x32_bf16(ah0, bh, acc2[ct], 0,0,0);
      acc2[ct] = __builtin_amdgcn_mfma_f32_16x16x32_bf16(al0, bh, acc2[ct], 0,0,0);
      acc2[ct] = __builtin_amdgcn_mfma_f32_16x16x32_bf16(ah0, bl, acc2[ct], 0,0,0);
    }
    __syncthreads();
  }

  if (og == 0){
    #pragma unroll
    for (int ct=0;ct<8;ct++){
      int col = ct*16 + n;
      float bv = B2[col];
      #pragma unroll
      for (int reg=0;reg<4;reg++){
        int row = wrow + quad*4 + reg;
        size_t idx = (size_t)row*128 + col;
        s2[idx] = s_in[idx] + acc2[ct][reg] + bv;
      }
    }
  } else {
    #pragma unroll
    for (int ct=0;ct<8;ct++){
      int col = ct*16 + n;
      float bv = B2[col];
      #pragma unroll
      for (int reg=0;reg<4;reg++){
        int row = wrow + quad*4 + reg;
        size_t idx = (size_t)row*128 + col;
        float g = sigmoid_f(acc2[ct][reg] + bv);
        v_out[idx]                    += g*aggv[idx];
        v_out[(size_t)N_*128 + idx]   += g*aggv[(size_t)N_*128 + idx];
        v_out[(size_t)N_*256 + idx]   += g*aggv[(size_t)N_*256 + idx];
      }
    }
  }
}

// ---------------- generic fp32 row-MLP GEMM (node_in only) ----------------
__launch_bounds__(128)
__global__ void k_gemm(const float* __restrict__ A,
                       const float* __restrict__ W,
                       const float* __restrict__ bias,
                       float* __restrict__ C, int R, int K)
{
  __shared__ float ws[CW*128];
  __shared__ float as[RB][CW];
  const int tid = threadIdx.x;
  const int nchunk = (K + CW - 1) / CW;

  for (int rb = blockIdx.x*RB; rb < R; rb += gridDim.x*RB){
    float acc[RB];
    #pragma unroll
    for (int r=0;r<RB;r++) acc[r] = 0.f;

    for (int c=0;c<nchunk;c++){
      const int k0 = c*CW;
      for (int i=tid; i<CW*128; i+=128){
        int kk = i >> 7, col = i & 127;
        int k = k0 + kk;
        ws[i] = (k < K) ? W[k*128 + col] : 0.f;
      }
      for (int i=tid; i<RB*CW; i+=128){
        int r  = i >> 6, kk = i & 63;
        int k  = k0 + kk;
        as[r][kk] = (k < K) ? A[(long)(rb+r)*K + k] : 0.f;
      }
      __syncthreads();
      #pragma unroll 4
      for (int kq2=0; kq2<CW/4; kq2++){
        float w0 = ws[(4*kq2+0)*128 + tid];
        float w1 = ws[(4*kq2+1)*128 + tid];
        float w2 = ws[(4*kq2+2)*128 + tid];
        float w3 = ws[(4*kq2+3)*128 + tid];
        #pragma unroll
        for (int r=0;r<RB;r++){
          const float4 av = *reinterpret_cast<const float4*>(&as[r][4*kq2]);
          acc[r] = fmaf(av.x, w0, acc[r]);
          acc[r] = fmaf(av.y, w1, acc[r]);
          acc[r] = fmaf(av.z, w2, acc[r]);
          acc[r] = fmaf(av.w, w3, acc[r]);
        }
      }
      __syncthreads();
    }

    const float bv = bias[tid];
    #pragma unroll
    for (int r=0;r<RB;r++)
      C[(long)(rb+r)*128 + tid] = acc[r] + bv;
  }
}

// ---------------- small fused kernels ----------------

// G x 128 2-layer MLP, row-parallel: grid 8 blocks x 4 rows each.
__launch_bounds__(256)
__global__ void k_small_mlp2(const float* __restrict__ in,
                             const float* __restrict__ w1, const float* __restrict__ b1,
                             const float* __restrict__ w2, const float* __restrict__ b2,
                             float* __restrict__ outp, int accumulate){
  __shared__ float a[4][128];
  __shared__ float h[4][128];
  int tid = threadIdx.x;
  int rbase = blockIdx.x*4;
  for (int i=tid;i<4*128;i+=256) a[i>>7][i&127] = in[(rbase + (i>>7))*128 + (i&127)];
  __syncthreads();
  int col = tid & 127, rg = tid >> 7;   // rg 0..1 -> rows rg*2, rg*2+1
  float acc0=0.f, acc1=0.f;
  for (int k=0;k<128;k++){
    float w = w1[k*128+col];
    acc0 = fmaf(a[rg*2+0][k], w, acc0);
    acc1 = fmaf(a[rg*2+1][k], w, acc1);
  }
  {
    float bv = b1[col];
    h[rg*2+0][col] = silu_f(acc0+bv);
    h[rg*2+1][col] = silu_f(acc1+bv);
  }
  __syncthreads();
  acc0=0.f; acc1=0.f;
  for (int k=0;k<128;k++){
    float w = w2[k*128+col];
    acc0 = fmaf(h[rg*2+0][k], w, acc0);
    acc1 = fmaf(h[rg*2+1][k], w, acc1);
  }
  {
    float bv = b2[col];
    int idx0 = (rbase+rg*2+0)*128+col;
    int idx1 = (rbase+rg*2+1)*128+col;
    float v0 = acc0+bv, v1 = acc1+bv;
    outp[idx0] = accumulate ? outp[idx0]+v0 : v0;
    outp[idx1] = accumulate ? outp[idx1]+v1 : v1;
  }
}

__global__ void k_head(const float* __restrict__ gbuf,
                       const float* __restrict__ w1, const float* __restrict__ b1,
                       const float* __restrict__ w2, const float* __restrict__ b2,
                       float* __restrict__ outp){
  __shared__ float red[128];
  int g = blockIdx.x, tid = threadIdx.x;
  float acc = 0.f;
  for (int k=0;k<640;k++) acc = fmaf(gbuf[g*640+k], w1[k*128+tid], acc);
  float h = silu_f(acc + b1[tid]);
  red[tid] = h * w2[tid];
  __syncthreads();
  for (int o=64;o>0;o>>=1){ if (tid<o) red[tid]+=red[tid+o]; __syncthreads(); }
  if (tid == 0) outp[g] = red[0] + b2[0];
}

// ---------------- elementwise / reduction kernels ----------------

__global__ void k_sadd_batch(float* __restrict__ s, const float* __restrict__ t2,
                             const int* __restrict__ batch, ushort_t* __restrict__ s16){
  int i = blockIdx.x*256 + threadIdx.x;
  if (i >= N_*H_) return;
  int n = i >> 7, h = i & 127;
  float v = s[i] + t2[batch[n]*128 + h];
  s[i] = v;
  s16[i] = f2bf(v);
}

// LN + silu (no atomics)
__global__ void k_ln_silu(const float* __restrict__ in, float* __restrict__ outp,
                          const float* __restrict__ g, const float* __restrict__ b){
  __shared__ float red[128];
  int n = blockIdx.x, tid = threadIdx.x;
  float x = in[n*128 + tid];
  red[tid] = x; __syncthreads();
  for (int o=64;o>0;o>>=1){ if (tid<o) red[tid]+=red[tid+o]; __syncthreads(); }
  float mu = red[0] * (1.f/128.f);
  __syncthreads();
  float dx = x - mu;
  red[tid] = dx*dx; __syncthreads();
  for (int o=64;o>0;o>>=1){ if (tid<o) red[tid]+=red[tid+o]; __syncthreads(); }
  float var = red[0] * (1.f/128.f);
  float y = dx * rsqrtf(var + 1e-5f) * g[tid] + b[tid];
  outp[n*128 + tid] = silu_f(y);
}

// batch CSR segment-sum of s into ssum (ssum pre-zeroed)
__global__ void k_ssum_csr(const float* __restrict__ s, const int* __restrict__ bends,
                           float* __restrict__ ssum){
  int g = blockIdx.x, c = blockIdx.y, tid = threadIdx.x;
  int s0 = g ? bends[g-1] : 0;
  int e0 = bends[g];
  long len = e0 - s0;
  int lo = s0 + (int)((len*c) >> 3);
  int hi = s0 + (int)((len*(c+1)) >> 3);
  float a = 0.f;
  for (int n=lo; n<hi; n++) a += s[(size_t)n*128 + tid];
  if (hi > lo) atomicAdd(&ssum[g*128 + tid], a);
}

// readout scatter: per-block segmented accumulation over 32 sorted nodes
__global__ void k_scatter_nf2(const float* __restrict__ s, const float* __restrict__ v /*[3][N][128]*/,
                              const int* __restrict__ batch, float* __restrict__ addp){
  int j = threadIdx.x;            // 0..255 (col in the 256-wide nf row)
  int base = blockIdx.x*32;
  float acc = 0.f;
  int prev = batch[base];
  for (int r=0;r<32;r++){
    int nn = base + r;
    int b = batch[nn];
    if (b != prev){ atomicAdd(&addp[prev*256 + j], acc); acc = 0.f; prev = b; }
    float val;
    if (j < 128){
      val = s[(size_t)nn*128 + j];
    } else {
      size_t idx = (size_t)nn*128 + (j - 128);
      float v0 = v[idx], v1 = v[(size_t)N_*128 + idx], v2 = v[(size_t)N_*256 + idx];
      val = sqrtf(v0*v0 + v1*v1 + v2*v2 + 1e-12f);
    }
    acc += val;
  }
  atomicAdd(&addp[prev*256 + j], acc);
}

// counts derived from bends (no atomics)
__global__ void k_build_g(const float* __restrict__ addp, const int* __restrict__ bends,
                          const float* __restrict__ vn, float* __restrict__ gbuf){
  int i = blockIdx.x*256 + threadIdx.x;
  if (i >= G_*640) return;
  int g = i / 640, j = i % 640;
  float cnt = (float)(bends[g] - (g ? bends[g-1] : 0));
  float val;
  if (j < 256)       val = addp[g*256 + j];
  else if (j < 512)  val = addp[g*256 + (j-256)] / fmaxf(cnt, 1.f);
  else               val = vn[g*128 + (j-512)];
  gbuf[i] = val;
}

// ---------------- host launcher ----------------

extern "C" void kernel_launch(void* const* d_in, const int* in_sizes, int n_in,
                              void* d_out, int out_size, void* d_ws, size_t ws_size,
                              hipStream_t stream)
{
  const float* x         = (const float*)d_in[0];
  const float* pos       = (const float*)d_in[1];
  const float* edist     = (const float*)d_in[2];
  const float* node_in_w = (const float*)d_in[3];
  const float* node_in_b = (const float*)d_in[4];
  const float* tm_w1 = (const float*)d_in[5];
  const float* tm_b1 = (const float*)d_in[6];
  const float* tm_w2 = (const float*)d_in[7];
  const float* tm_b2 = (const float*)d_in[8];
  const float* mm_w1 = (const float*)d_in[9];
  const float* mm_b1 = (const float*)d_in[10];
  const float* mm_w2 = (const float*)d_in[11];
  const float* mm_b2 = (const float*)d_in[12];
  const float* us_w1 = (const float*)d_in[13];
  const float* us_b1 = (const float*)d_in[14];
  const float* us_w2 = (const float*)d_in[15];
  const float* us_b2 = (const float*)d_in[16];
  const float* gv_w1 = (const float*)d_in[17];
  const float* gv_b1 = (const float*)d_in[18];
  const float* gv_w2 = (const float*)d_in[19];
  const float* gv_b2 = (const float*)d_in[20];
  const float* ln_g  = (const float*)d_in[21];
  const float* ln_b  = (const float*)d_in[22];
  const float* vn_init = (const float*)d_in[23];
  const float* v2n_w1 = (const float*)d_in[24];
  const float* v2n_b1 = (const float*)d_in[25];
  const float* v2n_w2 = (const float*)d_in[26];
  const float* v2n_b2 = (const float*)d_in[27];
  const float* n2v_w1 = (const float*)d_in[28];
  const float* n2v_b1 = (const float*)d_in[29];
  const float* n2v_w2 = (const float*)d_in[30];
  const float* n2v_b2 = (const float*)d_in[31];
  const float* head_w1 = (const float*)d_in[32];
  const float* head_b1 = (const float*)d_in[33];
  const float* head_w2 = (const float*)d_in[34];
  const float* head_b2 = (const float*)d_in[35];
  const int* ei    = (const int*)d_in[36];
  const int* t_kj  = (const int*)d_in[37];
  const int* t_ji  = (const int*)d_in[38];
  const int* batch = (const int*)d_in[39];
  float* out = (float*)d_out;

  // ---- workspace layout (~150 MiB) ----
  float* f = (float*)d_ws;
  size_t off = 0;
  auto alloc = [&](size_t n){ n = (n + 3) & ~(size_t)3; float* p = f + off; off += n; return p; };
  float*    vec    = alloc((size_t)E_*3);    // aliased: perm_t + perm_e after k_angle
  float*    dir    = alloc((size_t)E_*3);
  ushort_t* rbf16  = (ushort_t*)alloc((size_t)E_*16);
  float*    angle  = alloc((size_t)T_);
  float*    tmsg_f = alloc((size_t)E_*128);  // triplet hidden T*128 bf16 / edge hidden E*128 bf16
  float*    eagg2_f= alloc((size_t)E_*64);   // eagg bf16 (E*128); later: moments + node scratch
  float*    dir_s  = alloc((size_t)E_*3);    // sorted dir
  float*    tends_f= alloc((size_t)E_ + 1024); // triplet CSR ends (E ints) + scan sums
  float*    eends_f= alloc((size_t)N_ + 1024); // edge CSR ends (N ints) + scan sums
  float*    bends_f= alloc((size_t)G_);      // batch CSR ends (G ints)
  float*    s      = alloc((size_t)N_*128);
  ushort_t* s16    = (ushort_t*)alloc((size_t)N_*64);
  float*    v      = alloc((size_t)N_*384);  // PLANAR [3][N][128]
  float*    aggv   = alloc((size_t)N_*384);  // PLANAR [3][N][128]
  float*    rank_f = alloc((size_t)E_);      // rank_e (E ints)
  float*    wtbuf_f= alloc((size_t)376832);  // bf16 transposed weights (hi + node-lo)
  float*    vn     = alloc((size_t)G_*128);
  float*    tg2    = alloc((size_t)G_*128);
  float*    ssum   = alloc((size_t)G_*128);
  float*    addp   = alloc((size_t)G_*256);
  float*    gbuf   = alloc((size_t)G_*640);

  if (off * sizeof(float) > ws_size){
    k_sentinel<<<1, 64, 0, stream>>>(out, G_);
    return;
  }

  // aliases
  int* perm_t = (int*)vec;
  int* perm_e = perm_t + T_;
  int* rank_e = (int*)rank_f;
  int* tends  = (int*)tends_f;
  int* eends  = (int*)eends_f;
  int* bends  = (int*)bends_f;
  ushort_t* tmsg   = (ushort_t*)tmsg_f;   // T*128 bf16 (triplet hidden)
  ushort_t* ehid   = (ushort_t*)tmsg_f;   // E*128 bf16 (edge hidden; tmsg dead by then)
  ushort_t* eagg2  = (ushort_t*)eagg2_f;  // E*128 bf16
  // edge moments + node scratch inside eagg2_f (eagg2 dead after edge MLP reads it)
  float*    mom  = eagg2_f;                              // [4][N][128] fp32 + sumdir [N][4]
  ushort_t* a16h = (ushort_t*)(eagg2_f + 4227072);       // 4*N*128 + 4*N region
  ushort_t* a16l = a16h + (size_t)N_*128;
  ushort_t* vnh  = a16l + (size_t)N_*128;
  ushort_t* vnl  = vnh  + (size_t)N_*128;
  float*    s2   = (float*)(vnl + (size_t)N_*128);       // N*128 fp32

  ushort_t* wtbuf = (ushort_t*)wtbuf_f;
  auto WT = [&](int l, size_t o){ return wtbuf + (size_t)l*376832 + o; };

  auto zero = [&](float* p, long n){
    int blocks = (int)((n/4 + 255)/256); if (blocks > 16384) blocks = 16384; if (blocks < 1) blocks = 1;
    k_zero<<<blocks, 256, 0, stream>>>(p, n);
  };
  auto csort = [&](const int* keys, const int* map, int M, int B, int* perm, int* ends){
    int nb = (B+1023)/1024;
    zero((float*)ends, B + nb);
    if (map) k_hist2<<<(M+255)/256, 256, 0, stream>>>(keys, map, M, ends);
    else     k_hist <<<(M+255)/256, 256, 0, stream>>>(keys, M, ends);
    k_scan1<<<nb, 256, 0, stream>>>(ends, ends, ends + B, B);
    k_scan2<<<1, 64, 0, stream>>>(ends + B, nb);
    k_scan3<<<(B+255)/256, 256, 0, stream>>>(ends, ends + B, B);
    if (map) k_fill2<<<(M+255)/256, 256, 0, stream>>>(keys, map, M, ends, perm);
    else     k_fill <<<(M+255)/256, 256, 0, stream>>>(keys, M, ends, perm);
    // post-fill: ends[b] == segment end offset for bin b
  };

  // ---- prologue ----
  zero(v, (long)N_*384);
  k_init_vn<<<(G_*H_ + 255)/256, 256, 0, stream>>>(vn, vn_init);
  k_geom<<<(E_ + 255)/256, 256, 0, stream>>>(pos, edist, ei, vec, dir, rbf16);
  k_angle<<<(T_ + 255)/256, 256, 0, stream>>>(vec, t_kj, t_ji, angle);
  csort(ei+E_, nullptr, E_, N_, perm_e, eends);
  k_invert<<<(E_+255)/256, 256, 0, stream>>>(perm_e, rank_e, E_);
  k_dirs<<<(E_+255)/256, 256, 0, stream>>>(dir, perm_e, dir_s);
  csort(t_ji, rank_e, T_, E_, perm_t, tends);
  // batch CSR ends
  zero(bends_f, G_);
  k_bhist<<<(N_+255)/256, 256, 0, stream>>>(batch, bends);
  k_bscan<<<1, 64, 0, stream>>>(bends);
  k_wt_all<<<dim3(960, 2), 256, 0, stream>>>(tm_w1, tm_w2, mm_w1, mm_w2,
                                             us_w1, us_w2, gv_w1, gv_w2, wtbuf);
  k_gemm<<<512, 128, 0, stream>>>(x, node_in_w, node_in_b, s, N_, IND_);

  for (int l=0; l<L_; l++){
    // 1) s += v2n_mlp(vn)[batch]  (snapshots s16)
    k_small_mlp2<<<8, 256, 0, stream>>>(vn, v2n_w1, v2n_b1, v2n_w2, v2n_b2, tg2, 0);
    k_sadd_batch<<<(N_*H_ + 255)/256, 256, 0, stream>>>(s, tg2, batch, s16);

    // 2) triplet: hidden MLP (4-wave, LDS-union weights) -> tmsg; fused CSR+W2 -> eagg2
    k_mlp1<1,96><<<T_/128, 256, 0, stream>>>(perm_t, t_kj, t_ji,
        rbf16, angle, s16, eagg2, WT(l,0), tm_b1 + l*128, tmsg);
    k_aggemm_t<<<E_/MROWS, 64, 0, stream>>>(tmsg, tends, WT(l,12288), tm_b2 + l*128, eagg2);

    // 3) edge: hidden MLP (4-wave, LDS-union weights) -> ehid; moment reduce; W2 GEMMs
    k_mlp1<2,416><<<E_/128, 256, 0, stream>>>(perm_e, ei, ei + E_,
        rbf16, angle, s16, eagg2, WT(l,28672), mm_b1 + l*128, ehid);
    k_agg_e<<<(N_*64)/256, 256, 0, stream>>>(ehid, eends, dir_s, mom);
    k_gemm_e<<<dim3(N_/MROWS, 4), 64, 0, stream>>>(mom, eends, WT(l,81920), mm_b2 + l*256,
        v, a16h, a16l, vnh, vnl, aggv);

    // 5+6) node update (4-wave blocks, LDS-shared weights): s2 = s + us_mlp; gated v update
    k_node_mfma<<<dim3(N_/64, 2), 256, 0, stream>>>(s, a16h, a16l, vnh, vnl, s2, v, aggv,
        WT(l,114688), WT(l,163840), us_b1 + l*128, WT(l,212992), WT(l,229376), us_b2 + l*128,
        WT(l,245760), WT(l,294912), gv_b1 + l*128, WT(l,344064), WT(l,360448), gv_b2 + l*128);

    // 7) s = silu(LN(s2)); 8) vn += n2v_mlp(batch-CSR segment sum of s)
    k_ln_silu<<<N_, 128, 0, stream>>>(s2, s, ln_g + l*128, ln_b + l*128);
    zero(ssum, (long)G_*128);
    k_ssum_csr<<<dim3(G_, 8), 128, 0, stream>>>(s, bends, ssum);
    k_small_mlp2<<<8, 256, 0, stream>>>(ssum, n2v_w1, n2v_b1, n2v_w2, n2v_b2, vn, 1);
  }

  // ---- readout ----
  zero(addp, (long)G_*256);
  k_scatter_nf2<<<N_/32, 256, 0, stream>>>(s, v, batch, addp);
  k_build_g<<<(G_*640 + 255)/256, 256, 0, stream>>>(addp, bends, vn, gbuf);
  k_head<<<G_, 128, 0, stream>>>(gbuf, head_w1, head_b1, head_w2, head_b2, out);
}

// Round 16
// 807.039 us; speedup vs baseline: 1.1241x; 1.1241x over previous
//
#include <hip/hip_runtime.h>
#include <math.h>

// ---- problem constants (from reference) ----
#define N_   8192
#define E_   131072
#define T_   262144
#define H_   128
#define IND_ 64
#define G_   32
#define L_   2

// generic fp32 GEMM tiling (node_in only)
#define CW 64
#define RB 16

// MFMA fused MLP tiling
#define MROWS 32     // rows per wave (reducer/GEMM kernels)
#define HSTRIDE 136  // LDS hidden row stride (bf16 elems)
#define WSTRIDE 36   // LDS weight col stride (bf16 elems) - spreads banks

// RBF constants
#define STEP_E  ((float)(5.0/31.0))
#define GAMMA_E ((float)(1.0/(2.0*((5.0/31.0)*(5.0/31.0) + 1e-12))))
#define PI_D    3.14159265358979323846
#define STEP_A  ((float)(PI_D/15.0))
#define GAMMA_A ((float)(1.0/(2.0*((PI_D/15.0)*(PI_D/15.0) + 1e-12))))

typedef __attribute__((ext_vector_type(8))) short short8;
typedef __attribute__((ext_vector_type(4))) float f32x4;
typedef unsigned short ushort_t;

static __device__ __forceinline__ float silu_f(float x){ return x / (1.f + expf(-x)); }
static __device__ __forceinline__ float sigmoid_f(float x){ return 1.f / (1.f + expf(-x)); }

static __device__ __forceinline__ ushort_t f2bf(float x){
  unsigned int u = __builtin_bit_cast(unsigned int, x);
  u += 0x7FFFu + ((u >> 16) & 1u);
  return (ushort_t)(u >> 16);
}
static __device__ __forceinline__ float bf2f(ushort_t h){
  unsigned int u = ((unsigned int)h) << 16;
  return __builtin_bit_cast(float, u);
}

// ---------------- small utility kernels ----------------

__global__ void k_zero(float* __restrict__ p, long n){
  long stride = (long)gridDim.x*256;
  long n4 = n >> 2;
  float4* p4 = (float4*)p;
  for (long i = (long)blockIdx.x*256 + threadIdx.x; i < n4; i += stride)
    p4[i] = make_float4(0.f,0.f,0.f,0.f);
  for (long i = (n4<<2) + (long)blockIdx.x*256 + threadIdx.x; i < n; i += stride)
    p[i] = 0.f;
}

__global__ void k_sentinel(float* __restrict__ p, int n){
  int i = blockIdx.x*256 + threadIdx.x;
  if (i < n) p[i] = 1.0e30f;
}

__global__ void k_init_vn(float* __restrict__ vn, const float* __restrict__ vn_init){
  int i = blockIdx.x*256 + threadIdx.x;
  if (i < G_*H_) vn[i] = vn_init[i & 127];
}

// batch histogram (bends pre-zeroed), then tiny scan -> segment ENDS
__global__ void k_bhist(const int* __restrict__ batch, int* __restrict__ bh){
  int i = blockIdx.x*256 + threadIdx.x;
  if (i < N_) atomicAdd(&bh[batch[i]], 1);
}
__global__ void k_bscan(int* __restrict__ bh){
  if (threadIdx.x == 0 && blockIdx.x == 0){
    int a = 0;
    for (int g=0; g<G_; g++){ a += bh[g]; bh[g] = a; }
  }
}

// ---- fused weight convert+transpose for ALL weights of one layer ----
__global__ void k_wt_all(const float* __restrict__ tm_w1, const float* __restrict__ tm_w2,
                         const float* __restrict__ mm_w1, const float* __restrict__ mm_w2,
                         const float* __restrict__ us_w1, const float* __restrict__ us_w2,
                         const float* __restrict__ gv_w1, const float* __restrict__ gv_w2,
                         ushort_t* __restrict__ wtbuf){
  const int l = blockIdx.y;
  int i = blockIdx.x*256 + threadIdx.x;
  if (i >= 245760) return;
  ushort_t* base = wtbuf + (size_t)l*376832;
  if (i < 12288){                    // tm1: K=80, C=128, Kpad=96 (hi only)
    int c = i/96, k = i%96;
    base[i] = (k < 80) ? f2bf(tm_w1[(size_t)l*10240 + (size_t)k*128 + c]) : (ushort_t)0;
  } else if (i < 28672){             // tm2: 128x128 (hi only)
    int j = i - 12288; int c = j >> 7, k = j & 127;
    base[12288 + j] = f2bf(tm_w2[(size_t)l*16384 + (size_t)k*128 + c]);
  } else if (i < 81920){             // mm1: K=416, C=128 (hi only)
    int j = i - 28672; int c = j/416, k = j%416;
    base[28672 + j] = f2bf(mm_w1[(size_t)l*53248 + (size_t)k*128 + c]);
  } else if (i < 114688){            // mm2: K=128, C=256 (hi only)
    int j = i - 81920; int c = j >> 7, k = j & 127;
    base[81920 + j] = f2bf(mm_w2[(size_t)l*32768 + (size_t)k*256 + c]);
  } else if (i < 163840){            // us1: K=384, C=128 (hi+lo)
    int j = i - 114688; int c = j/384, k = j%384;
    float w = us_w1[(size_t)l*49152 + (size_t)k*128 + c];
    ushort_t h = f2bf(w);
    base[114688 + j] = h; base[163840 + j] = f2bf(w - bf2f(h));
  } else if (i < 180224){            // us2: 128x128 (hi+lo)
    int j = i - 163840; int c = j >> 7, k = j & 127;
    float w = us_w2[(size_t)l*16384 + (size_t)k*128 + c];
    ushort_t h = f2bf(w);
    base[212992 + j] = h; base[229376 + j] = f2bf(w - bf2f(h));
  } else if (i < 229376){            // gv1: K=384, C=128 (hi+lo)
    int j = i - 180224; int c = j/384, k = j%384;
    float w = gv_w1[(size_t)l*49152 + (size_t)k*128 + c];
    ushort_t h = f2bf(w);
    base[245760 + j] = h; base[294912 + j] = f2bf(w - bf2f(h));
  } else {                           // gv2: 128x128 (hi+lo)
    int j = i - 229376; int c = j >> 7, k = j & 127;
    float w = gv_w2[(size_t)l*16384 + (size_t)k*128 + c];
    ushort_t h = f2bf(w);
    base[344064 + j] = h; base[360448 + j] = f2bf(w - bf2f(h));
  }
}

// per-edge: vec, dir, edge RBF(32) in bf16
__global__ void k_geom(const float* __restrict__ pos, const float* __restrict__ dist,
                       const int* __restrict__ ei,
                       float* __restrict__ vec, float* __restrict__ dir,
                       ushort_t* __restrict__ rbf16){
  int e = blockIdx.x*256 + threadIdx.x;
  if (e >= E_) return;
  int s = ei[e], d = ei[E_ + e];
  float vx = pos[d*3+0] - pos[s*3+0];
  float vy = pos[d*3+1] - pos[s*3+1];
  float vz = pos[d*3+2] - pos[s*3+2];
  vec[e*3+0]=vx; vec[e*3+1]=vy; vec[e*3+2]=vz;
  float dd = dist[e];
  float inv = 1.f / (dd + 1e-9f);
  dir[e*3+0]=vx*inv; dir[e*3+1]=vy*inv; dir[e*3+2]=vz*inv;
  #pragma unroll
  for (int i=0;i<32;i++){
    float df = dd - i*STEP_E;
    rbf16[e*32+i] = f2bf(expf(-GAMMA_E*df*df));
  }
}

// gather dir into sorted-edge order: dir_s[p] = dir[perm_e[p]]
__global__ void k_dirs(const float* __restrict__ dir, const int* __restrict__ perm_e,
                       float* __restrict__ dir_s){
  int p = blockIdx.x*256 + threadIdx.x;
  if (p >= E_) return;
  int e = perm_e[p];
  dir_s[p*3+0] = dir[e*3+0];
  dir_s[p*3+1] = dir[e*3+1];
  dir_s[p*3+2] = dir[e*3+2];
}

// per-triplet angle
__global__ void k_angle(const float* __restrict__ vec,
                        const int* __restrict__ kj, const int* __restrict__ ji,
                        float* __restrict__ angle){
  int t = blockIdx.x*256 + threadIdx.x;
  if (t >= T_) return;
  int ea = ji[t], eb = kj[t];
  float ax=vec[ea*3+0], ay=vec[ea*3+1], az=vec[ea*3+2];
  float bx=vec[eb*3+0], by=vec[eb*3+1], bz=vec[eb*3+2];
  float dot = ax*bx + ay*by + az*bz;
  float na = sqrtf(ax*ax+ay*ay+az*az + 1e-12f);
  float nb = sqrtf(bx*bx+by*by+bz*bz + 1e-12f);
  float c = dot / (na*nb + 1e-9f);
  c = fminf(fmaxf(c, -1.f + 1e-7f), 1.f - 1e-7f);
  angle[t] = acosf(c);
}

// ---------------- counting-sort kernels ----------------

__global__ void k_hist(const int* __restrict__ keys, int M, int* __restrict__ hist){
  int i = blockIdx.x*256 + threadIdx.x;
  if (i < M) atomicAdd(&hist[keys[i]], 1);
}

__global__ void k_hist2(const int* __restrict__ keys, const int* __restrict__ map,
                        int M, int* __restrict__ hist){
  int i = blockIdx.x*256 + threadIdx.x;
  if (i < M) atomicAdd(&hist[map[keys[i]]], 1);
}

__global__ void k_scan1(const int* __restrict__ in, int* __restrict__ out,
                        int* __restrict__ sums, int B){
  __shared__ int sh[1024];
  int base = blockIdx.x*1024, t = threadIdx.x;
  for (int j=t;j<1024;j+=256) sh[j] = (base+j<B) ? in[base+j] : 0;
  __syncthreads();
  for (int o=1;o<1024;o<<=1){
    int v[4];
    #pragma unroll
    for (int q=0;q<4;q++){ int idx=t+q*256; v[q]=(idx>=o)? sh[idx-o]:0; }
    __syncthreads();
    #pragma unroll
    for (int q=0;q<4;q++){ int idx=t+q*256; sh[idx]+=v[q]; }
    __syncthreads();
  }
  for (int j=t;j<1024;j+=256) if (base+j<B) out[base+j] = (j==0)?0:sh[j-1];
  if (t==0) sums[blockIdx.x] = sh[1023];
}

__global__ void k_scan2(int* __restrict__ sums, int nb){
  if (threadIdx.x==0 && blockIdx.x==0){
    int a=0;
    for (int i=0;i<nb;i++){ int x=sums[i]; sums[i]=a; a+=x; }
  }
}

__global__ void k_scan3(int* __restrict__ out, const int* __restrict__ sums, int B){
  int i = blockIdx.x*256+threadIdx.x;
  if (i<B) out[i] += sums[i>>10];
}

__global__ void k_fill(const int* __restrict__ keys, int M, int* __restrict__ cur,
                       int* __restrict__ perm){
  int i = blockIdx.x*256+threadIdx.x;
  if (i<M){ int p = atomicAdd(&cur[keys[i]],1); perm[p]=i; }
}

__global__ void k_fill2(const int* __restrict__ keys, const int* __restrict__ map,
                        int M, int* __restrict__ cur, int* __restrict__ perm){
  int i = blockIdx.x*256+threadIdx.x;
  if (i<M){ int p = atomicAdd(&cur[map[keys[i]]],1); perm[p]=i; }
}

__global__ void k_invert(const int* __restrict__ perm, int* __restrict__ rank, int M){
  int i = blockIdx.x*256+threadIdx.x;
  if (i<M) rank[perm[i]] = i;
}

// ---------------- MFMA first-layer MLP (4-wave block, 16 rows/wave) ----------------
// 256 threads = 4 waves, each wave owns 16 rows (64 rows/block). Per 32-k chunk:
// the chunk's GATHER load is issued FIRST (latency overlaps the weight staging +
// barrier), then the W1 slice is cooperatively staged in LDS, then MFMA.
// acc is only 32 regs/lane -> no register squeeze at 4+ blocks/CU
// (R15 lesson: occupancy bought with reg pressure sinks the gathers).
template<int SM, int K1PAD>
__launch_bounds__(256, 4)
__global__ void k_mlp1(
    const int* __restrict__ perm,
    const int* __restrict__ idx1, const int* __restrict__ idx2,
    const ushort_t* __restrict__ rbf16, const float* __restrict__ angle,
    const ushort_t* __restrict__ s16, const ushort_t* __restrict__ eagg_in,
    const ushort_t* __restrict__ W1t, const float* __restrict__ b1,
    ushort_t* __restrict__ outbuf)
{
  __shared__ ushort_t lw[128*WSTRIDE];       // 9216 B weight chunk
  __shared__ ushort_t hid[4][16*HSTRIDE];    // 17408 B (per-wave staging)  -> 26.6 KB total
  const int tid  = threadIdx.x;
  const int wave = tid >> 6;
  const int lane = tid & 63;
  const int n    = lane & 15;
  const int quad = lane >> 4;
  const int kq   = quad*8;
  const int wrow = blockIdx.x*64 + wave*16;
  const int row  = wrow + n;

  const int e0 = perm[row];
  int i1a = idx1[e0];
  int i2a = idx2[e0];
  float ang0 = 0.f;
  if (SM == 1){ ang0 = angle[e0]; }

  f32x4 acc[8];
  #pragma unroll
  for (int ct=0;ct<8;ct++) acc[ct] = (f32x4){0.f,0.f,0.f,0.f};

  #pragma unroll
  for (int k0 = 0; k0 < K1PAD; k0 += 32){
    // ---- issue this chunk's gather load FIRST (overlap with staging+barrier) ----
    short8 a0;
    if (SM == 1){
      if (k0 == 0){
        a0 = *(const short8*)&rbf16[(size_t)i1a*32 + kq];
      } else if (k0 == 32){
        a0 = *(const short8*)&rbf16[(size_t)i2a*32 + kq];
      } else {
        #pragma unroll
        for (int j=0;j<8;j++){
          int kk = kq + j;
          float v0 = 0.f;
          if (kk < 16){
            float c = (float)kk*STEP_A;
            float d0 = ang0 - c;
            v0 = expf(-GAMMA_A*d0*d0);
          }
          a0[j] = (short)f2bf(v0);
        }
      }
    } else {
      const int k = k0 + kq;
      if (k0 < 128){
        a0 = *(const short8*)&s16[(size_t)i1a*128 + k];
      } else if (k0 < 256){
        a0 = *(const short8*)&s16[(size_t)i2a*128 + (k-128)];
      } else if (k0 < 288){
        a0 = *(const short8*)&rbf16[(size_t)e0*32 + (k-256)];
      } else {
        // eagg (post-W2) bf16 in sorted-edge-position order -> sequential rows
        a0 = *(const short8*)&eagg_in[(size_t)row*128 + (k-288)];
      }
    }

    // ---- cooperative stage of the 128x32 weight slice (hi only) ----
    #pragma unroll
    for (int it=0; it<2; it++){
      int idx = tid + it*256;           // 0..511
      int col = idx >> 2, seg = idx & 3;
      *(short8*)&lw[col*WSTRIDE + seg*8] = *(const short8*)&W1t[(size_t)col*K1PAD + k0 + seg*8];
    }
    __syncthreads();

    #pragma unroll
    for (int ct=0;ct<8;ct++){
      short8 b = *(const short8*)&lw[(ct*16 + n)*WSTRIDE + kq];
      acc[ct] = __builtin_amdgcn_mfma_f32_16x16x32_bf16(a0, b, acc[ct], 0,0,0);
    }
    __syncthreads();
  }

  // bias + silu -> LDS staging (wave-private), then coalesced 16B stores
  #pragma unroll
  for (int ct=0;ct<8;ct++){
    int col = ct*16 + n;
    float bv = b1[col];
    #pragma unroll
    for (int reg=0;reg<4;reg++){
      int rloc = quad*4 + reg;
      float h = acc[ct][reg] + bv;
      hid[wave][rloc*HSTRIDE + col] = f2bf(silu_f(h));
    }
  }
  const int rsub = lane >> 4;
  const int c8   = (lane & 15) * 8;
  #pragma unroll
  for (int i=0;i<4;i++){
    int rloc = i*4 + rsub;
    int grow = wrow + rloc;
    short8 vv = *(const short8*)&hid[wave][(size_t)rloc*HSTRIDE + c8];
    *(short8*)&outbuf[(size_t)grow*128 + c8] = vv;
  }
}

// ---------------- FUSED triplet aggregate + W2 GEMM ----------------
__launch_bounds__(64, 4)
__global__ void k_aggemm_t(const ushort_t* __restrict__ tmsg, const int* __restrict__ tends,
                           const ushort_t* __restrict__ W2t, const float* __restrict__ b2,
                           ushort_t* __restrict__ eagg2){
  __shared__ ushort_t hid[MROWS*HSTRIDE];
  const int lane = threadIdx.x;
  const int n    = lane & 15;
  const int quad = lane >> 4;
  const int kq   = quad*8;
  const int wrow = blockIdx.x*MROWS;
  const int r0 = wrow + n, r1 = wrow + 16 + n;
  const int s0 = r0 ? tends[r0-1] : 0;
  const int e0 = tends[r0];
  const int s1 = tends[r1-1];
  const int e1 = tends[r1];

  f32x4 acc[2][8];
  #pragma unroll
  for (int rh=0;rh<2;rh++)
    #pragma unroll
    for (int ct=0;ct<8;ct++) acc[rh][ct] = (f32x4){0.f,0.f,0.f,0.f};

  #pragma unroll
  for (int k0=0;k0<128;k0+=32){
    float sum0[8], sum1[8];
    #pragma unroll
    for (int j=0;j<8;j++){ sum0[j]=0.f; sum1[j]=0.f; }
    for (int p=s0;p<e0;p++){
      short8 w = *(const short8*)&tmsg[(size_t)p*128 + k0 + kq];
      #pragma unroll
      for (int j=0;j<8;j++) sum0[j] += bf2f((ushort_t)w[j]);
    }
    for (int p=s1;p<e1;p++){
      short8 w = *(const short8*)&tmsg[(size_t)p*128 + k0 + kq];
      #pragma unroll
      for (int j=0;j<8;j++) sum1[j] += bf2f((ushort_t)w[j]);
    }
    short8 a0, a1;
    #pragma unroll
    for (int j=0;j<8;j++){
      a0[j] = (short)f2bf(sum0[j]);
      a1[j] = (short)f2bf(sum1[j]);
    }
    #pragma unroll
    for (int ct=0;ct<8;ct++){
      short8 b = *(const short8*)&W2t[(size_t)(ct*16 + n)*128 + k0 + kq];
      acc[0][ct] = __builtin_amdgcn_mfma_f32_16x16x32_bf16(a0, b, acc[0][ct], 0,0,0);
      acc[1][ct] = __builtin_amdgcn_mfma_f32_16x16x32_bf16(a1, b, acc[1][ct], 0,0,0);
    }
  }

  // per-row segment counts for the bias
  float cnts[2][4];
  #pragma unroll
  for (int rh=0;rh<2;rh++)
    #pragma unroll
    for (int reg=0;reg<4;reg++){
      int row = wrow + rh*16 + quad*4 + reg;
      cnts[rh][reg] = (float)(tends[row] - (row ? tends[row-1] : 0));
    }

  #pragma unroll
  for (int rh=0;rh<2;rh++){
    #pragma unroll
    for (int ct=0;ct<8;ct++){
      int col = ct*16 + n;
      float bv = b2[col];
      #pragma unroll
      for (int reg=0;reg<4;reg++){
        int rloc = rh*16 + quad*4 + reg;
        hid[rloc*HSTRIDE + col] = f2bf(acc[rh][ct][reg] + cnts[rh][reg]*bv);
      }
    }
  }
  const int rsub = lane >> 4;
  const int c8   = (lane & 15) * 8;
  #pragma unroll
  for (int i=0;i<8;i++){
    int rloc = i*4 + rsub;
    int grow = wrow + rloc;
    short8 vv = *(const short8*)&hid[(size_t)rloc*HSTRIDE + c8];
    *(short8*)&eagg2[(size_t)grow*128 + c8] = vv;
  }
}

// edge moment reducer
__global__ void k_agg_e(const ushort_t* __restrict__ hbuf, const int* __restrict__ eends,
                        const float* __restrict__ dir_s, float* __restrict__ mom){
  int i = blockIdx.x*256 + threadIdx.x;
  int d = i >> 6, c2 = (i & 63)*2;
  if (d >= N_) return;
  int s = (d == 0) ? 0 : eends[d-1];
  int e = eends[d];
  float hs0=0.f,hs1=0.f, hx0=0.f,hx1=0.f, hy0=0.f,hy1=0.f, hz0=0.f,hz1=0.f;
  float sdx=0.f, sdy=0.f, sdz=0.f;
  for (int q=s;q<e;q++){
    unsigned int w = *(const unsigned int*)&hbuf[(size_t)q*128 + c2];
    float h0 = bf2f((ushort_t)(w & 0xFFFFu));
    float h1 = bf2f((ushort_t)(w >> 16));
    float dx = dir_s[q*3+0], dy = dir_s[q*3+1], dz = dir_s[q*3+2];
    hs0 += h0; hs1 += h1;
    hx0 += h0*dx; hx1 += h1*dx;
    hy0 += h0*dy; hy1 += h1*dy;
    hz0 += h0*dz; hz1 += h1*dz;
    sdx += dx; sdy += dy; sdz += dz;
  }
  size_t base = (size_t)d*128 + c2;
  *(float2*)&mom[base]                        = make_float2(hs0, hs1);
  *(float2*)&mom[(size_t)N_*128   + base]     = make_float2(hx0, hx1);
  *(float2*)&mom[(size_t)N_*256   + base]     = make_float2(hy0, hy1);
  *(float2*)&mom[(size_t)N_*384   + base]     = make_float2(hz0, hz1);
  if (c2 == 0){
    mom[(size_t)N_*512 + d*4+0] = sdx;
    mom[(size_t)N_*512 + d*4+1] = sdy;
    mom[(size_t)N_*512 + d*4+2] = sdz;
  }
}

// edge: moment GEMM per og = blockIdx.y (0: Ms -> a16 + vn; 1..3: Mx/My/Mz -> aggv plane).
__launch_bounds__(64, 4)
__global__ void k_gemm_e(const float* __restrict__ mom, const int* __restrict__ eends,
                         const ushort_t* __restrict__ W2t /*[256][128]*/,
                         const float* __restrict__ b2 /*[256]*/,
                         const float* __restrict__ v /*[3][N][128]*/,
                         ushort_t* __restrict__ a16h, ushort_t* __restrict__ a16l,
                         ushort_t* __restrict__ vnh,  ushort_t* __restrict__ vnl,
                         float* __restrict__ aggv /*[3][N][128]*/){
  __shared__ float sbuf[MROWS*130];   // 16640 B staging
  const int lane = threadIdx.x;
  const int n    = lane & 15;
  const int quad = lane >> 4;
  const int kq   = quad*8;
  const int wrow = blockIdx.x*MROWS;
  const int og   = blockIdx.y;

  const float* M = mom + (size_t)og*((size_t)N_*128);
  const ushort_t* W = W2t + (og ? (size_t)128*128 : 0);

  f32x4 acc[2][8];
  #pragma unroll
  for (int rh=0;rh<2;rh++)
    #pragma unroll
    for (int ct=0;ct<8;ct++) acc[rh][ct] = (f32x4){0.f,0.f,0.f,0.f};

  #pragma unroll
  for (int k0=0;k0<128;k0+=32){
    const int k = k0 + kq;
    const float* p0 = &M[(size_t)(wrow + n)*128 + k];
    const float* p1 = &M[(size_t)(wrow + 16 + n)*128 + k];
    f32x4 x0 = *(const f32x4*)p0, x1 = *(const f32x4*)(p0+4);
    f32x4 y0 = *(const f32x4*)p1, y1 = *(const f32x4*)(p1+4);
    short8 ah0, al0, ah1, al1;
    #pragma unroll
    for (int j=0;j<4;j++){
      ushort_t h;
      h = f2bf(x0[j]); ah0[j]   = (short)h; al0[j]   = (short)f2bf(x0[j] - bf2f(h));
      h = f2bf(x1[j]); ah0[4+j] = (short)h; al0[4+j] = (short)f2bf(x1[j] - bf2f(h));
      h = f2bf(y0[j]); ah1[j]   = (short)h; al1[j]   = (short)f2bf(y0[j] - bf2f(h));
      h = f2bf(y1[j]); ah1[4+j] = (short)h; al1[4+j] = (short)f2bf(y1[j] - bf2f(h));
    }
    #pragma unroll
    for (int ct=0;ct<8;ct++){
      short8 b = *(const short8*)&W[(size_t)(ct*16 + n)*128 + k0 + kq];
      acc[0][ct] = __builtin_amdgcn_mfma_f32_16x16x32_bf16(ah0, b, acc[0][ct], 0,0,0);
      acc[0][ct] = __builtin_amdgcn_mfma_f32_16x16x32_bf16(al0, b, acc[0][ct], 0,0,0);
      acc[1][ct] = __builtin_amdgcn_mfma_f32_16x16x32_bf16(ah1, b, acc[1][ct], 0,0,0);
      acc[1][ct] = __builtin_amdgcn_mfma_f32_16x16x32_bf16(al1, b, acc[1][ct], 0,0,0);
    }
  }

  const int rsub = lane >> 4;
  const int c8   = (lane & 15) * 8;

  if (og == 0){
    float cnts[2][4];
    #pragma unroll
    for (int rh=0;rh<2;rh++)
      #pragma unroll
      for (int reg=0;reg<4;reg++){
        int row = wrow + rh*16 + quad*4 + reg;
        cnts[rh][reg] = (float)(eends[row] - (row ? eends[row-1] : 0));
      }
    ushort_t* us = (ushort_t*)sbuf;
    // pass 1: hi
    #pragma unroll
    for (int rh=0;rh<2;rh++)
      #pragma unroll
      for (int ct=0;ct<8;ct++){
        int col = ct*16 + n;
        float bv = b2[col];
        #pragma unroll
        for (int reg=0;reg<4;reg++){
          int rloc = rh*16 + quad*4 + reg;
          float val = acc[rh][ct][reg] + cnts[rh][reg]*bv;
          us[rloc*HSTRIDE + col] = f2bf(val);
        }
      }
    #pragma unroll
    for (int i=0;i<8;i++){
      int rloc = i*4 + rsub;
      short8 vv = *(const short8*)&us[(size_t)rloc*HSTRIDE + c8];
      *(short8*)&a16h[(size_t)(wrow + rloc)*128 + c8] = vv;
    }
    // pass 2: lo
    #pragma unroll
    for (int rh=0;rh<2;rh++)
      #pragma unroll
      for (int ct=0;ct<8;ct++){
        int col = ct*16 + n;
        float bv = b2[col];
        #pragma unroll
        for (int reg=0;reg<4;reg++){
          int rloc = rh*16 + quad*4 + reg;
          float val = acc[rh][ct][reg] + cnts[rh][reg]*bv;
          ushort_t h = f2bf(val);
          us[rloc*HSTRIDE + col] = f2bf(val - bf2f(h));
        }
      }
    #pragma unroll
    for (int i=0;i<8;i++){
      int rloc = i*4 + rsub;
      short8 vv = *(const short8*)&us[(size_t)rloc*HSTRIDE + c8];
      *(short8*)&a16l[(size_t)(wrow + rloc)*128 + c8] = vv;
    }
    // vn norms, linear sweep (planar v)
    #pragma unroll 4
    for (int j=0;j<32;j++){
      size_t idx = (size_t)wrow*128 + (size_t)j*128 + lane*2;
      float2 a = *(const float2*)&v[idx];
      float2 b = *(const float2*)&v[(size_t)N_*128 + idx];
      float2 c = *(const float2*)&v[(size_t)N_*256 + idx];
      float n0 = sqrtf(a.x*a.x + b.x*b.x + c.x*c.x + 1e-12f);
      float n1 = sqrtf(a.y*a.y + b.y*b.y + c.y*c.y + 1e-12f);
      ushort_t h0 = f2bf(n0), h1 = f2bf(n1);
      *(unsigned int*)&vnh[idx] = (unsigned int)h0 | ((unsigned int)h1 << 16);
      *(unsigned int*)&vnl[idx] = (unsigned int)f2bf(n0 - bf2f(h0))
                                | ((unsigned int)f2bf(n1 - bf2f(h1)) << 16);
    }
  } else {
    const int x = og - 1;
    #pragma unroll
    for (int rh=0;rh<2;rh++)
      #pragma unroll
      for (int ct=0;ct<8;ct++){
        int col = ct*16 + n;
        float bv = b2[128 + col];
        #pragma unroll
        for (int reg=0;reg<4;reg++){
          int rloc = rh*16 + quad*4 + reg;
          int row = wrow + rloc;
          float sd = mom[(size_t)N_*512 + row*4 + x];
          sbuf[rloc*130 + col] = acc[rh][ct][reg] + sd*bv;
        }
      }
    float* plane = aggv + (size_t)x*((size_t)N_*128);
    #pragma unroll
    for (int i=0;i<8;i++){
      int rloc = i*4 + rsub;
      f32x4 v0 = *(const f32x4*)&sbuf[rloc*130 + c8];
      f32x4 v1 = *(const f32x4*)&sbuf[rloc*130 + c8 + 4];
      *(f32x4*)&plane[(size_t)(wrow + rloc)*128 + c8] = v0;
      *(f32x4*)&plane[(size_t)(wrow + rloc)*128 + c8 + 4] = v1;
    }
  }
}

// ---------------- MFMA node-update kernel (4-wave block, LDS-shared weights) ----------------
__launch_bounds__(256, 3)
__global__ void k_node_mfma(
    const float* __restrict__ s_in,
    const ushort_t* __restrict__ a16h, const ushort_t* __restrict__ a16l,
    const ushort_t* __restrict__ vnh,  const ushort_t* __restrict__ vnl,
    float* __restrict__ s2, float* __restrict__ v_out /*[3][N][128]*/,
    const float* __restrict__ aggv /*[3][N][128]*/,
    const ushort_t* __restrict__ us1h, const ushort_t* __restrict__ us1l, const float* __restrict__ us_b1,
    const ushort_t* __restrict__ us2h, const ushort_t* __restrict__ us2l, const float* __restrict__ us_b2,
    const ushort_t* __restrict__ gv1h, const ushort_t* __restrict__ gv1l, const float* __restrict__ gv_b1,
    const ushort_t* __restrict__ gv2h, const ushort_t* __restrict__ gv2l, const float* __restrict__ gv_b2)
{
  __shared__ ushort_t lwh[128*WSTRIDE];       // 9216 B weight chunk (hi)
  __shared__ ushort_t lwl[128*WSTRIDE];       // 9216 B weight chunk (lo)
  __shared__ ushort_t hidh[4][16*HSTRIDE];    // 17408 B
  __shared__ ushort_t hidl[4][16*HSTRIDE];    // 17408 B  (total 53248 B)
  const int tid  = threadIdx.x;
  const int wave = tid >> 6;
  const int lane = tid & 63;
  const int n    = lane & 15;
  const int quad = lane >> 4;
  const int kq   = quad*8;
  const int og   = blockIdx.y;
  const int wrow = blockIdx.x*64 + wave*16;
  const int r0 = wrow + n;

  const ushort_t* W1h = og ? gv1h : us1h;
  const ushort_t* W1l = og ? gv1l : us1l;
  const float*    B1  = og ? gv_b1 : us_b1;
  const ushort_t* W2h = og ? gv2h : us2h;
  const ushort_t* W2l = og ? gv2l : us2l;
  const float*    B2  = og ? gv_b2 : us_b2;

  // ---------- phase A ----------
  f32x4 acc[8];
  #pragma unroll
  for (int ct=0;ct<8;ct++) acc[ct] = (f32x4){0.f,0.f,0.f,0.f};

  #pragma unroll
  for (int k0=0; k0<384; k0+=32){
    #pragma unroll
    for (int it = 0; it < 2; it++){
      int idx = tid + it*256;          // 0..511
      int col = idx >> 2, seg = idx & 3;
      *(short8*)&lwh[col*WSTRIDE + seg*8] = *(const short8*)&W1h[(size_t)col*384 + k0 + seg*8];
      *(short8*)&lwl[col*WSTRIDE + seg*8] = *(const short8*)&W1l[(size_t)col*384 + k0 + seg*8];
    }
    __syncthreads();

    short8 ah0, al0;
    const int k = k0 + kq;
    if (k0 < 128){
      const float* p0 = &s_in[(size_t)r0*128 + k];
      f32x4 x0 = *(const f32x4*)p0, x1 = *(const f32x4*)(p0+4);
      #pragma unroll
      for (int j=0;j<4;j++){
        ushort_t h;
        h = f2bf(x0[j]); ah0[j]   = (short)h; al0[j]   = (short)f2bf(x0[j] - bf2f(h));
        h = f2bf(x1[j]); ah0[4+j] = (short)h; al0[4+j] = (short)f2bf(x1[j] - bf2f(h));
      }
    } else if (k0 < 256){
      int kk = k - 128;
      ah0 = *(const short8*)&a16h[(size_t)r0*128 + kk];
      al0 = *(const short8*)&a16l[(size_t)r0*128 + kk];
    } else {
      int kk = k - 256;
      ah0 = *(const short8*)&vnh[(size_t)r0*128 + kk];
      al0 = *(const short8*)&vnl[(size_t)r0*128 + kk];
    }
    #pragma unroll
    for (int ct=0;ct<8;ct++){
      short8 bh = *(const short8*)&lwh[(ct*16 + n)*WSTRIDE + kq];
      short8 bl = *(const short8*)&lwl[(ct*16 + n)*WSTRIDE + kq];
      acc[ct] = __builtin_amdgcn_mfma_f32_16x16x32_bf16(ah0, bh, acc[ct], 0,0,0);
      acc[ct] = __builtin_amdgcn_mfma_f32_16x16x32_bf16(al0, bh, acc[ct], 0,0,0);
      acc[ct] = __builtin_amdgcn_mfma_f32_16x16x32_bf16(ah0, bl, acc[ct], 0,0,0);
    }
    __syncthreads();
  }

  #pragma unroll
  for (int ct=0;ct<8;ct++){
    int col = ct*16 + n;
    float bv = B1[col];
    #pragma unroll
    for (int reg=0;reg<4;reg++){
      int rloc = quad*4 + reg;
      float h = silu_f(acc[ct][reg] + bv);
      ushort_t hh = f2bf(h);
      hidh[wave][rloc*HSTRIDE + col] = hh;
      hidl[wave][rloc*HSTRIDE + col] = f2bf(h - bf2f(hh));
    }
  }

  // ---------- phase B ----------
  f32x4 acc2[8];
  #pragma unroll
  for (int ct=0;ct<8;ct++) acc2[ct] = (f32x4){0.f,0.f,0.f,0.f};

  #pragma unroll
  for (int k0=0;k0<128;k0+=32){
    #pragma unroll
    for (int it = 0; it < 2; it++){
      int idx = tid + it*256;
      int col = idx >> 2, seg = idx & 3;
      *(short8*)&lwh[col*WSTRIDE + seg*8] = *(const short8*)&W2h[(size_t)col*128 + k0 + seg*8];
      *(short8*)&lwl[col*WSTRIDE + seg*8] = *(const short8*)&W2l[(size_t)col*128 + k0 + seg*8];
    }
    __syncthreads();

    short8 ah0 = *(const short8*)&hidh[wave][(size_t)(n)*HSTRIDE + k0 + kq];
    short8 al0 = *(const short8*)&hidl[wave][(size_t)(n)*HSTRIDE + k0 + kq];
    #pragma unroll
    for (int ct=0;ct<8;ct++){
      short8 bh = *(const short8*)&lwh[(ct*16 + n)*WSTRIDE + kq];
      short8 bl = *(const short8*)&lwl[(ct*16 + n)*WSTRIDE + kq];
      acc2[ct] = __builtin_amdgcn_mfma_f32_16x16x32_bf16(ah0, bh, acc2[ct], 0,0,0);
      acc2[ct] = __builtin_amdgcn_mfma_f32_16x16x32_bf16(al0, bh, acc2[ct], 0,0,0);
      acc2[ct] = __builtin_amdgcn_mfma_f32_16x16x32_bf16(ah0, bl, acc2[ct], 0,0,0);
    }
    __syncthreads();
  }

  if (og == 0){
    #pragma unroll
    for (int ct=0;ct<8;ct++){
      int col = ct*16 + n;
      float bv = B2[col];
      #pragma unroll
      for (int reg=0;reg<4;reg++){
        int row = wrow + quad*4 + reg;
        size_t idx = (size_t)row*128 + col;
        s2[idx] = s_in[idx] + acc2[ct][reg] + bv;
      }
    }
  } else {
    #pragma unroll
    for (int ct=0;ct<8;ct++){
      int col = ct*16 + n;
      float bv = B2[col];
      #pragma unroll
      for (int reg=0;reg<4;reg++){
        int row = wrow + quad*4 + reg;
        size_t idx = (size_t)row*128 + col;
        float g = sigmoid_f(acc2[ct][reg] + bv);
        v_out[idx]                    += g*aggv[idx];
        v_out[(size_t)N_*128 + idx]   += g*aggv[(size_t)N_*128 + idx];
        v_out[(size_t)N_*256 + idx]   += g*aggv[(size_t)N_*256 + idx];
      }
    }
  }
}

// ---------------- generic fp32 row-MLP GEMM (node_in only) ----------------
__launch_bounds__(128)
__global__ void k_gemm(const float* __restrict__ A,
                       const float* __restrict__ W,
                       const float* __restrict__ bias,
                       float* __restrict__ C, int R, int K)
{
  __shared__ float ws[CW*128];
  __shared__ float as[RB][CW];
  const int tid = threadIdx.x;
  const int nchunk = (K + CW - 1) / CW;

  for (int rb = blockIdx.x*RB; rb < R; rb += gridDim.x*RB){
    float acc[RB];
    #pragma unroll
    for (int r=0;r<RB;r++) acc[r] = 0.f;

    for (int c=0;c<nchunk;c++){
      const int k0 = c*CW;
      for (int i=tid; i<CW*128; i+=128){
        int kk = i >> 7, col = i & 127;
        int k = k0 + kk;
        ws[i] = (k < K) ? W[k*128 + col] : 0.f;
      }
      for (int i=tid; i<RB*CW; i+=128){
        int r  = i >> 6, kk = i & 63;
        int k  = k0 + kk;
        as[r][kk] = (k < K) ? A[(long)(rb+r)*K + k] : 0.f;
      }
      __syncthreads();
      #pragma unroll 4
      for (int kq2=0; kq2<CW/4; kq2++){
        float w0 = ws[(4*kq2+0)*128 + tid];
        float w1 = ws[(4*kq2+1)*128 + tid];
        float w2 = ws[(4*kq2+2)*128 + tid];
        float w3 = ws[(4*kq2+3)*128 + tid];
        #pragma unroll
        for (int r=0;r<RB;r++){
          const float4 av = *reinterpret_cast<const float4*>(&as[r][4*kq2]);
          acc[r] = fmaf(av.x, w0, acc[r]);
          acc[r] = fmaf(av.y, w1, acc[r]);
          acc[r] = fmaf(av.z, w2, acc[r]);
          acc[r] = fmaf(av.w, w3, acc[r]);
        }
      }
      __syncthreads();
    }

    const float bv = bias[tid];
    #pragma unroll
    for (int r=0;r<RB;r++)
      C[(long)(rb+r)*128 + tid] = acc[r] + bv;
  }
}

// ---------------- small fused kernels ----------------

// G x 128 2-layer MLP, row-parallel: grid 8 blocks x 4 rows each.
__launch_bounds__(256)
__global__ void k_small_mlp2(const float* __restrict__ in,
                             const float* __restrict__ w1, const float* __restrict__ b1,
                             const float* __restrict__ w2, const float* __restrict__ b2,
                             float* __restrict__ outp, int accumulate){
  __shared__ float a[4][128];
  __shared__ float h[4][128];
  int tid = threadIdx.x;
  int rbase = blockIdx.x*4;
  for (int i=tid;i<4*128;i+=256) a[i>>7][i&127] = in[(rbase + (i>>7))*128 + (i&127)];
  __syncthreads();
  int col = tid & 127, rg = tid >> 7;   // rg 0..1 -> rows rg*2, rg*2+1
  float acc0=0.f, acc1=0.f;
  for (int k=0;k<128;k++){
    float w = w1[k*128+col];
    acc0 = fmaf(a[rg*2+0][k], w, acc0);
    acc1 = fmaf(a[rg*2+1][k], w, acc1);
  }
  {
    float bv = b1[col];
    h[rg*2+0][col] = silu_f(acc0+bv);
    h[rg*2+1][col] = silu_f(acc1+bv);
  }
  __syncthreads();
  acc0=0.f; acc1=0.f;
  for (int k=0;k<128;k++){
    float w = w2[k*128+col];
    acc0 = fmaf(h[rg*2+0][k], w, acc0);
    acc1 = fmaf(h[rg*2+1][k], w, acc1);
  }
  {
    float bv = b2[col];
    int idx0 = (rbase+rg*2+0)*128+col;
    int idx1 = (rbase+rg*2+1)*128+col;
    float v0 = acc0+bv, v1 = acc1+bv;
    outp[idx0] = accumulate ? outp[idx0]+v0 : v0;
    outp[idx1] = accumulate ? outp[idx1]+v1 : v1;
  }
}

__global__ void k_head(const float* __restrict__ gbuf,
                       const float* __restrict__ w1, const float* __restrict__ b1,
                       const float* __restrict__ w2, const float* __restrict__ b2,
                       float* __restrict__ outp){
  __shared__ float red[128];
  int g = blockIdx.x, tid = threadIdx.x;
  float acc = 0.f;
  for (int k=0;k<640;k++) acc = fmaf(gbuf[g*640+k], w1[k*128+tid], acc);
  float h = silu_f(acc + b1[tid]);
  red[tid] = h * w2[tid];
  __syncthreads();
  for (int o=64;o>0;o>>=1){ if (tid<o) red[tid]+=red[tid+o]; __syncthreads(); }
  if (tid == 0) outp[g] = red[0] + b2[0];
}

// ---------------- elementwise / reduction kernels ----------------

__global__ void k_sadd_batch(float* __restrict__ s, const float* __restrict__ t2,
                             const int* __restrict__ batch, ushort_t* __restrict__ s16){
  int i = blockIdx.x*256 + threadIdx.x;
  if (i >= N_*H_) return;
  int n = i >> 7, h = i & 127;
  float v = s[i] + t2[batch[n]*128 + h];
  s[i] = v;
  s16[i] = f2bf(v);
}

// LN + silu (no atomics)
__global__ void k_ln_silu(const float* __restrict__ in, float* __restrict__ outp,
                          const float* __restrict__ g, const float* __restrict__ b){
  __shared__ float red[128];
  int n = blockIdx.x, tid = threadIdx.x;
  float x = in[n*128 + tid];
  red[tid] = x; __syncthreads();
  for (int o=64;o>0;o>>=1){ if (tid<o) red[tid]+=red[tid+o]; __syncthreads(); }
  float mu = red[0] * (1.f/128.f);
  __syncthreads();
  float dx = x - mu;
  red[tid] = dx*dx; __syncthreads();
  for (int o=64;o>0;o>>=1){ if (tid<o) red[tid]+=red[tid+o]; __syncthreads(); }
  float var = red[0] * (1.f/128.f);
  float y = dx * rsqrtf(var + 1e-5f) * g[tid] + b[tid];
  outp[n*128 + tid] = silu_f(y);
}

// batch CSR segment-sum of s into ssum (ssum pre-zeroed)
__global__ void k_ssum_csr(const float* __restrict__ s, const int* __restrict__ bends,
                           float* __restrict__ ssum){
  int g = blockIdx.x, c = blockIdx.y, tid = threadIdx.x;
  int s0 = g ? bends[g-1] : 0;
  int e0 = bends[g];
  long len = e0 - s0;
  int lo = s0 + (int)((len*c) >> 3);
  int hi = s0 + (int)((len*(c+1)) >> 3);
  float a = 0.f;
  for (int n=lo; n<hi; n++) a += s[(size_t)n*128 + tid];
  if (hi > lo) atomicAdd(&ssum[g*128 + tid], a);
}

// readout scatter: per-block segmented accumulation over 32 sorted nodes
__global__ void k_scatter_nf2(const float* __restrict__ s, const float* __restrict__ v /*[3][N][128]*/,
                              const int* __restrict__ batch, float* __restrict__ addp){
  int j = threadIdx.x;            // 0..255 (col in the 256-wide nf row)
  int base = blockIdx.x*32;
  float acc = 0.f;
  int prev = batch[base];
  for (int r=0;r<32;r++){
    int nn = base + r;
    int b = batch[nn];
    if (b != prev){ atomicAdd(&addp[prev*256 + j], acc); acc = 0.f; prev = b; }
    float val;
    if (j < 128){
      val = s[(size_t)nn*128 + j];
    } else {
      size_t idx = (size_t)nn*128 + (j - 128);
      float v0 = v[idx], v1 = v[(size_t)N_*128 + idx], v2 = v[(size_t)N_*256 + idx];
      val = sqrtf(v0*v0 + v1*v1 + v2*v2 + 1e-12f);
    }
    acc += val;
  }
  atomicAdd(&addp[prev*256 + j], acc);
}

// counts derived from bends (no atomics)
__global__ void k_build_g(const float* __restrict__ addp, const int* __restrict__ bends,
                          const float* __restrict__ vn, float* __restrict__ gbuf){
  int i = blockIdx.x*256 + threadIdx.x;
  if (i >= G_*640) return;
  int g = i / 640, j = i % 640;
  float cnt = (float)(bends[g] - (g ? bends[g-1] : 0));
  float val;
  if (j < 256)       val = addp[g*256 + j];
  else if (j < 512)  val = addp[g*256 + (j-256)] / fmaxf(cnt, 1.f);
  else               val = vn[g*128 + (j-512)];
  gbuf[i] = val;
}

// ---------------- host launcher ----------------

extern "C" void kernel_launch(void* const* d_in, const int* in_sizes, int n_in,
                              void* d_out, int out_size, void* d_ws, size_t ws_size,
                              hipStream_t stream)
{
  const float* x         = (const float*)d_in[0];
  const float* pos       = (const float*)d_in[1];
  const float* edist     = (const float*)d_in[2];
  const float* node_in_w = (const float*)d_in[3];
  const float* node_in_b = (const float*)d_in[4];
  const float* tm_w1 = (const float*)d_in[5];
  const float* tm_b1 = (const float*)d_in[6];
  const float* tm_w2 = (const float*)d_in[7];
  const float* tm_b2 = (const float*)d_in[8];
  const float* mm_w1 = (const float*)d_in[9];
  const float* mm_b1 = (const float*)d_in[10];
  const float* mm_w2 = (const float*)d_in[11];
  const float* mm_b2 = (const float*)d_in[12];
  const float* us_w1 = (const float*)d_in[13];
  const float* us_b1 = (const float*)d_in[14];
  const float* us_w2 = (const float*)d_in[15];
  const float* us_b2 = (const float*)d_in[16];
  const float* gv_w1 = (const float*)d_in[17];
  const float* gv_b1 = (const float*)d_in[18];
  const float* gv_w2 = (const float*)d_in[19];
  const float* gv_b2 = (const float*)d_in[20];
  const float* ln_g  = (const float*)d_in[21];
  const float* ln_b  = (const float*)d_in[22];
  const float* vn_init = (const float*)d_in[23];
  const float* v2n_w1 = (const float*)d_in[24];
  const float* v2n_b1 = (const float*)d_in[25];
  const float* v2n_w2 = (const float*)d_in[26];
  const float* v2n_b2 = (const float*)d_in[27];
  const float* n2v_w1 = (const float*)d_in[28];
  const float* n2v_b1 = (const float*)d_in[29];
  const float* n2v_w2 = (const float*)d_in[30];
  const float* n2v_b2 = (const float*)d_in[31];
  const float* head_w1 = (const float*)d_in[32];
  const float* head_b1 = (const float*)d_in[33];
  const float* head_w2 = (const float*)d_in[34];
  const float* head_b2 = (const float*)d_in[35];
  const int* ei    = (const int*)d_in[36];
  const int* t_kj  = (const int*)d_in[37];
  const int* t_ji  = (const int*)d_in[38];
  const int* batch = (const int*)d_in[39];
  float* out = (float*)d_out;

  // ---- workspace layout (~150 MiB) ----
  float* f = (float*)d_ws;
  size_t off = 0;
  auto alloc = [&](size_t n){ n = (n + 3) & ~(size_t)3; float* p = f + off; off += n; return p; };
  float*    vec    = alloc((size_t)E_*3);    // aliased: perm_t + perm_e after k_angle
  float*    dir    = alloc((size_t)E_*3);
  ushort_t* rbf16  = (ushort_t*)alloc((size_t)E_*16);
  float*    angle  = alloc((size_t)T_);
  float*    tmsg_f = alloc((size_t)E_*128);  // triplet hidden T*128 bf16 / edge hidden E*128 bf16
  float*    eagg2_f= alloc((size_t)E_*64);   // eagg bf16 (E*128); later: moments + node scratch
  float*    dir_s  = alloc((size_t)E_*3);    // sorted dir
  float*    tends_f= alloc((size_t)E_ + 1024); // triplet CSR ends (E ints) + scan sums
  float*    eends_f= alloc((size_t)N_ + 1024); // edge CSR ends (N ints) + scan sums
  float*    bends_f= alloc((size_t)G_);      // batch CSR ends (G ints)
  float*    s      = alloc((size_t)N_*128);
  ushort_t* s16    = (ushort_t*)alloc((size_t)N_*64);
  float*    v      = alloc((size_t)N_*384);  // PLANAR [3][N][128]
  float*    aggv   = alloc((size_t)N_*384);  // PLANAR [3][N][128]
  float*    rank_f = alloc((size_t)E_);      // rank_e (E ints)
  float*    wtbuf_f= alloc((size_t)376832);  // bf16 transposed weights (hi + node-lo)
  float*    vn     = alloc((size_t)G_*128);
  float*    tg2    = alloc((size_t)G_*128);
  float*    ssum   = alloc((size_t)G_*128);
  float*    addp   = alloc((size_t)G_*256);
  float*    gbuf   = alloc((size_t)G_*640);

  if (off * sizeof(float) > ws_size){
    k_sentinel<<<1, 64, 0, stream>>>(out, G_);
    return;
  }

  // aliases
  int* perm_t = (int*)vec;
  int* perm_e = perm_t + T_;
  int* rank_e = (int*)rank_f;
  int* tends  = (int*)tends_f;
  int* eends  = (int*)eends_f;
  int* bends  = (int*)bends_f;
  ushort_t* tmsg   = (ushort_t*)tmsg_f;   // T*128 bf16 (triplet hidden)
  ushort_t* ehid   = (ushort_t*)tmsg_f;   // E*128 bf16 (edge hidden; tmsg dead by then)
  ushort_t* eagg2  = (ushort_t*)eagg2_f;  // E*128 bf16
  // edge moments + node scratch inside eagg2_f (eagg2 dead after edge MLP reads it)
  float*    mom  = eagg2_f;                              // [4][N][128] fp32 + sumdir [N][4]
  ushort_t* a16h = (ushort_t*)(eagg2_f + 4227072);       // 4*N*128 + 4*N region
  ushort_t* a16l = a16h + (size_t)N_*128;
  ushort_t* vnh  = a16l + (size_t)N_*128;
  ushort_t* vnl  = vnh  + (size_t)N_*128;
  float*    s2   = (float*)(vnl + (size_t)N_*128);       // N*128 fp32

  ushort_t* wtbuf = (ushort_t*)wtbuf_f;
  auto WT = [&](int l, size_t o){ return wtbuf + (size_t)l*376832 + o; };

  auto zero = [&](float* p, long n){
    int blocks = (int)((n/4 + 255)/256); if (blocks > 16384) blocks = 16384; if (blocks < 1) blocks = 1;
    k_zero<<<blocks, 256, 0, stream>>>(p, n);
  };
  auto csort = [&](const int* keys, const int* map, int M, int B, int* perm, int* ends){
    int nb = (B+1023)/1024;
    zero((float*)ends, B + nb);
    if (map) k_hist2<<<(M+255)/256, 256, 0, stream>>>(keys, map, M, ends);
    else     k_hist <<<(M+255)/256, 256, 0, stream>>>(keys, M, ends);
    k_scan1<<<nb, 256, 0, stream>>>(ends, ends, ends + B, B);
    k_scan2<<<1, 64, 0, stream>>>(ends + B, nb);
    k_scan3<<<(B+255)/256, 256, 0, stream>>>(ends, ends + B, B);
    if (map) k_fill2<<<(M+255)/256, 256, 0, stream>>>(keys, map, M, ends, perm);
    else     k_fill <<<(M+255)/256, 256, 0, stream>>>(keys, M, ends, perm);
    // post-fill: ends[b] == segment end offset for bin b
  };

  // ---- prologue ----
  zero(v, (long)N_*384);
  k_init_vn<<<(G_*H_ + 255)/256, 256, 0, stream>>>(vn, vn_init);
  k_geom<<<(E_ + 255)/256, 256, 0, stream>>>(pos, edist, ei, vec, dir, rbf16);
  k_angle<<<(T_ + 255)/256, 256, 0, stream>>>(vec, t_kj, t_ji, angle);
  csort(ei+E_, nullptr, E_, N_, perm_e, eends);
  k_invert<<<(E_+255)/256, 256, 0, stream>>>(perm_e, rank_e, E_);
  k_dirs<<<(E_+255)/256, 256, 0, stream>>>(dir, perm_e, dir_s);
  csort(t_ji, rank_e, T_, E_, perm_t, tends);
  // batch CSR ends
  zero(bends_f, G_);
  k_bhist<<<(N_+255)/256, 256, 0, stream>>>(batch, bends);
  k_bscan<<<1, 64, 0, stream>>>(bends);
  k_wt_all<<<dim3(960, 2), 256, 0, stream>>>(tm_w1, tm_w2, mm_w1, mm_w2,
                                             us_w1, us_w2, gv_w1, gv_w2, wtbuf);
  k_gemm<<<512, 128, 0, stream>>>(x, node_in_w, node_in_b, s, N_, IND_);

  for (int l=0; l<L_; l++){
    // 1) s += v2n_mlp(vn)[batch]  (snapshots s16)
    k_small_mlp2<<<8, 256, 0, stream>>>(vn, v2n_w1, v2n_b1, v2n_w2, v2n_b2, tg2, 0);
    k_sadd_batch<<<(N_*H_ + 255)/256, 256, 0, stream>>>(s, tg2, batch, s16);

    // 2) triplet: hidden MLP (4-wave, 16 rows/wave, gather-first) -> tmsg; fused CSR+W2 -> eagg2
    k_mlp1<1,96><<<T_/64, 256, 0, stream>>>(perm_t, t_kj, t_ji,
        rbf16, angle, s16, eagg2, WT(l,0), tm_b1 + l*128, tmsg);
    k_aggemm_t<<<E_/MROWS, 64, 0, stream>>>(tmsg, tends, WT(l,12288), tm_b2 + l*128, eagg2);

    // 3) edge: hidden MLP (4-wave, 16 rows/wave, gather-first) -> ehid; moment reduce; W2 GEMMs
    k_mlp1<2,416><<<E_/64, 256, 0, stream>>>(perm_e, ei, ei + E_,
        rbf16, angle, s16, eagg2, WT(l,28672), mm_b1 + l*128, ehid);
    k_agg_e<<<(N_*64)/256, 256, 0, stream>>>(ehid, eends, dir_s, mom);
    k_gemm_e<<<dim3(N_/MROWS, 4), 64, 0, stream>>>(mom, eends, WT(l,81920), mm_b2 + l*256,
        v, a16h, a16l, vnh, vnl, aggv);

    // 5+6) node update (4-wave blocks, LDS-shared weights): s2 = s + us_mlp; gated v update
    k_node_mfma<<<dim3(N_/64, 2), 256, 0, stream>>>(s, a16h, a16l, vnh, vnl, s2, v, aggv,
        WT(l,114688), WT(l,163840), us_b1 + l*128, WT(l,212992), WT(l,229376), us_b2 + l*128,
        WT(l,245760), WT(l,294912), gv_b1 + l*128, WT(l,344064), WT(l,360448), gv_b2 + l*128);

    // 7) s = silu(LN(s2)); 8) vn += n2v_mlp(batch-CSR segment sum of s)
    k_ln_silu<<<N_, 128, 0, stream>>>(s2, s, ln_g + l*128, ln_b + l*128);
    zero(ssum, (long)G_*128);
    k_ssum_csr<<<dim3(G_, 8), 128, 0, stream>>>(s, bends, ssum);
    k_small_mlp2<<<8, 256, 0, stream>>>(ssum, n2v_w1, n2v_b1, n2v_w2, n2v_b2, vn, 1);
  }

  // ---- readout ----
  zero(addp, (long)G_*256);
  k_scatter_nf2<<<N_/32, 256, 0, stream>>>(s, v, batch, addp);
  k_build_g<<<(G_*640 + 255)/256, 256, 0, stream>>>(addp, bends, vn, gbuf);
  k_head<<<G_, 128, 0, stream>>>(gbuf, head_w1, head_b1, head_w2, head_b2, out);
}

// Round 17
// 759.268 us; speedup vs baseline: 1.1948x; 1.0629x over previous
//
#include <hip/hip_runtime.h>
#include <math.h>

// ---- problem constants (from reference) ----
#define N_   8192
#define E_   131072
#define T_   262144
#define H_   128
#define IND_ 64
#define G_   32
#define L_   2

// generic fp32 GEMM tiling (node_in only)
#define CW 64
#define RB 16

// MFMA fused MLP tiling
#define MROWS 32     // rows per wave (reducer/GEMM kernels)
#define HSTRIDE 136  // LDS hidden row stride (bf16 elems)
#define WSTRIDE 36   // LDS weight col stride (bf16 elems) - spreads banks

// RBF constants
#define STEP_E  ((float)(5.0/31.0))
#define GAMMA_E ((float)(1.0/(2.0*((5.0/31.0)*(5.0/31.0) + 1e-12))))
#define PI_D    3.14159265358979323846
#define STEP_A  ((float)(PI_D/15.0))
#define GAMMA_A ((float)(1.0/(2.0*((PI_D/15.0)*(PI_D/15.0) + 1e-12))))

typedef __attribute__((ext_vector_type(8))) short short8;
typedef __attribute__((ext_vector_type(4))) float f32x4;
typedef unsigned short ushort_t;

static __device__ __forceinline__ float silu_f(float x){ return x / (1.f + expf(-x)); }
static __device__ __forceinline__ float sigmoid_f(float x){ return 1.f / (1.f + expf(-x)); }

static __device__ __forceinline__ ushort_t f2bf(float x){
  unsigned int u = __builtin_bit_cast(unsigned int, x);
  u += 0x7FFFu + ((u >> 16) & 1u);
  return (ushort_t)(u >> 16);
}
static __device__ __forceinline__ float bf2f(ushort_t h){
  unsigned int u = ((unsigned int)h) << 16;
  return __builtin_bit_cast(float, u);
}

// ---------------- small utility kernels ----------------

__global__ void k_zero(float* __restrict__ p, long n){
  long stride = (long)gridDim.x*256;
  long n4 = n >> 2;
  float4* p4 = (float4*)p;
  for (long i = (long)blockIdx.x*256 + threadIdx.x; i < n4; i += stride)
    p4[i] = make_float4(0.f,0.f,0.f,0.f);
  for (long i = (n4<<2) + (long)blockIdx.x*256 + threadIdx.x; i < n; i += stride)
    p[i] = 0.f;
}

__global__ void k_sentinel(float* __restrict__ p, int n){
  int i = blockIdx.x*256 + threadIdx.x;
  if (i < n) p[i] = 1.0e30f;
}

__global__ void k_init_vn(float* __restrict__ vn, const float* __restrict__ vn_init){
  int i = blockIdx.x*256 + threadIdx.x;
  if (i < G_*H_) vn[i] = vn_init[i & 127];
}

// batch segment ENDS via binary search over the SORTED batch array:
// bends[g] = first index where batch[i] > g. One wavefront, no atomics
// (R16 lesson: 8192 device-scope atomics on 32 counters cost 53 us).
__global__ void k_bends(const int* __restrict__ batch, int* __restrict__ bends){
  int g = threadIdx.x;
  if (g >= G_) return;
  int lo = 0, hi = N_;
  while (lo < hi){
    int mid = (lo + hi) >> 1;
    if (batch[mid] <= g) lo = mid + 1; else hi = mid;
  }
  bends[g] = lo;
}

// ---- fused weight convert+transpose for ALL weights of one layer ----
__global__ void k_wt_all(const float* __restrict__ tm_w1, const float* __restrict__ tm_w2,
                         const float* __restrict__ mm_w1, const float* __restrict__ mm_w2,
                         const float* __restrict__ us_w1, const float* __restrict__ us_w2,
                         const float* __restrict__ gv_w1, const float* __restrict__ gv_w2,
                         ushort_t* __restrict__ wtbuf){
  const int l = blockIdx.y;
  int i = blockIdx.x*256 + threadIdx.x;
  if (i >= 245760) return;
  ushort_t* base = wtbuf + (size_t)l*376832;
  if (i < 12288){                    // tm1: K=80, C=128, Kpad=96 (hi only)
    int c = i/96, k = i%96;
    base[i] = (k < 80) ? f2bf(tm_w1[(size_t)l*10240 + (size_t)k*128 + c]) : (ushort_t)0;
  } else if (i < 28672){             // tm2: 128x128 (hi only)
    int j = i - 12288; int c = j >> 7, k = j & 127;
    base[12288 + j] = f2bf(tm_w2[(size_t)l*16384 + (size_t)k*128 + c]);
  } else if (i < 81920){             // mm1: K=416, C=128 (hi only)
    int j = i - 28672; int c = j/416, k = j%416;
    base[28672 + j] = f2bf(mm_w1[(size_t)l*53248 + (size_t)k*128 + c]);
  } else if (i < 114688){            // mm2: K=128, C=256 (hi only)
    int j = i - 81920; int c = j >> 7, k = j & 127;
    base[81920 + j] = f2bf(mm_w2[(size_t)l*32768 + (size_t)k*256 + c]);
  } else if (i < 163840){            // us1: K=384, C=128 (hi+lo)
    int j = i - 114688; int c = j/384, k = j%384;
    float w = us_w1[(size_t)l*49152 + (size_t)k*128 + c];
    ushort_t h = f2bf(w);
    base[114688 + j] = h; base[163840 + j] = f2bf(w - bf2f(h));
  } else if (i < 180224){            // us2: 128x128 (hi+lo)
    int j = i - 163840; int c = j >> 7, k = j & 127;
    float w = us_w2[(size_t)l*16384 + (size_t)k*128 + c];
    ushort_t h = f2bf(w);
    base[212992 + j] = h; base[229376 + j] = f2bf(w - bf2f(h));
  } else if (i < 229376){            // gv1: K=384, C=128 (hi+lo)
    int j = i - 180224; int c = j/384, k = j%384;
    float w = gv_w1[(size_t)l*49152 + (size_t)k*128 + c];
    ushort_t h = f2bf(w);
    base[245760 + j] = h; base[294912 + j] = f2bf(w - bf2f(h));
  } else {                           // gv2: 128x128 (hi+lo)
    int j = i - 229376; int c = j >> 7, k = j & 127;
    float w = gv_w2[(size_t)l*16384 + (size_t)k*128 + c];
    ushort_t h = f2bf(w);
    base[344064 + j] = h; base[360448 + j] = f2bf(w - bf2f(h));
  }
}

// per-edge: vec, dir, edge RBF(32) in bf16
__global__ void k_geom(const float* __restrict__ pos, const float* __restrict__ dist,
                       const int* __restrict__ ei,
                       float* __restrict__ vec, float* __restrict__ dir,
                       ushort_t* __restrict__ rbf16){
  int e = blockIdx.x*256 + threadIdx.x;
  if (e >= E_) return;
  int s = ei[e], d = ei[E_ + e];
  float vx = pos[d*3+0] - pos[s*3+0];
  float vy = pos[d*3+1] - pos[s*3+1];
  float vz = pos[d*3+2] - pos[s*3+2];
  vec[e*3+0]=vx; vec[e*3+1]=vy; vec[e*3+2]=vz;
  float dd = dist[e];
  float inv = 1.f / (dd + 1e-9f);
  dir[e*3+0]=vx*inv; dir[e*3+1]=vy*inv; dir[e*3+2]=vz*inv;
  #pragma unroll
  for (int i=0;i<32;i++){
    float df = dd - i*STEP_E;
    rbf16[e*32+i] = f2bf(expf(-GAMMA_E*df*df));
  }
}

// gather dir into sorted-edge order: dir_s[p] = dir[perm_e[p]]
__global__ void k_dirs(const float* __restrict__ dir, const int* __restrict__ perm_e,
                       float* __restrict__ dir_s){
  int p = blockIdx.x*256 + threadIdx.x;
  if (p >= E_) return;
  int e = perm_e[p];
  dir_s[p*3+0] = dir[e*3+0];
  dir_s[p*3+1] = dir[e*3+1];
  dir_s[p*3+2] = dir[e*3+2];
}

// per-triplet angle
__global__ void k_angle(const float* __restrict__ vec,
                        const int* __restrict__ kj, const int* __restrict__ ji,
                        float* __restrict__ angle){
  int t = blockIdx.x*256 + threadIdx.x;
  if (t >= T_) return;
  int ea = ji[t], eb = kj[t];
  float ax=vec[ea*3+0], ay=vec[ea*3+1], az=vec[ea*3+2];
  float bx=vec[eb*3+0], by=vec[eb*3+1], bz=vec[eb*3+2];
  float dot = ax*bx + ay*by + az*bz;
  float na = sqrtf(ax*ax+ay*ay+az*az + 1e-12f);
  float nb = sqrtf(bx*bx+by*by+bz*bz + 1e-12f);
  float c = dot / (na*nb + 1e-9f);
  c = fminf(fmaxf(c, -1.f + 1e-7f), 1.f - 1e-7f);
  angle[t] = acosf(c);
}

// ---------------- counting-sort kernels ----------------

__global__ void k_hist(const int* __restrict__ keys, int M, int* __restrict__ hist){
  int i = blockIdx.x*256 + threadIdx.x;
  if (i < M) atomicAdd(&hist[keys[i]], 1);
}

__global__ void k_hist2(const int* __restrict__ keys, const int* __restrict__ map,
                        int M, int* __restrict__ hist){
  int i = blockIdx.x*256 + threadIdx.x;
  if (i < M) atomicAdd(&hist[map[keys[i]]], 1);
}

__global__ void k_scan1(const int* __restrict__ in, int* __restrict__ out,
                        int* __restrict__ sums, int B){
  __shared__ int sh[1024];
  int base = blockIdx.x*1024, t = threadIdx.x;
  for (int j=t;j<1024;j+=256) sh[j] = (base+j<B) ? in[base+j] : 0;
  __syncthreads();
  for (int o=1;o<1024;o<<=1){
    int v[4];
    #pragma unroll
    for (int q=0;q<4;q++){ int idx=t+q*256; v[q]=(idx>=o)? sh[idx-o]:0; }
    __syncthreads();
    #pragma unroll
    for (int q=0;q<4;q++){ int idx=t+q*256; sh[idx]+=v[q]; }
    __syncthreads();
  }
  for (int j=t;j<1024;j+=256) if (base+j<B) out[base+j] = (j==0)?0:sh[j-1];
  if (t==0) sums[blockIdx.x] = sh[1023];
}

__global__ void k_scan2(int* __restrict__ sums, int nb){
  if (threadIdx.x==0 && blockIdx.x==0){
    int a=0;
    for (int i=0;i<nb;i++){ int x=sums[i]; sums[i]=a; a+=x; }
  }
}

__global__ void k_scan3(int* __restrict__ out, const int* __restrict__ sums, int B){
  int i = blockIdx.x*256+threadIdx.x;
  if (i<B) out[i] += sums[i>>10];
}

__global__ void k_fill(const int* __restrict__ keys, int M, int* __restrict__ cur,
                       int* __restrict__ perm){
  int i = blockIdx.x*256+threadIdx.x;
  if (i<M){ int p = atomicAdd(&cur[keys[i]],1); perm[p]=i; }
}

__global__ void k_fill2(const int* __restrict__ keys, const int* __restrict__ map,
                        int M, int* __restrict__ cur, int* __restrict__ perm){
  int i = blockIdx.x*256+threadIdx.x;
  if (i<M){ int p = atomicAdd(&cur[map[keys[i]]],1); perm[p]=i; }
}

__global__ void k_invert(const int* __restrict__ perm, int* __restrict__ rank, int M){
  int i = blockIdx.x*256+threadIdx.x;
  if (i<M) rank[perm[i]] = i;
}

// ---------------- MFMA first-layer MLP (4-wave block, 16 rows/wave) ----------------
// 256 threads = 4 waves, each wave owns 16 rows (64 rows/block). Per 32-k chunk:
// the chunk's GATHER load is issued FIRST (latency overlaps the weight staging +
// barrier), then the W1 slice is cooperatively staged in LDS, then MFMA.
// acc is only 32 regs/lane -> no register squeeze at 4+ blocks/CU
// (R15 lesson: occupancy bought with reg pressure sinks the gathers).
template<int SM, int K1PAD>
__launch_bounds__(256, 4)
__global__ void k_mlp1(
    const int* __restrict__ perm,
    const int* __restrict__ idx1, const int* __restrict__ idx2,
    const ushort_t* __restrict__ rbf16, const float* __restrict__ angle,
    const ushort_t* __restrict__ s16, const ushort_t* __restrict__ eagg_in,
    const ushort_t* __restrict__ W1t, const float* __restrict__ b1,
    ushort_t* __restrict__ outbuf)
{
  __shared__ ushort_t lw[128*WSTRIDE];       // 9216 B weight chunk
  __shared__ ushort_t hid[4][16*HSTRIDE];    // 17408 B (per-wave staging)  -> 26.6 KB total
  const int tid  = threadIdx.x;
  const int wave = tid >> 6;
  const int lane = tid & 63;
  const int n    = lane & 15;
  const int quad = lane >> 4;
  const int kq   = quad*8;
  const int wrow = blockIdx.x*64 + wave*16;
  const int row  = wrow + n;

  const int e0 = perm[row];
  int i1a = idx1[e0];
  int i2a = idx2[e0];
  float ang0 = 0.f;
  if (SM == 1){ ang0 = angle[e0]; }

  f32x4 acc[8];
  #pragma unroll
  for (int ct=0;ct<8;ct++) acc[ct] = (f32x4){0.f,0.f,0.f,0.f};

  #pragma unroll
  for (int k0 = 0; k0 < K1PAD; k0 += 32){
    // ---- issue this chunk's gather load FIRST (overlap with staging+barrier) ----
    short8 a0;
    if (SM == 1){
      if (k0 == 0){
        a0 = *(const short8*)&rbf16[(size_t)i1a*32 + kq];
      } else if (k0 == 32){
        a0 = *(const short8*)&rbf16[(size_t)i2a*32 + kq];
      } else {
        #pragma unroll
        for (int j=0;j<8;j++){
          int kk = kq + j;
          float v0 = 0.f;
          if (kk < 16){
            float c = (float)kk*STEP_A;
            float d0 = ang0 - c;
            v0 = expf(-GAMMA_A*d0*d0);
          }
          a0[j] = (short)f2bf(v0);
        }
      }
    } else {
      const int k = k0 + kq;
      if (k0 < 128){
        a0 = *(const short8*)&s16[(size_t)i1a*128 + k];
      } else if (k0 < 256){
        a0 = *(const short8*)&s16[(size_t)i2a*128 + (k-128)];
      } else if (k0 < 288){
        a0 = *(const short8*)&rbf16[(size_t)e0*32 + (k-256)];
      } else {
        // eagg (post-W2) bf16 in sorted-edge-position order -> sequential rows
        a0 = *(const short8*)&eagg_in[(size_t)row*128 + (k-288)];
      }
    }

    // ---- cooperative stage of the 128x32 weight slice (hi only) ----
    #pragma unroll
    for (int it=0; it<2; it++){
      int idx = tid + it*256;           // 0..511
      int col = idx >> 2, seg = idx & 3;
      *(short8*)&lw[col*WSTRIDE + seg*8] = *(const short8*)&W1t[(size_t)col*K1PAD + k0 + seg*8];
    }
    __syncthreads();

    #pragma unroll
    for (int ct=0;ct<8;ct++){
      short8 b = *(const short8*)&lw[(ct*16 + n)*WSTRIDE + kq];
      acc[ct] = __builtin_amdgcn_mfma_f32_16x16x32_bf16(a0, b, acc[ct], 0,0,0);
    }
    __syncthreads();
  }

  // bias + silu -> LDS staging (wave-private), then coalesced 16B stores
  #pragma unroll
  for (int ct=0;ct<8;ct++){
    int col = ct*16 + n;
    float bv = b1[col];
    #pragma unroll
    for (int reg=0;reg<4;reg++){
      int rloc = quad*4 + reg;
      float h = acc[ct][reg] + bv;
      hid[wave][rloc*HSTRIDE + col] = f2bf(silu_f(h));
    }
  }
  const int rsub = lane >> 4;
  const int c8   = (lane & 15) * 8;
  #pragma unroll
  for (int i=0;i<4;i++){
    int rloc = i*4 + rsub;
    int grow = wrow + rloc;
    short8 vv = *(const short8*)&hid[wave][(size_t)rloc*HSTRIDE + c8];
    *(short8*)&outbuf[(size_t)grow*128 + c8] = vv;
  }
}

// ---------------- FUSED triplet aggregate + W2 GEMM ----------------
__launch_bounds__(64, 4)
__global__ void k_aggemm_t(const ushort_t* __restrict__ tmsg, const int* __restrict__ tends,
                           const ushort_t* __restrict__ W2t, const float* __restrict__ b2,
                           ushort_t* __restrict__ eagg2){
  __shared__ ushort_t hid[MROWS*HSTRIDE];
  const int lane = threadIdx.x;
  const int n    = lane & 15;
  const int quad = lane >> 4;
  const int kq   = quad*8;
  const int wrow = blockIdx.x*MROWS;
  const int r0 = wrow + n, r1 = wrow + 16 + n;
  const int s0 = r0 ? tends[r0-1] : 0;
  const int e0 = tends[r0];
  const int s1 = tends[r1-1];
  const int e1 = tends[r1];

  f32x4 acc[2][8];
  #pragma unroll
  for (int rh=0;rh<2;rh++)
    #pragma unroll
    for (int ct=0;ct<8;ct++) acc[rh][ct] = (f32x4){0.f,0.f,0.f,0.f};

  #pragma unroll
  for (int k0=0;k0<128;k0+=32){
    float sum0[8], sum1[8];
    #pragma unroll
    for (int j=0;j<8;j++){ sum0[j]=0.f; sum1[j]=0.f; }
    for (int p=s0;p<e0;p++){
      short8 w = *(const short8*)&tmsg[(size_t)p*128 + k0 + kq];
      #pragma unroll
      for (int j=0;j<8;j++) sum0[j] += bf2f((ushort_t)w[j]);
    }
    for (int p=s1;p<e1;p++){
      short8 w = *(const short8*)&tmsg[(size_t)p*128 + k0 + kq];
      #pragma unroll
      for (int j=0;j<8;j++) sum1[j] += bf2f((ushort_t)w[j]);
    }
    short8 a0, a1;
    #pragma unroll
    for (int j=0;j<8;j++){
      a0[j] = (short)f2bf(sum0[j]);
      a1[j] = (short)f2bf(sum1[j]);
    }
    #pragma unroll
    for (int ct=0;ct<8;ct++){
      short8 b = *(const short8*)&W2t[(size_t)(ct*16 + n)*128 + k0 + kq];
      acc[0][ct] = __builtin_amdgcn_mfma_f32_16x16x32_bf16(a0, b, acc[0][ct], 0,0,0);
      acc[1][ct] = __builtin_amdgcn_mfma_f32_16x16x32_bf16(a1, b, acc[1][ct], 0,0,0);
    }
  }

  // per-row segment counts for the bias
  float cnts[2][4];
  #pragma unroll
  for (int rh=0;rh<2;rh++)
    #pragma unroll
    for (int reg=0;reg<4;reg++){
      int row = wrow + rh*16 + quad*4 + reg;
      cnts[rh][reg] = (float)(tends[row] - (row ? tends[row-1] : 0));
    }

  #pragma unroll
  for (int rh=0;rh<2;rh++){
    #pragma unroll
    for (int ct=0;ct<8;ct++){
      int col = ct*16 + n;
      float bv = b2[col];
      #pragma unroll
      for (int reg=0;reg<4;reg++){
        int rloc = rh*16 + quad*4 + reg;
        hid[rloc*HSTRIDE + col] = f2bf(acc[rh][ct][reg] + cnts[rh][reg]*bv);
      }
    }
  }
  const int rsub = lane >> 4;
  const int c8   = (lane & 15) * 8;
  #pragma unroll
  for (int i=0;i<8;i++){
    int rloc = i*4 + rsub;
    int grow = wrow + rloc;
    short8 vv = *(const short8*)&hid[(size_t)rloc*HSTRIDE + c8];
    *(short8*)&eagg2[(size_t)grow*128 + c8] = vv;
  }
}

// edge moment reducer
__global__ void k_agg_e(const ushort_t* __restrict__ hbuf, const int* __restrict__ eends,
                        const float* __restrict__ dir_s, float* __restrict__ mom){
  int i = blockIdx.x*256 + threadIdx.x;
  int d = i >> 6, c2 = (i & 63)*2;
  if (d >= N_) return;
  int s = (d == 0) ? 0 : eends[d-1];
  int e = eends[d];
  float hs0=0.f,hs1=0.f, hx0=0.f,hx1=0.f, hy0=0.f,hy1=0.f, hz0=0.f,hz1=0.f;
  float sdx=0.f, sdy=0.f, sdz=0.f;
  for (int q=s;q<e;q++){
    unsigned int w = *(const unsigned int*)&hbuf[(size_t)q*128 + c2];
    float h0 = bf2f((ushort_t)(w & 0xFFFFu));
    float h1 = bf2f((ushort_t)(w >> 16));
    float dx = dir_s[q*3+0], dy = dir_s[q*3+1], dz = dir_s[q*3+2];
    hs0 += h0; hs1 += h1;
    hx0 += h0*dx; hx1 += h1*dx;
    hy0 += h0*dy; hy1 += h1*dy;
    hz0 += h0*dz; hz1 += h1*dz;
    sdx += dx; sdy += dy; sdz += dz;
  }
  size_t base = (size_t)d*128 + c2;
  *(float2*)&mom[base]                        = make_float2(hs0, hs1);
  *(float2*)&mom[(size_t)N_*128   + base]     = make_float2(hx0, hx1);
  *(float2*)&mom[(size_t)N_*256   + base]     = make_float2(hy0, hy1);
  *(float2*)&mom[(size_t)N_*384   + base]     = make_float2(hz0, hz1);
  if (c2 == 0){
    mom[(size_t)N_*512 + d*4+0] = sdx;
    mom[(size_t)N_*512 + d*4+1] = sdy;
    mom[(size_t)N_*512 + d*4+2] = sdz;
  }
}

// edge: moment GEMM per og = blockIdx.y (0: Ms -> a16 + vn; 1..3: Mx/My/Mz -> aggv plane).
__launch_bounds__(64, 4)
__global__ void k_gemm_e(const float* __restrict__ mom, const int* __restrict__ eends,
                         const ushort_t* __restrict__ W2t /*[256][128]*/,
                         const float* __restrict__ b2 /*[256]*/,
                         const float* __restrict__ v /*[3][N][128]*/,
                         ushort_t* __restrict__ a16h, ushort_t* __restrict__ a16l,
                         ushort_t* __restrict__ vnh,  ushort_t* __restrict__ vnl,
                         float* __restrict__ aggv /*[3][N][128]*/){
  __shared__ float sbuf[MROWS*130];   // 16640 B staging
  const int lane = threadIdx.x;
  const int n    = lane & 15;
  const int quad = lane >> 4;
  const int kq   = quad*8;
  const int wrow = blockIdx.x*MROWS;
  const int og   = blockIdx.y;

  const float* M = mom + (size_t)og*((size_t)N_*128);
  const ushort_t* W = W2t + (og ? (size_t)128*128 : 0);

  f32x4 acc[2][8];
  #pragma unroll
  for (int rh=0;rh<2;rh++)
    #pragma unroll
    for (int ct=0;ct<8;ct++) acc[rh][ct] = (f32x4){0.f,0.f,0.f,0.f};

  #pragma unroll
  for (int k0=0;k0<128;k0+=32){
    const int k = k0 + kq;
    const float* p0 = &M[(size_t)(wrow + n)*128 + k];
    const float* p1 = &M[(size_t)(wrow + 16 + n)*128 + k];
    f32x4 x0 = *(const f32x4*)p0, x1 = *(const f32x4*)(p0+4);
    f32x4 y0 = *(const f32x4*)p1, y1 = *(const f32x4*)(p1+4);
    short8 ah0, al0, ah1, al1;
    #pragma unroll
    for (int j=0;j<4;j++){
      ushort_t h;
      h = f2bf(x0[j]); ah0[j]   = (short)h; al0[j]   = (short)f2bf(x0[j] - bf2f(h));
      h = f2bf(x1[j]); ah0[4+j] = (short)h; al0[4+j] = (short)f2bf(x1[j] - bf2f(h));
      h = f2bf(y0[j]); ah1[j]   = (short)h; al1[j]   = (short)f2bf(y0[j] - bf2f(h));
      h = f2bf(y1[j]); ah1[4+j] = (short)h; al1[4+j] = (short)f2bf(y1[j] - bf2f(h));
    }
    #pragma unroll
    for (int ct=0;ct<8;ct++){
      short8 b = *(const short8*)&W[(size_t)(ct*16 + n)*128 + k0 + kq];
      acc[0][ct] = __builtin_amdgcn_mfma_f32_16x16x32_bf16(ah0, b, acc[0][ct], 0,0,0);
      acc[0][ct] = __builtin_amdgcn_mfma_f32_16x16x32_bf16(al0, b, acc[0][ct], 0,0,0);
      acc[1][ct] = __builtin_amdgcn_mfma_f32_16x16x32_bf16(ah1, b, acc[1][ct], 0,0,0);
      acc[1][ct] = __builtin_amdgcn_mfma_f32_16x16x32_bf16(al1, b, acc[1][ct], 0,0,0);
    }
  }

  const int rsub = lane >> 4;
  const int c8   = (lane & 15) * 8;

  if (og == 0){
    float cnts[2][4];
    #pragma unroll
    for (int rh=0;rh<2;rh++)
      #pragma unroll
      for (int reg=0;reg<4;reg++){
        int row = wrow + rh*16 + quad*4 + reg;
        cnts[rh][reg] = (float)(eends[row] - (row ? eends[row-1] : 0));
      }
    ushort_t* us = (ushort_t*)sbuf;
    // pass 1: hi
    #pragma unroll
    for (int rh=0;rh<2;rh++)
      #pragma unroll
      for (int ct=0;ct<8;ct++){
        int col = ct*16 + n;
        float bv = b2[col];
        #pragma unroll
        for (int reg=0;reg<4;reg++){
          int rloc = rh*16 + quad*4 + reg;
          float val = acc[rh][ct][reg] + cnts[rh][reg]*bv;
          us[rloc*HSTRIDE + col] = f2bf(val);
        }
      }
    #pragma unroll
    for (int i=0;i<8;i++){
      int rloc = i*4 + rsub;
      short8 vv = *(const short8*)&us[(size_t)rloc*HSTRIDE + c8];
      *(short8*)&a16h[(size_t)(wrow + rloc)*128 + c8] = vv;
    }
    // pass 2: lo
    #pragma unroll
    for (int rh=0;rh<2;rh++)
      #pragma unroll
      for (int ct=0;ct<8;ct++){
        int col = ct*16 + n;
        float bv = b2[col];
        #pragma unroll
        for (int reg=0;reg<4;reg++){
          int rloc = rh*16 + quad*4 + reg;
          float val = acc[rh][ct][reg] + cnts[rh][reg]*bv;
          ushort_t h = f2bf(val);
          us[rloc*HSTRIDE + col] = f2bf(val - bf2f(h));
        }
      }
    #pragma unroll
    for (int i=0;i<8;i++){
      int rloc = i*4 + rsub;
      short8 vv = *(const short8*)&us[(size_t)rloc*HSTRIDE + c8];
      *(short8*)&a16l[(size_t)(wrow + rloc)*128 + c8] = vv;
    }
    // vn norms, linear sweep (planar v)
    #pragma unroll 4
    for (int j=0;j<32;j++){
      size_t idx = (size_t)wrow*128 + (size_t)j*128 + lane*2;
      float2 a = *(const float2*)&v[idx];
      float2 b = *(const float2*)&v[(size_t)N_*128 + idx];
      float2 c = *(const float2*)&v[(size_t)N_*256 + idx];
      float n0 = sqrtf(a.x*a.x + b.x*b.x + c.x*c.x + 1e-12f);
      float n1 = sqrtf(a.y*a.y + b.y*b.y + c.y*c.y + 1e-12f);
      ushort_t h0 = f2bf(n0), h1 = f2bf(n1);
      *(unsigned int*)&vnh[idx] = (unsigned int)h0 | ((unsigned int)h1 << 16);
      *(unsigned int*)&vnl[idx] = (unsigned int)f2bf(n0 - bf2f(h0))
                                | ((unsigned int)f2bf(n1 - bf2f(h1)) << 16);
    }
  } else {
    const int x = og - 1;
    #pragma unroll
    for (int rh=0;rh<2;rh++)
      #pragma unroll
      for (int ct=0;ct<8;ct++){
        int col = ct*16 + n;
        float bv = b2[128 + col];
        #pragma unroll
        for (int reg=0;reg<4;reg++){
          int rloc = rh*16 + quad*4 + reg;
          int row = wrow + rloc;
          float sd = mom[(size_t)N_*512 + row*4 + x];
          sbuf[rloc*130 + col] = acc[rh][ct][reg] + sd*bv;
        }
      }
    float* plane = aggv + (size_t)x*((size_t)N_*128);
    #pragma unroll
    for (int i=0;i<8;i++){
      int rloc = i*4 + rsub;
      f32x4 v0 = *(const f32x4*)&sbuf[rloc*130 + c8];
      f32x4 v1 = *(const f32x4*)&sbuf[rloc*130 + c8 + 4];
      *(f32x4*)&plane[(size_t)(wrow + rloc)*128 + c8] = v0;
      *(f32x4*)&plane[(size_t)(wrow + rloc)*128 + c8 + 4] = v1;
    }
  }
}

// ---------------- MFMA node-update kernel (4-wave block, LDS-shared weights) ----------------
__launch_bounds__(256, 3)
__global__ void k_node_mfma(
    const float* __restrict__ s_in,
    const ushort_t* __restrict__ a16h, const ushort_t* __restrict__ a16l,
    const ushort_t* __restrict__ vnh,  const ushort_t* __restrict__ vnl,
    float* __restrict__ s2, float* __restrict__ v_out /*[3][N][128]*/,
    const float* __restrict__ aggv /*[3][N][128]*/,
    const ushort_t* __restrict__ us1h, const ushort_t* __restrict__ us1l, const float* __restrict__ us_b1,
    const ushort_t* __restrict__ us2h, const ushort_t* __restrict__ us2l, const float* __restrict__ us_b2,
    const ushort_t* __restrict__ gv1h, const ushort_t* __restrict__ gv1l, const float* __restrict__ gv_b1,
    const ushort_t* __restrict__ gv2h, const ushort_t* __restrict__ gv2l, const float* __restrict__ gv_b2)
{
  __shared__ ushort_t lwh[128*WSTRIDE];       // 9216 B weight chunk (hi)
  __shared__ ushort_t lwl[128*WSTRIDE];       // 9216 B weight chunk (lo)
  __shared__ ushort_t hidh[4][16*HSTRIDE];    // 17408 B
  __shared__ ushort_t hidl[4][16*HSTRIDE];    // 17408 B  (total 53248 B)
  const int tid  = threadIdx.x;
  const int wave = tid >> 6;
  const int lane = tid & 63;
  const int n    = lane & 15;
  const int quad = lane >> 4;
  const int kq   = quad*8;
  const int og   = blockIdx.y;
  const int wrow = blockIdx.x*64 + wave*16;
  const int r0 = wrow + n;

  const ushort_t* W1h = og ? gv1h : us1h;
  const ushort_t* W1l = og ? gv1l : us1l;
  const float*    B1  = og ? gv_b1 : us_b1;
  const ushort_t* W2h = og ? gv2h : us2h;
  const ushort_t* W2l = og ? gv2l : us2l;
  const float*    B2  = og ? gv_b2 : us_b2;

  // ---------- phase A ----------
  f32x4 acc[8];
  #pragma unroll
  for (int ct=0;ct<8;ct++) acc[ct] = (f32x4){0.f,0.f,0.f,0.f};

  #pragma unroll
  for (int k0=0; k0<384; k0+=32){
    #pragma unroll
    for (int it = 0; it < 2; it++){
      int idx = tid + it*256;          // 0..511
      int col = idx >> 2, seg = idx & 3;
      *(short8*)&lwh[col*WSTRIDE + seg*8] = *(const short8*)&W1h[(size_t)col*384 + k0 + seg*8];
      *(short8*)&lwl[col*WSTRIDE + seg*8] = *(const short8*)&W1l[(size_t)col*384 + k0 + seg*8];
    }
    __syncthreads();

    short8 ah0, al0;
    const int k = k0 + kq;
    if (k0 < 128){
      const float* p0 = &s_in[(size_t)r0*128 + k];
      f32x4 x0 = *(const f32x4*)p0, x1 = *(const f32x4*)(p0+4);
      #pragma unroll
      for (int j=0;j<4;j++){
        ushort_t h;
        h = f2bf(x0[j]); ah0[j]   = (short)h; al0[j]   = (short)f2bf(x0[j] - bf2f(h));
        h = f2bf(x1[j]); ah0[4+j] = (short)h; al0[4+j] = (short)f2bf(x1[j] - bf2f(h));
      }
    } else if (k0 < 256){
      int kk = k - 128;
      ah0 = *(const short8*)&a16h[(size_t)r0*128 + kk];
      al0 = *(const short8*)&a16l[(size_t)r0*128 + kk];
    } else {
      int kk = k - 256;
      ah0 = *(const short8*)&vnh[(size_t)r0*128 + kk];
      al0 = *(const short8*)&vnl[(size_t)r0*128 + kk];
    }
    #pragma unroll
    for (int ct=0;ct<8;ct++){
      short8 bh = *(const short8*)&lwh[(ct*16 + n)*WSTRIDE + kq];
      short8 bl = *(const short8*)&lwl[(ct*16 + n)*WSTRIDE + kq];
      acc[ct] = __builtin_amdgcn_mfma_f32_16x16x32_bf16(ah0, bh, acc[ct], 0,0,0);
      acc[ct] = __builtin_amdgcn_mfma_f32_16x16x32_bf16(al0, bh, acc[ct], 0,0,0);
      acc[ct] = __builtin_amdgcn_mfma_f32_16x16x32_bf16(ah0, bl, acc[ct], 0,0,0);
    }
    __syncthreads();
  }

  #pragma unroll
  for (int ct=0;ct<8;ct++){
    int col = ct*16 + n;
    float bv = B1[col];
    #pragma unroll
    for (int reg=0;reg<4;reg++){
      int rloc = quad*4 + reg;
      float h = silu_f(acc[ct][reg] + bv);
      ushort_t hh = f2bf(h);
      hidh[wave][rloc*HSTRIDE + col] = hh;
      hidl[wave][rloc*HSTRIDE + col] = f2bf(h - bf2f(hh));
    }
  }

  // ---------- phase B ----------
  f32x4 acc2[8];
  #pragma unroll
  for (int ct=0;ct<8;ct++) acc2[ct] = (f32x4){0.f,0.f,0.f,0.f};

  #pragma unroll
  for (int k0=0;k0<128;k0+=32){
    #pragma unroll
    for (int it = 0; it < 2; it++){
      int idx = tid + it*256;
      int col = idx >> 2, seg = idx & 3;
      *(short8*)&lwh[col*WSTRIDE + seg*8] = *(const short8*)&W2h[(size_t)col*128 + k0 + seg*8];
      *(short8*)&lwl[col*WSTRIDE + seg*8] = *(const short8*)&W2l[(size_t)col*128 + k0 + seg*8];
    }
    __syncthreads();

    short8 ah0 = *(const short8*)&hidh[wave][(size_t)(n)*HSTRIDE + k0 + kq];
    short8 al0 = *(const short8*)&hidl[wave][(size_t)(n)*HSTRIDE + k0 + kq];
    #pragma unroll
    for (int ct=0;ct<8;ct++){
      short8 bh = *(const short8*)&lwh[(ct*16 + n)*WSTRIDE + kq];
      short8 bl = *(const short8*)&lwl[(ct*16 + n)*WSTRIDE + kq];
      acc2[ct] = __builtin_amdgcn_mfma_f32_16x16x32_bf16(ah0, bh, acc2[ct], 0,0,0);
      acc2[ct] = __builtin_amdgcn_mfma_f32_16x16x32_bf16(al0, bh, acc2[ct], 0,0,0);
      acc2[ct] = __builtin_amdgcn_mfma_f32_16x16x32_bf16(ah0, bl, acc2[ct], 0,0,0);
    }
    __syncthreads();
  }

  if (og == 0){
    #pragma unroll
    for (int ct=0;ct<8;ct++){
      int col = ct*16 + n;
      float bv = B2[col];
      #pragma unroll
      for (int reg=0;reg<4;reg++){
        int row = wrow + quad*4 + reg;
        size_t idx = (size_t)row*128 + col;
        s2[idx] = s_in[idx] + acc2[ct][reg] + bv;
      }
    }
  } else {
    #pragma unroll
    for (int ct=0;ct<8;ct++){
      int col = ct*16 + n;
      float bv = B2[col];
      #pragma unroll
      for (int reg=0;reg<4;reg++){
        int row = wrow + quad*4 + reg;
        size_t idx = (size_t)row*128 + col;
        float g = sigmoid_f(acc2[ct][reg] + bv);
        v_out[idx]                    += g*aggv[idx];
        v_out[(size_t)N_*128 + idx]   += g*aggv[(size_t)N_*128 + idx];
        v_out[(size_t)N_*256 + idx]   += g*aggv[(size_t)N_*256 + idx];
      }
    }
  }
}

// ---------------- generic fp32 row-MLP GEMM (node_in only) ----------------
__launch_bounds__(128)
__global__ void k_gemm(const float* __restrict__ A,
                       const float* __restrict__ W,
                       const float* __restrict__ bias,
                       float* __restrict__ C, int R, int K)
{
  __shared__ float ws[CW*128];
  __shared__ float as[RB][CW];
  const int tid = threadIdx.x;
  const int nchunk = (K + CW - 1) / CW;

  for (int rb = blockIdx.x*RB; rb < R; rb += gridDim.x*RB){
    float acc[RB];
    #pragma unroll
    for (int r=0;r<RB;r++) acc[r] = 0.f;

    for (int c=0;c<nchunk;c++){
      const int k0 = c*CW;
      for (int i=tid; i<CW*128; i+=128){
        int kk = i >> 7, col = i & 127;
        int k = k0 + kk;
        ws[i] = (k < K) ? W[k*128 + col] : 0.f;
      }
      for (int i=tid; i<RB*CW; i+=128){
        int r  = i >> 6, kk = i & 63;
        int k  = k0 + kk;
        as[r][kk] = (k < K) ? A[(long)(rb+r)*K + k] : 0.f;
      }
      __syncthreads();
      #pragma unroll 4
      for (int kq2=0; kq2<CW/4; kq2++){
        float w0 = ws[(4*kq2+0)*128 + tid];
        float w1 = ws[(4*kq2+1)*128 + tid];
        float w2 = ws[(4*kq2+2)*128 + tid];
        float w3 = ws[(4*kq2+3)*128 + tid];
        #pragma unroll
        for (int r=0;r<RB;r++){
          const float4 av = *reinterpret_cast<const float4*>(&as[r][4*kq2]);
          acc[r] = fmaf(av.x, w0, acc[r]);
          acc[r] = fmaf(av.y, w1, acc[r]);
          acc[r] = fmaf(av.z, w2, acc[r]);
          acc[r] = fmaf(av.w, w3, acc[r]);
        }
      }
      __syncthreads();
    }

    const float bv = bias[tid];
    #pragma unroll
    for (int r=0;r<RB;r++)
      C[(long)(rb+r)*128 + tid] = acc[r] + bv;
  }
}

// ---------------- small fused kernels ----------------

// G x 128 2-layer MLP, row-parallel: grid 8 blocks x 4 rows each.
__launch_bounds__(256)
__global__ void k_small_mlp2(const float* __restrict__ in,
                             const float* __restrict__ w1, const float* __restrict__ b1,
                             const float* __restrict__ w2, const float* __restrict__ b2,
                             float* __restrict__ outp, int accumulate){
  __shared__ float a[4][128];
  __shared__ float h[4][128];
  int tid = threadIdx.x;
  int rbase = blockIdx.x*4;
  for (int i=tid;i<4*128;i+=256) a[i>>7][i&127] = in[(rbase + (i>>7))*128 + (i&127)];
  __syncthreads();
  int col = tid & 127, rg = tid >> 7;   // rg 0..1 -> rows rg*2, rg*2+1
  float acc0=0.f, acc1=0.f;
  for (int k=0;k<128;k++){
    float w = w1[k*128+col];
    acc0 = fmaf(a[rg*2+0][k], w, acc0);
    acc1 = fmaf(a[rg*2+1][k], w, acc1);
  }
  {
    float bv = b1[col];
    h[rg*2+0][col] = silu_f(acc0+bv);
    h[rg*2+1][col] = silu_f(acc1+bv);
  }
  __syncthreads();
  acc0=0.f; acc1=0.f;
  for (int k=0;k<128;k++){
    float w = w2[k*128+col];
    acc0 = fmaf(h[rg*2+0][k], w, acc0);
    acc1 = fmaf(h[rg*2+1][k], w, acc1);
  }
  {
    float bv = b2[col];
    int idx0 = (rbase+rg*2+0)*128+col;
    int idx1 = (rbase+rg*2+1)*128+col;
    float v0 = acc0+bv, v1 = acc1+bv;
    outp[idx0] = accumulate ? outp[idx0]+v0 : v0;
    outp[idx1] = accumulate ? outp[idx1]+v1 : v1;
  }
}

__global__ void k_head(const float* __restrict__ gbuf,
                       const float* __restrict__ w1, const float* __restrict__ b1,
                       const float* __restrict__ w2, const float* __restrict__ b2,
                       float* __restrict__ outp){
  __shared__ float red[128];
  int g = blockIdx.x, tid = threadIdx.x;
  float acc = 0.f;
  for (int k=0;k<640;k++) acc = fmaf(gbuf[g*640+k], w1[k*128+tid], acc);
  float h = silu_f(acc + b1[tid]);
  red[tid] = h * w2[tid];
  __syncthreads();
  for (int o=64;o>0;o>>=1){ if (tid<o) red[tid]+=red[tid+o]; __syncthreads(); }
  if (tid == 0) outp[g] = red[0] + b2[0];
}

// ---------------- elementwise / reduction kernels ----------------

__global__ void k_sadd_batch(float* __restrict__ s, const float* __restrict__ t2,
                             const int* __restrict__ batch, ushort_t* __restrict__ s16){
  int i = blockIdx.x*256 + threadIdx.x;
  if (i >= N_*H_) return;
  int n = i >> 7, h = i & 127;
  float v = s[i] + t2[batch[n]*128 + h];
  s[i] = v;
  s16[i] = f2bf(v);
}

// LN + silu (no atomics)
__global__ void k_ln_silu(const float* __restrict__ in, float* __restrict__ outp,
                          const float* __restrict__ g, const float* __restrict__ b){
  __shared__ float red[128];
  int n = blockIdx.x, tid = threadIdx.x;
  float x = in[n*128 + tid];
  red[tid] = x; __syncthreads();
  for (int o=64;o>0;o>>=1){ if (tid<o) red[tid]+=red[tid+o]; __syncthreads(); }
  float mu = red[0] * (1.f/128.f);
  __syncthreads();
  float dx = x - mu;
  red[tid] = dx*dx; __syncthreads();
  for (int o=64;o>0;o>>=1){ if (tid<o) red[tid]+=red[tid+o]; __syncthreads(); }
  float var = red[0] * (1.f/128.f);
  float y = dx * rsqrtf(var + 1e-5f) * g[tid] + b[tid];
  outp[n*128 + tid] = silu_f(y);
}

// batch CSR segment-sum of s into ssum (ssum pre-zeroed)
__global__ void k_ssum_csr(const float* __restrict__ s, const int* __restrict__ bends,
                           float* __restrict__ ssum){
  int g = blockIdx.x, c = blockIdx.y, tid = threadIdx.x;
  int s0 = g ? bends[g-1] : 0;
  int e0 = bends[g];
  long len = e0 - s0;
  int lo = s0 + (int)((len*c) >> 3);
  int hi = s0 + (int)((len*(c+1)) >> 3);
  float a = 0.f;
  for (int n=lo; n<hi; n++) a += s[(size_t)n*128 + tid];
  if (hi > lo) atomicAdd(&ssum[g*128 + tid], a);
}

// readout scatter: per-block segmented accumulation over 32 sorted nodes
__global__ void k_scatter_nf2(const float* __restrict__ s, const float* __restrict__ v /*[3][N][128]*/,
                              const int* __restrict__ batch, float* __restrict__ addp){
  int j = threadIdx.x;            // 0..255 (col in the 256-wide nf row)
  int base = blockIdx.x*32;
  float acc = 0.f;
  int prev = batch[base];
  for (int r=0;r<32;r++){
    int nn = base + r;
    int b = batch[nn];
    if (b != prev){ atomicAdd(&addp[prev*256 + j], acc); acc = 0.f; prev = b; }
    float val;
    if (j < 128){
      val = s[(size_t)nn*128 + j];
    } else {
      size_t idx = (size_t)nn*128 + (j - 128);
      float v0 = v[idx], v1 = v[(size_t)N_*128 + idx], v2 = v[(size_t)N_*256 + idx];
      val = sqrtf(v0*v0 + v1*v1 + v2*v2 + 1e-12f);
    }
    acc += val;
  }
  atomicAdd(&addp[prev*256 + j], acc);
}

// counts derived from bends (no atomics)
__global__ void k_build_g(const float* __restrict__ addp, const int* __restrict__ bends,
                          const float* __restrict__ vn, float* __restrict__ gbuf){
  int i = blockIdx.x*256 + threadIdx.x;
  if (i >= G_*640) return;
  int g = i / 640, j = i % 640;
  float cnt = (float)(bends[g] - (g ? bends[g-1] : 0));
  float val;
  if (j < 256)       val = addp[g*256 + j];
  else if (j < 512)  val = addp[g*256 + (j-256)] / fmaxf(cnt, 1.f);
  else               val = vn[g*128 + (j-512)];
  gbuf[i] = val;
}

// ---------------- host launcher ----------------

extern "C" void kernel_launch(void* const* d_in, const int* in_sizes, int n_in,
                              void* d_out, int out_size, void* d_ws, size_t ws_size,
                              hipStream_t stream)
{
  const float* x         = (const float*)d_in[0];
  const float* pos       = (const float*)d_in[1];
  const float* edist     = (const float*)d_in[2];
  const float* node_in_w = (const float*)d_in[3];
  const float* node_in_b = (const float*)d_in[4];
  const float* tm_w1 = (const float*)d_in[5];
  const float* tm_b1 = (const float*)d_in[6];
  const float* tm_w2 = (const float*)d_in[7];
  const float* tm_b2 = (const float*)d_in[8];
  const float* mm_w1 = (const float*)d_in[9];
  const float* mm_b1 = (const float*)d_in[10];
  const float* mm_w2 = (const float*)d_in[11];
  const float* mm_b2 = (const float*)d_in[12];
  const float* us_w1 = (const float*)d_in[13];
  const float* us_b1 = (const float*)d_in[14];
  const float* us_w2 = (const float*)d_in[15];
  const float* us_b2 = (const float*)d_in[16];
  const float* gv_w1 = (const float*)d_in[17];
  const float* gv_b1 = (const float*)d_in[18];
  const float* gv_w2 = (const float*)d_in[19];
  const float* gv_b2 = (const float*)d_in[20];
  const float* ln_g  = (const float*)d_in[21];
  const float* ln_b  = (const float*)d_in[22];
  const float* vn_init = (const float*)d_in[23];
  const float* v2n_w1 = (const float*)d_in[24];
  const float* v2n_b1 = (const float*)d_in[25];
  const float* v2n_w2 = (const float*)d_in[26];
  const float* v2n_b2 = (const float*)d_in[27];
  const float* n2v_w1 = (const float*)d_in[28];
  const float* n2v_b1 = (const float*)d_in[29];
  const float* n2v_w2 = (const float*)d_in[30];
  const float* n2v_b2 = (const float*)d_in[31];
  const float* head_w1 = (const float*)d_in[32];
  const float* head_b1 = (const float*)d_in[33];
  const float* head_w2 = (const float*)d_in[34];
  const float* head_b2 = (const float*)d_in[35];
  const int* ei    = (const int*)d_in[36];
  const int* t_kj  = (const int*)d_in[37];
  const int* t_ji  = (const int*)d_in[38];
  const int* batch = (const int*)d_in[39];
  float* out = (float*)d_out;

  // ---- workspace layout (~150 MiB) ----
  float* f = (float*)d_ws;
  size_t off = 0;
  auto alloc = [&](size_t n){ n = (n + 3) & ~(size_t)3; float* p = f + off; off += n; return p; };
  float*    vec    = alloc((size_t)E_*3);    // aliased: perm_t + perm_e after k_angle
  float*    dir    = alloc((size_t)E_*3);
  ushort_t* rbf16  = (ushort_t*)alloc((size_t)E_*16);
  float*    angle  = alloc((size_t)T_);
  float*    tmsg_f = alloc((size_t)E_*128);  // triplet hidden T*128 bf16 / edge hidden E*128 bf16
  float*    eagg2_f= alloc((size_t)E_*64);   // eagg bf16 (E*128); later: moments + node scratch
  float*    dir_s  = alloc((size_t)E_*3);    // sorted dir
  float*    tends_f= alloc((size_t)E_ + 1024); // triplet CSR ends (E ints) + scan sums
  float*    eends_f= alloc((size_t)N_ + 1024); // edge CSR ends (N ints) + scan sums
  float*    bends_f= alloc((size_t)G_);      // batch CSR ends (G ints)
  float*    s      = alloc((size_t)N_*128);
  ushort_t* s16    = (ushort_t*)alloc((size_t)N_*64);
  float*    v      = alloc((size_t)N_*384);  // PLANAR [3][N][128]
  float*    aggv   = alloc((size_t)N_*384);  // PLANAR [3][N][128]
  float*    rank_f = alloc((size_t)E_);      // rank_e (E ints)
  float*    wtbuf_f= alloc((size_t)376832);  // bf16 transposed weights (hi + node-lo)
  float*    vn     = alloc((size_t)G_*128);
  float*    tg2    = alloc((size_t)G_*128);
  float*    ssum   = alloc((size_t)G_*128);
  float*    addp   = alloc((size_t)G_*256);
  float*    gbuf   = alloc((size_t)G_*640);

  if (off * sizeof(float) > ws_size){
    k_sentinel<<<1, 64, 0, stream>>>(out, G_);
    return;
  }

  // aliases
  int* perm_t = (int*)vec;
  int* perm_e = perm_t + T_;
  int* rank_e = (int*)rank_f;
  int* tends  = (int*)tends_f;
  int* eends  = (int*)eends_f;
  int* bends  = (int*)bends_f;
  ushort_t* tmsg   = (ushort_t*)tmsg_f;   // T*128 bf16 (triplet hidden)
  ushort_t* ehid   = (ushort_t*)tmsg_f;   // E*128 bf16 (edge hidden; tmsg dead by then)
  ushort_t* eagg2  = (ushort_t*)eagg2_f;  // E*128 bf16
  // edge moments + node scratch inside eagg2_f (eagg2 dead after edge MLP reads it)
  float*    mom  = eagg2_f;                              // [4][N][128] fp32 + sumdir [N][4]
  ushort_t* a16h = (ushort_t*)(eagg2_f + 4227072);       // 4*N*128 + 4*N region
  ushort_t* a16l = a16h + (size_t)N_*128;
  ushort_t* vnh  = a16l + (size_t)N_*128;
  ushort_t* vnl  = vnh  + (size_t)N_*128;
  float*    s2   = (float*)(vnl + (size_t)N_*128);       // N*128 fp32

  ushort_t* wtbuf = (ushort_t*)wtbuf_f;
  auto WT = [&](int l, size_t o){ return wtbuf + (size_t)l*376832 + o; };

  auto zero = [&](float* p, long n){
    int blocks = (int)((n/4 + 255)/256); if (blocks > 16384) blocks = 16384; if (blocks < 1) blocks = 1;
    k_zero<<<blocks, 256, 0, stream>>>(p, n);
  };
  auto csort = [&](const int* keys, const int* map, int M, int B, int* perm, int* ends){
    int nb = (B+1023)/1024;
    zero((float*)ends, B + nb);
    if (map) k_hist2<<<(M+255)/256, 256, 0, stream>>>(keys, map, M, ends);
    else     k_hist <<<(M+255)/256, 256, 0, stream>>>(keys, M, ends);
    k_scan1<<<nb, 256, 0, stream>>>(ends, ends, ends + B, B);
    k_scan2<<<1, 64, 0, stream>>>(ends + B, nb);
    k_scan3<<<(B+255)/256, 256, 0, stream>>>(ends, ends + B, B);
    if (map) k_fill2<<<(M+255)/256, 256, 0, stream>>>(keys, map, M, ends, perm);
    else     k_fill <<<(M+255)/256, 256, 0, stream>>>(keys, M, ends, perm);
    // post-fill: ends[b] == segment end offset for bin b
  };

  // ---- prologue ----
  zero(v, (long)N_*384);
  k_init_vn<<<(G_*H_ + 255)/256, 256, 0, stream>>>(vn, vn_init);
  k_geom<<<(E_ + 255)/256, 256, 0, stream>>>(pos, edist, ei, vec, dir, rbf16);
  k_angle<<<(T_ + 255)/256, 256, 0, stream>>>(vec, t_kj, t_ji, angle);
  csort(ei+E_, nullptr, E_, N_, perm_e, eends);
  k_invert<<<(E_+255)/256, 256, 0, stream>>>(perm_e, rank_e, E_);
  k_dirs<<<(E_+255)/256, 256, 0, stream>>>(dir, perm_e, dir_s);
  csort(t_ji, rank_e, T_, E_, perm_t, tends);
  // batch CSR ends: binary search over sorted batch (no atomics)
  k_bends<<<1, 64, 0, stream>>>(batch, bends);
  k_wt_all<<<dim3(960, 2), 256, 0, stream>>>(tm_w1, tm_w2, mm_w1, mm_w2,
                                             us_w1, us_w2, gv_w1, gv_w2, wtbuf);
  k_gemm<<<512, 128, 0, stream>>>(x, node_in_w, node_in_b, s, N_, IND_);

  for (int l=0; l<L_; l++){
    // 1) s += v2n_mlp(vn)[batch]  (snapshots s16)
    k_small_mlp2<<<8, 256, 0, stream>>>(vn, v2n_w1, v2n_b1, v2n_w2, v2n_b2, tg2, 0);
    k_sadd_batch<<<(N_*H_ + 255)/256, 256, 0, stream>>>(s, tg2, batch, s16);

    // 2) triplet: hidden MLP (4-wave, 16 rows/wave, gather-first) -> tmsg; fused CSR+W2 -> eagg2
    k_mlp1<1,96><<<T_/64, 256, 0, stream>>>(perm_t, t_kj, t_ji,
        rbf16, angle, s16, eagg2, WT(l,0), tm_b1 + l*128, tmsg);
    k_aggemm_t<<<E_/MROWS, 64, 0, stream>>>(tmsg, tends, WT(l,12288), tm_b2 + l*128, eagg2);

    // 3) edge: hidden MLP (4-wave, 16 rows/wave, gather-first) -> ehid; moment reduce; W2 GEMMs
    k_mlp1<2,416><<<E_/64, 256, 0, stream>>>(perm_e, ei, ei + E_,
        rbf16, angle, s16, eagg2, WT(l,28672), mm_b1 + l*128, ehid);
    k_agg_e<<<(N_*64)/256, 256, 0, stream>>>(ehid, eends, dir_s, mom);
    k_gemm_e<<<dim3(N_/MROWS, 4), 64, 0, stream>>>(mom, eends, WT(l,81920), mm_b2 + l*256,
        v, a16h, a16l, vnh, vnl, aggv);

    // 5+6) node update (4-wave blocks, LDS-shared weights): s2 = s + us_mlp; gated v update
    k_node_mfma<<<dim3(N_/64, 2), 256, 0, stream>>>(s, a16h, a16l, vnh, vnl, s2, v, aggv,
        WT(l,114688), WT(l,163840), us_b1 + l*128, WT(l,212992), WT(l,229376), us_b2 + l*128,
        WT(l,245760), WT(l,294912), gv_b1 + l*128, WT(l,344064), WT(l,360448), gv_b2 + l*128);

    // 7) s = silu(LN(s2)); 8) vn += n2v_mlp(batch-CSR segment sum of s)
    k_ln_silu<<<N_, 128, 0, stream>>>(s2, s, ln_g + l*128, ln_b + l*128);
    zero(ssum, (long)G_*128);
    k_ssum_csr<<<dim3(G_, 8), 128, 0, stream>>>(s, bends, ssum);
    k_small_mlp2<<<8, 256, 0, stream>>>(ssum, n2v_w1, n2v_b1, n2v_w2, n2v_b2, vn, 1);
  }

  // ---- readout ----
  zero(addp, (long)G_*256);
  k_scatter_nf2<<<N_/32, 256, 0, stream>>>(s, v, batch, addp);
  k_build_g<<<(G_*640 + 255)/256, 256, 0, stream>>>(addp, bends, vn, gbuf);
  k_head<<<G_, 128, 0, stream>>>(gbuf, head_w1, head_b1, head_w2, head_b2, out);
}

// Round 18
// 739.253 us; speedup vs baseline: 1.2272x; 1.0271x over previous
//
#include <hip/hip_runtime.h>
#include <math.h>

// ---- problem constants (from reference) ----
#define N_   8192
#define E_   131072
#define T_   262144
#define H_   128
#define IND_ 64
#define G_   32
#define L_   2

// generic fp32 GEMM tiling (node_in only)
#define CW 64
#define RB 16

// MFMA fused MLP tiling
#define MROWS 32     // rows per wave (reducer/GEMM kernels)
#define HSTRIDE 136  // LDS hidden row stride (bf16 elems)
#define WSTRIDE 36   // LDS weight col stride (bf16 elems) - spreads banks

// RBF constants
#define STEP_E  ((float)(5.0/31.0))
#define GAMMA_E ((float)(1.0/(2.0*((5.0/31.0)*(5.0/31.0) + 1e-12))))
#define PI_D    3.14159265358979323846
#define STEP_A  ((float)(PI_D/15.0))
#define GAMMA_A ((float)(1.0/(2.0*((PI_D/15.0)*(PI_D/15.0) + 1e-12))))

typedef __attribute__((ext_vector_type(8))) short short8;
typedef __attribute__((ext_vector_type(4))) float f32x4;
typedef unsigned short ushort_t;

// fast native exp (v_exp_f32); outputs feed bf16 paths so ~1-ulp diff is immaterial
static __device__ __forceinline__ float fexp_f(float x){ return __expf(x); }
static __device__ __forceinline__ float silu_f(float x){ return x / (1.f + fexp_f(-x)); }
static __device__ __forceinline__ float sigmoid_f(float x){ return 1.f / (1.f + fexp_f(-x)); }

static __device__ __forceinline__ ushort_t f2bf(float x){
  unsigned int u = __builtin_bit_cast(unsigned int, x);
  u += 0x7FFFu + ((u >> 16) & 1u);
  return (ushort_t)(u >> 16);
}
static __device__ __forceinline__ float bf2f(ushort_t h){
  unsigned int u = ((unsigned int)h) << 16;
  return __builtin_bit_cast(float, u);
}

// ---------------- small utility kernels ----------------

__global__ void k_zero(float* __restrict__ p, long n){
  long stride = (long)gridDim.x*256;
  long n4 = n >> 2;
  float4* p4 = (float4*)p;
  for (long i = (long)blockIdx.x*256 + threadIdx.x; i < n4; i += stride)
    p4[i] = make_float4(0.f,0.f,0.f,0.f);
  for (long i = (n4<<2) + (long)blockIdx.x*256 + threadIdx.x; i < n; i += stride)
    p[i] = 0.f;
}

__global__ void k_sentinel(float* __restrict__ p, int n){
  int i = blockIdx.x*256 + threadIdx.x;
  if (i < n) p[i] = 1.0e30f;
}

__global__ void k_init_vn(float* __restrict__ vn, const float* __restrict__ vn_init){
  int i = blockIdx.x*256 + threadIdx.x;
  if (i < G_*H_) vn[i] = vn_init[i & 127];
}

// batch segment ENDS via binary search over the SORTED batch array:
// bends[g] = first index where batch[i] > g. One wavefront, no atomics
// (R16 lesson: 8192 device-scope atomics on 32 counters cost 53 us).
__global__ void k_bends(const int* __restrict__ batch, int* __restrict__ bends){
  int g = threadIdx.x;
  if (g >= G_) return;
  int lo = 0, hi = N_;
  while (lo < hi){
    int mid = (lo + hi) >> 1;
    if (batch[mid] <= g) lo = mid + 1; else hi = mid;
  }
  bends[g] = lo;
}

// ---- fused weight convert+transpose for ALL weights of one layer ----
__global__ void k_wt_all(const float* __restrict__ tm_w1, const float* __restrict__ tm_w2,
                         const float* __restrict__ mm_w1, const float* __restrict__ mm_w2,
                         const float* __restrict__ us_w1, const float* __restrict__ us_w2,
                         const float* __restrict__ gv_w1, const float* __restrict__ gv_w2,
                         ushort_t* __restrict__ wtbuf){
  const int l = blockIdx.y;
  int i = blockIdx.x*256 + threadIdx.x;
  if (i >= 245760) return;
  ushort_t* base = wtbuf + (size_t)l*376832;
  if (i < 12288){                    // tm1: K=80, C=128, Kpad=96 (hi only)
    int c = i/96, k = i%96;
    base[i] = (k < 80) ? f2bf(tm_w1[(size_t)l*10240 + (size_t)k*128 + c]) : (ushort_t)0;
  } else if (i < 28672){             // tm2: 128x128 (hi only)
    int j = i - 12288; int c = j >> 7, k = j & 127;
    base[12288 + j] = f2bf(tm_w2[(size_t)l*16384 + (size_t)k*128 + c]);
  } else if (i < 81920){             // mm1: K=416, C=128 (hi only)
    int j = i - 28672; int c = j/416, k = j%416;
    base[28672 + j] = f2bf(mm_w1[(size_t)l*53248 + (size_t)k*128 + c]);
  } else if (i < 114688){            // mm2: K=128, C=256 (hi only)
    int j = i - 81920; int c = j >> 7, k = j & 127;
    base[81920 + j] = f2bf(mm_w2[(size_t)l*32768 + (size_t)k*256 + c]);
  } else if (i < 163840){            // us1: K=384, C=128 (hi+lo)
    int j = i - 114688; int c = j/384, k = j%384;
    float w = us_w1[(size_t)l*49152 + (size_t)k*128 + c];
    ushort_t h = f2bf(w);
    base[114688 + j] = h; base[163840 + j] = f2bf(w - bf2f(h));
  } else if (i < 180224){            // us2: 128x128 (hi+lo)
    int j = i - 163840; int c = j >> 7, k = j & 127;
    float w = us_w2[(size_t)l*16384 + (size_t)k*128 + c];
    ushort_t h = f2bf(w);
    base[212992 + j] = h; base[229376 + j] = f2bf(w - bf2f(h));
  } else if (i < 229376){            // gv1: K=384, C=128 (hi+lo)
    int j = i - 180224; int c = j/384, k = j%384;
    float w = gv_w1[(size_t)l*49152 + (size_t)k*128 + c];
    ushort_t h = f2bf(w);
    base[245760 + j] = h; base[294912 + j] = f2bf(w - bf2f(h));
  } else {                           // gv2: 128x128 (hi+lo)
    int j = i - 229376; int c = j >> 7, k = j & 127;
    float w = gv_w2[(size_t)l*16384 + (size_t)k*128 + c];
    ushort_t h = f2bf(w);
    base[344064 + j] = h; base[360448 + j] = f2bf(w - bf2f(h));
  }
}

// per-edge: vec, dir, edge RBF(32) in bf16
__global__ void k_geom(const float* __restrict__ pos, const float* __restrict__ dist,
                       const int* __restrict__ ei,
                       float* __restrict__ vec, float* __restrict__ dir,
                       ushort_t* __restrict__ rbf16){
  int e = blockIdx.x*256 + threadIdx.x;
  if (e >= E_) return;
  int s = ei[e], d = ei[E_ + e];
  float vx = pos[d*3+0] - pos[s*3+0];
  float vy = pos[d*3+1] - pos[s*3+1];
  float vz = pos[d*3+2] - pos[s*3+2];
  vec[e*3+0]=vx; vec[e*3+1]=vy; vec[e*3+2]=vz;
  float dd = dist[e];
  float inv = 1.f / (dd + 1e-9f);
  dir[e*3+0]=vx*inv; dir[e*3+1]=vy*inv; dir[e*3+2]=vz*inv;
  #pragma unroll
  for (int i=0;i<32;i++){
    float df = dd - i*STEP_E;
    rbf16[e*32+i] = f2bf(fexp_f(-GAMMA_E*df*df));
  }
}

// gather dir into sorted-edge order: dir_s[p] = dir[perm_e[p]]
__global__ void k_dirs(const float* __restrict__ dir, const int* __restrict__ perm_e,
                       float* __restrict__ dir_s){
  int p = blockIdx.x*256 + threadIdx.x;
  if (p >= E_) return;
  int e = perm_e[p];
  dir_s[p*3+0] = dir[e*3+0];
  dir_s[p*3+1] = dir[e*3+1];
  dir_s[p*3+2] = dir[e*3+2];
}

// per-triplet angle
__global__ void k_angle(const float* __restrict__ vec,
                        const int* __restrict__ kj, const int* __restrict__ ji,
                        float* __restrict__ angle){
  int t = blockIdx.x*256 + threadIdx.x;
  if (t >= T_) return;
  int ea = ji[t], eb = kj[t];
  float ax=vec[ea*3+0], ay=vec[ea*3+1], az=vec[ea*3+2];
  float bx=vec[eb*3+0], by=vec[eb*3+1], bz=vec[eb*3+2];
  float dot = ax*bx + ay*by + az*bz;
  float na = sqrtf(ax*ax+ay*ay+az*az + 1e-12f);
  float nb = sqrtf(bx*bx+by*by+bz*bz + 1e-12f);
  float c = dot / (na*nb + 1e-9f);
  c = fminf(fmaxf(c, -1.f + 1e-7f), 1.f - 1e-7f);
  angle[t] = acosf(c);
}

// ---------------- counting-sort kernels ----------------

__global__ void k_hist(const int* __restrict__ keys, int M, int* __restrict__ hist){
  int i = blockIdx.x*256 + threadIdx.x;
  if (i < M) atomicAdd(&hist[keys[i]], 1);
}

__global__ void k_hist2(const int* __restrict__ keys, const int* __restrict__ map,
                        int M, int* __restrict__ hist){
  int i = blockIdx.x*256 + threadIdx.x;
  if (i < M) atomicAdd(&hist[map[keys[i]]], 1);
}

__global__ void k_scan1(const int* __restrict__ in, int* __restrict__ out,
                        int* __restrict__ sums, int B){
  __shared__ int sh[1024];
  int base = blockIdx.x*1024, t = threadIdx.x;
  for (int j=t;j<1024;j+=256) sh[j] = (base+j<B) ? in[base+j] : 0;
  __syncthreads();
  for (int o=1;o<1024;o<<=1){
    int v[4];
    #pragma unroll
    for (int q=0;q<4;q++){ int idx=t+q*256; v[q]=(idx>=o)? sh[idx-o]:0; }
    __syncthreads();
    #pragma unroll
    for (int q=0;q<4;q++){ int idx=t+q*256; sh[idx]+=v[q]; }
    __syncthreads();
  }
  for (int j=t;j<1024;j+=256) if (base+j<B) out[base+j] = (j==0)?0:sh[j-1];
  if (t==0) sums[blockIdx.x] = sh[1023];
}

__global__ void k_scan2(int* __restrict__ sums, int nb){
  if (threadIdx.x==0 && blockIdx.x==0){
    int a=0;
    for (int i=0;i<nb;i++){ int x=sums[i]; sums[i]=a; a+=x; }
  }
}

__global__ void k_scan3(int* __restrict__ out, const int* __restrict__ sums, int B){
  int i = blockIdx.x*256+threadIdx.x;
  if (i<B) out[i] += sums[i>>10];
}

__global__ void k_fill(const int* __restrict__ keys, int M, int* __restrict__ cur,
                       int* __restrict__ perm){
  int i = blockIdx.x*256+threadIdx.x;
  if (i<M){ int p = atomicAdd(&cur[keys[i]],1); perm[p]=i; }
}

__global__ void k_fill2(const int* __restrict__ keys, const int* __restrict__ map,
                        int M, int* __restrict__ cur, int* __restrict__ perm){
  int i = blockIdx.x*256+threadIdx.x;
  if (i<M){ int p = atomicAdd(&cur[map[keys[i]]],1); perm[p]=i; }
}

__global__ void k_invert(const int* __restrict__ perm, int* __restrict__ rank, int M){
  int i = blockIdx.x*256+threadIdx.x;
  if (i<M) rank[perm[i]] = i;
}

// ---------------- MFMA first-layer MLP (4-wave block, 16 rows/wave) ----------------
// 256 threads = 4 waves, each wave owns 16 rows (64 rows/block). Per 32-k chunk:
// the chunk's GATHER load is issued FIRST (latency overlaps the weight staging +
// barrier), then the W1 slice is cooperatively staged in LDS, then MFMA.
// acc is only 32 regs/lane -> no register squeeze at 4+ blocks/CU
// (R15 lesson: occupancy bought with reg pressure sinks the gathers).
template<int SM, int K1PAD>
__launch_bounds__(256, 4)
__global__ void k_mlp1(
    const int* __restrict__ perm,
    const int* __restrict__ idx1, const int* __restrict__ idx2,
    const ushort_t* __restrict__ rbf16, const float* __restrict__ angle,
    const ushort_t* __restrict__ s16, const ushort_t* __restrict__ eagg_in,
    const ushort_t* __restrict__ W1t, const float* __restrict__ b1,
    ushort_t* __restrict__ outbuf)
{
  __shared__ ushort_t lw[128*WSTRIDE];       // 9216 B weight chunk
  __shared__ ushort_t hid[4][16*HSTRIDE];    // 17408 B (per-wave staging)  -> 26.6 KB total
  const int tid  = threadIdx.x;
  const int wave = tid >> 6;
  const int lane = tid & 63;
  const int n    = lane & 15;
  const int quad = lane >> 4;
  const int kq   = quad*8;
  const int wrow = blockIdx.x*64 + wave*16;
  const int row  = wrow + n;

  const int e0 = perm[row];
  int i1a = idx1[e0];
  int i2a = idx2[e0];
  float ang0 = 0.f;
  if (SM == 1){ ang0 = angle[e0]; }

  f32x4 acc[8];
  #pragma unroll
  for (int ct=0;ct<8;ct++) acc[ct] = (f32x4){0.f,0.f,0.f,0.f};

  #pragma unroll
  for (int k0 = 0; k0 < K1PAD; k0 += 32){
    // ---- issue this chunk's gather load FIRST (overlap with staging+barrier) ----
    short8 a0;
    if (SM == 1){
      if (k0 == 0){
        a0 = *(const short8*)&rbf16[(size_t)i1a*32 + kq];
      } else if (k0 == 32){
        a0 = *(const short8*)&rbf16[(size_t)i2a*32 + kq];
      } else {
        #pragma unroll
        for (int j=0;j<8;j++){
          int kk = kq + j;
          float v0 = 0.f;
          if (kk < 16){
            float c = (float)kk*STEP_A;
            float d0 = ang0 - c;
            v0 = fexp_f(-GAMMA_A*d0*d0);
          }
          a0[j] = (short)f2bf(v0);
        }
      }
    } else {
      const int k = k0 + kq;
      if (k0 < 128){
        a0 = *(const short8*)&s16[(size_t)i1a*128 + k];
      } else if (k0 < 256){
        a0 = *(const short8*)&s16[(size_t)i2a*128 + (k-128)];
      } else if (k0 < 288){
        a0 = *(const short8*)&rbf16[(size_t)e0*32 + (k-256)];
      } else {
        // eagg (post-W2) bf16 in sorted-edge-position order -> sequential rows
        a0 = *(const short8*)&eagg_in[(size_t)row*128 + (k-288)];
      }
    }

    // ---- cooperative stage of the 128x32 weight slice (hi only) ----
    #pragma unroll
    for (int it=0; it<2; it++){
      int idx = tid + it*256;           // 0..511
      int col = idx >> 2, seg = idx & 3;
      *(short8*)&lw[col*WSTRIDE + seg*8] = *(const short8*)&W1t[(size_t)col*K1PAD + k0 + seg*8];
    }
    __syncthreads();

    #pragma unroll
    for (int ct=0;ct<8;ct++){
      short8 b = *(const short8*)&lw[(ct*16 + n)*WSTRIDE + kq];
      acc[ct] = __builtin_amdgcn_mfma_f32_16x16x32_bf16(a0, b, acc[ct], 0,0,0);
    }
    __syncthreads();
  }

  // bias + silu -> LDS staging (wave-private), then coalesced 16B stores
  #pragma unroll
  for (int ct=0;ct<8;ct++){
    int col = ct*16 + n;
    float bv = b1[col];
    #pragma unroll
    for (int reg=0;reg<4;reg++){
      int rloc = quad*4 + reg;
      float h = acc[ct][reg] + bv;
      hid[wave][rloc*HSTRIDE + col] = f2bf(silu_f(h));
    }
  }
  const int rsub = lane >> 4;
  const int c8   = (lane & 15) * 8;
  #pragma unroll
  for (int i=0;i<4;i++){
    int rloc = i*4 + rsub;
    int grow = wrow + rloc;
    short8 vv = *(const short8*)&hid[wave][(size_t)rloc*HSTRIDE + c8];
    *(short8*)&outbuf[(size_t)grow*128 + c8] = vv;
  }
}

// ---------------- FUSED triplet aggregate + W2 GEMM ----------------
__launch_bounds__(64, 4)
__global__ void k_aggemm_t(const ushort_t* __restrict__ tmsg, const int* __restrict__ tends,
                           const ushort_t* __restrict__ W2t, const float* __restrict__ b2,
                           ushort_t* __restrict__ eagg2){
  __shared__ ushort_t hid[MROWS*HSTRIDE];
  const int lane = threadIdx.x;
  const int n    = lane & 15;
  const int quad = lane >> 4;
  const int kq   = quad*8;
  const int wrow = blockIdx.x*MROWS;
  const int r0 = wrow + n, r1 = wrow + 16 + n;
  const int s0 = r0 ? tends[r0-1] : 0;
  const int e0 = tends[r0];
  const int s1 = tends[r1-1];
  const int e1 = tends[r1];

  f32x4 acc[2][8];
  #pragma unroll
  for (int rh=0;rh<2;rh++)
    #pragma unroll
    for (int ct=0;ct<8;ct++) acc[rh][ct] = (f32x4){0.f,0.f,0.f,0.f};

  #pragma unroll
  for (int k0=0;k0<128;k0+=32){
    float sum0[8], sum1[8];
    #pragma unroll
    for (int j=0;j<8;j++){ sum0[j]=0.f; sum1[j]=0.f; }
    for (int p=s0;p<e0;p++){
      short8 w = *(const short8*)&tmsg[(size_t)p*128 + k0 + kq];
      #pragma unroll
      for (int j=0;j<8;j++) sum0[j] += bf2f((ushort_t)w[j]);
    }
    for (int p=s1;p<e1;p++){
      short8 w = *(const short8*)&tmsg[(size_t)p*128 + k0 + kq];
      #pragma unroll
      for (int j=0;j<8;j++) sum1[j] += bf2f((ushort_t)w[j]);
    }
    short8 a0, a1;
    #pragma unroll
    for (int j=0;j<8;j++){
      a0[j] = (short)f2bf(sum0[j]);
      a1[j] = (short)f2bf(sum1[j]);
    }
    #pragma unroll
    for (int ct=0;ct<8;ct++){
      short8 b = *(const short8*)&W2t[(size_t)(ct*16 + n)*128 + k0 + kq];
      acc[0][ct] = __builtin_amdgcn_mfma_f32_16x16x32_bf16(a0, b, acc[0][ct], 0,0,0);
      acc[1][ct] = __builtin_amdgcn_mfma_f32_16x16x32_bf16(a1, b, acc[1][ct], 0,0,0);
    }
  }

  // per-row segment counts for the bias
  float cnts[2][4];
  #pragma unroll
  for (int rh=0;rh<2;rh++)
    #pragma unroll
    for (int reg=0;reg<4;reg++){
      int row = wrow + rh*16 + quad*4 + reg;
      cnts[rh][reg] = (float)(tends[row] - (row ? tends[row-1] : 0));
    }

  #pragma unroll
  for (int rh=0;rh<2;rh++){
    #pragma unroll
    for (int ct=0;ct<8;ct++){
      int col = ct*16 + n;
      float bv = b2[col];
      #pragma unroll
      for (int reg=0;reg<4;reg++){
        int rloc = rh*16 + quad*4 + reg;
        hid[rloc*HSTRIDE + col] = f2bf(acc[rh][ct][reg] + cnts[rh][reg]*bv);
      }
    }
  }
  const int rsub = lane >> 4;
  const int c8   = (lane & 15) * 8;
  #pragma unroll
  for (int i=0;i<8;i++){
    int rloc = i*4 + rsub;
    int grow = wrow + rloc;
    short8 vv = *(const short8*)&hid[(size_t)rloc*HSTRIDE + c8];
    *(short8*)&eagg2[(size_t)grow*128 + c8] = vv;
  }
}

// edge moment reducer
__global__ void k_agg_e(const ushort_t* __restrict__ hbuf, const int* __restrict__ eends,
                        const float* __restrict__ dir_s, float* __restrict__ mom){
  int i = blockIdx.x*256 + threadIdx.x;
  int d = i >> 6, c2 = (i & 63)*2;
  if (d >= N_) return;
  int s = (d == 0) ? 0 : eends[d-1];
  int e = eends[d];
  float hs0=0.f,hs1=0.f, hx0=0.f,hx1=0.f, hy0=0.f,hy1=0.f, hz0=0.f,hz1=0.f;
  float sdx=0.f, sdy=0.f, sdz=0.f;
  for (int q=s;q<e;q++){
    unsigned int w = *(const unsigned int*)&hbuf[(size_t)q*128 + c2];
    float h0 = bf2f((ushort_t)(w & 0xFFFFu));
    float h1 = bf2f((ushort_t)(w >> 16));
    float dx = dir_s[q*3+0], dy = dir_s[q*3+1], dz = dir_s[q*3+2];
    hs0 += h0; hs1 += h1;
    hx0 += h0*dx; hx1 += h1*dx;
    hy0 += h0*dy; hy1 += h1*dy;
    hz0 += h0*dz; hz1 += h1*dz;
    sdx += dx; sdy += dy; sdz += dz;
  }
  size_t base = (size_t)d*128 + c2;
  *(float2*)&mom[base]                        = make_float2(hs0, hs1);
  *(float2*)&mom[(size_t)N_*128   + base]     = make_float2(hx0, hx1);
  *(float2*)&mom[(size_t)N_*256   + base]     = make_float2(hy0, hy1);
  *(float2*)&mom[(size_t)N_*384   + base]     = make_float2(hz0, hz1);
  if (c2 == 0){
    mom[(size_t)N_*512 + d*4+0] = sdx;
    mom[(size_t)N_*512 + d*4+1] = sdy;
    mom[(size_t)N_*512 + d*4+2] = sdz;
  }
}

// edge: moment GEMM per og = blockIdx.y (0: Ms -> a16 + vn; 1..3: Mx/My/Mz -> aggv plane).
__launch_bounds__(64, 4)
__global__ void k_gemm_e(const float* __restrict__ mom, const int* __restrict__ eends,
                         const ushort_t* __restrict__ W2t /*[256][128]*/,
                         const float* __restrict__ b2 /*[256]*/,
                         const float* __restrict__ v /*[3][N][128]*/,
                         ushort_t* __restrict__ a16h, ushort_t* __restrict__ a16l,
                         ushort_t* __restrict__ vnh,  ushort_t* __restrict__ vnl,
                         float* __restrict__ aggv /*[3][N][128]*/){
  __shared__ float sbuf[MROWS*130];   // 16640 B staging
  const int lane = threadIdx.x;
  const int n    = lane & 15;
  const int quad = lane >> 4;
  const int kq   = quad*8;
  const int wrow = blockIdx.x*MROWS;
  const int og   = blockIdx.y;

  const float* M = mom + (size_t)og*((size_t)N_*128);
  const ushort_t* W = W2t + (og ? (size_t)128*128 : 0);

  f32x4 acc[2][8];
  #pragma unroll
  for (int rh=0;rh<2;rh++)
    #pragma unroll
    for (int ct=0;ct<8;ct++) acc[rh][ct] = (f32x4){0.f,0.f,0.f,0.f};

  #pragma unroll
  for (int k0=0;k0<128;k0+=32){
    const int k = k0 + kq;
    const float* p0 = &M[(size_t)(wrow + n)*128 + k];
    const float* p1 = &M[(size_t)(wrow + 16 + n)*128 + k];
    f32x4 x0 = *(const f32x4*)p0, x1 = *(const f32x4*)(p0+4);
    f32x4 y0 = *(const f32x4*)p1, y1 = *(const f32x4*)(p1+4);
    short8 ah0, al0, ah1, al1;
    #pragma unroll
    for (int j=0;j<4;j++){
      ushort_t h;
      h = f2bf(x0[j]); ah0[j]   = (short)h; al0[j]   = (short)f2bf(x0[j] - bf2f(h));
      h = f2bf(x1[j]); ah0[4+j] = (short)h; al0[4+j] = (short)f2bf(x1[j] - bf2f(h));
      h = f2bf(y0[j]); ah1[j]   = (short)h; al1[j]   = (short)f2bf(y0[j] - bf2f(h));
      h = f2bf(y1[j]); ah1[4+j] = (short)h; al1[4+j] = (short)f2bf(y1[j] - bf2f(h));
    }
    #pragma unroll
    for (int ct=0;ct<8;ct++){
      short8 b = *(const short8*)&W[(size_t)(ct*16 + n)*128 + k0 + kq];
      acc[0][ct] = __builtin_amdgcn_mfma_f32_16x16x32_bf16(ah0, b, acc[0][ct], 0,0,0);
      acc[0][ct] = __builtin_amdgcn_mfma_f32_16x16x32_bf16(al0, b, acc[0][ct], 0,0,0);
      acc[1][ct] = __builtin_amdgcn_mfma_f32_16x16x32_bf16(ah1, b, acc[1][ct], 0,0,0);
      acc[1][ct] = __builtin_amdgcn_mfma_f32_16x16x32_bf16(al1, b, acc[1][ct], 0,0,0);
    }
  }

  const int rsub = lane >> 4;
  const int c8   = (lane & 15) * 8;

  if (og == 0){
    float cnts[2][4];
    #pragma unroll
    for (int rh=0;rh<2;rh++)
      #pragma unroll
      for (int reg=0;reg<4;reg++){
        int row = wrow + rh*16 + quad*4 + reg;
        cnts[rh][reg] = (float)(eends[row] - (row ? eends[row-1] : 0));
      }
    ushort_t* us = (ushort_t*)sbuf;
    // pass 1: hi
    #pragma unroll
    for (int rh=0;rh<2;rh++)
      #pragma unroll
      for (int ct=0;ct<8;ct++){
        int col = ct*16 + n;
        float bv = b2[col];
        #pragma unroll
        for (int reg=0;reg<4;reg++){
          int rloc = rh*16 + quad*4 + reg;
          float val = acc[rh][ct][reg] + cnts[rh][reg]*bv;
          us[rloc*HSTRIDE + col] = f2bf(val);
        }
      }
    #pragma unroll
    for (int i=0;i<8;i++){
      int rloc = i*4 + rsub;
      short8 vv = *(const short8*)&us[(size_t)rloc*HSTRIDE + c8];
      *(short8*)&a16h[(size_t)(wrow + rloc)*128 + c8] = vv;
    }
    // pass 2: lo
    #pragma unroll
    for (int rh=0;rh<2;rh++)
      #pragma unroll
      for (int ct=0;ct<8;ct++){
        int col = ct*16 + n;
        float bv = b2[col];
        #pragma unroll
        for (int reg=0;reg<4;reg++){
          int rloc = rh*16 + quad*4 + reg;
          float val = acc[rh][ct][reg] + cnts[rh][reg]*bv;
          ushort_t h = f2bf(val);
          us[rloc*HSTRIDE + col] = f2bf(val - bf2f(h));
        }
      }
    #pragma unroll
    for (int i=0;i<8;i++){
      int rloc = i*4 + rsub;
      short8 vv = *(const short8*)&us[(size_t)rloc*HSTRIDE + c8];
      *(short8*)&a16l[(size_t)(wrow + rloc)*128 + c8] = vv;
    }
    // vn norms, linear sweep (planar v)
    #pragma unroll 4
    for (int j=0;j<32;j++){
      size_t idx = (size_t)wrow*128 + (size_t)j*128 + lane*2;
      float2 a = *(const float2*)&v[idx];
      float2 b = *(const float2*)&v[(size_t)N_*128 + idx];
      float2 c = *(const float2*)&v[(size_t)N_*256 + idx];
      float n0 = sqrtf(a.x*a.x + b.x*b.x + c.x*c.x + 1e-12f);
      float n1 = sqrtf(a.y*a.y + b.y*b.y + c.y*c.y + 1e-12f);
      ushort_t h0 = f2bf(n0), h1 = f2bf(n1);
      *(unsigned int*)&vnh[idx] = (unsigned int)h0 | ((unsigned int)h1 << 16);
      *(unsigned int*)&vnl[idx] = (unsigned int)f2bf(n0 - bf2f(h0))
                                | ((unsigned int)f2bf(n1 - bf2f(h1)) << 16);
    }
  } else {
    const int x = og - 1;
    #pragma unroll
    for (int rh=0;rh<2;rh++)
      #pragma unroll
      for (int ct=0;ct<8;ct++){
        int col = ct*16 + n;
        float bv = b2[128 + col];
        #pragma unroll
        for (int reg=0;reg<4;reg++){
          int rloc = rh*16 + quad*4 + reg;
          int row = wrow + rloc;
          float sd = mom[(size_t)N_*512 + row*4 + x];
          sbuf[rloc*130 + col] = acc[rh][ct][reg] + sd*bv;
        }
      }
    float* plane = aggv + (size_t)x*((size_t)N_*128);
    #pragma unroll
    for (int i=0;i<8;i++){
      int rloc = i*4 + rsub;
      f32x4 v0 = *(const f32x4*)&sbuf[rloc*130 + c8];
      f32x4 v1 = *(const f32x4*)&sbuf[rloc*130 + c8 + 4];
      *(f32x4*)&plane[(size_t)(wrow + rloc)*128 + c8] = v0;
      *(f32x4*)&plane[(size_t)(wrow + rloc)*128 + c8 + 4] = v1;
    }
  }
}

// ---------------- MFMA node-update kernel (4-wave block, LDS-shared weights) ----------------
__launch_bounds__(256, 3)
__global__ void k_node_mfma(
    const float* __restrict__ s_in,
    const ushort_t* __restrict__ a16h, const ushort_t* __restrict__ a16l,
    const ushort_t* __restrict__ vnh,  const ushort_t* __restrict__ vnl,
    float* __restrict__ s2, float* __restrict__ v_out /*[3][N][128]*/,
    const float* __restrict__ aggv /*[3][N][128]*/,
    const ushort_t* __restrict__ us1h, const ushort_t* __restrict__ us1l, const float* __restrict__ us_b1,
    const ushort_t* __restrict__ us2h, const ushort_t* __restrict__ us2l, const float* __restrict__ us_b2,
    const ushort_t* __restrict__ gv1h, const ushort_t* __restrict__ gv1l, const float* __restrict__ gv_b1,
    const ushort_t* __restrict__ gv2h, const ushort_t* __restrict__ gv2l, const float* __restrict__ gv_b2)
{
  __shared__ ushort_t lwh[128*WSTRIDE];       // 9216 B weight chunk (hi)
  __shared__ ushort_t lwl[128*WSTRIDE];       // 9216 B weight chunk (lo)
  __shared__ ushort_t hidh[4][16*HSTRIDE];    // 17408 B
  __shared__ ushort_t hidl[4][16*HSTRIDE];    // 17408 B  (total 53248 B)
  const int tid  = threadIdx.x;
  const int wave = tid >> 6;
  const int lane = tid & 63;
  const int n    = lane & 15;
  const int quad = lane >> 4;
  const int kq   = quad*8;
  const int og   = blockIdx.y;
  const int wrow = blockIdx.x*64 + wave*16;
  const int r0 = wrow + n;

  const ushort_t* W1h = og ? gv1h : us1h;
  const ushort_t* W1l = og ? gv1l : us1l;
  const float*    B1  = og ? gv_b1 : us_b1;
  const ushort_t* W2h = og ? gv2h : us2h;
  const ushort_t* W2l = og ? gv2l : us2l;
  const float*    B2  = og ? gv_b2 : us_b2;

  // ---------- phase A ----------
  f32x4 acc[8];
  #pragma unroll
  for (int ct=0;ct<8;ct++) acc[ct] = (f32x4){0.f,0.f,0.f,0.f};

  #pragma unroll
  for (int k0=0; k0<384; k0+=32){
    #pragma unroll
    for (int it = 0; it < 2; it++){
      int idx = tid + it*256;          // 0..511
      int col = idx >> 2, seg = idx & 3;
      *(short8*)&lwh[col*WSTRIDE + seg*8] = *(const short8*)&W1h[(size_t)col*384 + k0 + seg*8];
      *(short8*)&lwl[col*WSTRIDE + seg*8] = *(const short8*)&W1l[(size_t)col*384 + k0 + seg*8];
    }
    __syncthreads();

    short8 ah0, al0;
    const int k = k0 + kq;
    if (k0 < 128){
      const float* p0 = &s_in[(size_t)r0*128 + k];
      f32x4 x0 = *(const f32x4*)p0, x1 = *(const f32x4*)(p0+4);
      #pragma unroll
      for (int j=0;j<4;j++){
        ushort_t h;
        h = f2bf(x0[j]); ah0[j]   = (short)h; al0[j]   = (short)f2bf(x0[j] - bf2f(h));
        h = f2bf(x1[j]); ah0[4+j] = (short)h; al0[4+j] = (short)f2bf(x1[j] - bf2f(h));
      }
    } else if (k0 < 256){
      int kk = k - 128;
      ah0 = *(const short8*)&a16h[(size_t)r0*128 + kk];
      al0 = *(const short8*)&a16l[(size_t)r0*128 + kk];
    } else {
      int kk = k - 256;
      ah0 = *(const short8*)&vnh[(size_t)r0*128 + kk];
      al0 = *(const short8*)&vnl[(size_t)r0*128 + kk];
    }
    #pragma unroll
    for (int ct=0;ct<8;ct++){
      short8 bh = *(const short8*)&lwh[(ct*16 + n)*WSTRIDE + kq];
      short8 bl = *(const short8*)&lwl[(ct*16 + n)*WSTRIDE + kq];
      acc[ct] = __builtin_amdgcn_mfma_f32_16x16x32_bf16(ah0, bh, acc[ct], 0,0,0);
      acc[ct] = __builtin_amdgcn_mfma_f32_16x16x32_bf16(al0, bh, acc[ct], 0,0,0);
      acc[ct] = __builtin_amdgcn_mfma_f32_16x16x32_bf16(ah0, bl, acc[ct], 0,0,0);
    }
    __syncthreads();
  }

  #pragma unroll
  for (int ct=0;ct<8;ct++){
    int col = ct*16 + n;
    float bv = B1[col];
    #pragma unroll
    for (int reg=0;reg<4;reg++){
      int rloc = quad*4 + reg;
      float h = silu_f(acc[ct][reg] + bv);
      ushort_t hh = f2bf(h);
      hidh[wave][rloc*HSTRIDE + col] = hh;
      hidl[wave][rloc*HSTRIDE + col] = f2bf(h - bf2f(hh));
    }
  }

  // ---------- phase B ----------
  f32x4 acc2[8];
  #pragma unroll
  for (int ct=0;ct<8;ct++) acc2[ct] = (f32x4){0.f,0.f,0.f,0.f};

  #pragma unroll
  for (int k0=0;k0<128;k0+=32){
    #pragma unroll
    for (int it = 0; it < 2; it++){
      int idx = tid + it*256;
      int col = idx >> 2, seg = idx & 3;
      *(short8*)&lwh[col*WSTRIDE + seg*8] = *(const short8*)&W2h[(size_t)col*128 + k0 + seg*8];
      *(short8*)&lwl[col*WSTRIDE + seg*8] = *(const short8*)&W2l[(size_t)col*128 + k0 + seg*8];
    }
    __syncthreads();

    short8 ah0 = *(const short8*)&hidh[wave][(size_t)(n)*HSTRIDE + k0 + kq];
    short8 al0 = *(const short8*)&hidl[wave][(size_t)(n)*HSTRIDE + k0 + kq];
    #pragma unroll
    for (int ct=0;ct<8;ct++){
      short8 bh = *(const short8*)&lwh[(ct*16 + n)*WSTRIDE + kq];
      short8 bl = *(const short8*)&lwl[(ct*16 + n)*WSTRIDE + kq];
      acc2[ct] = __builtin_amdgcn_mfma_f32_16x16x32_bf16(ah0, bh, acc2[ct], 0,0,0);
      acc2[ct] = __builtin_amdgcn_mfma_f32_16x16x32_bf16(al0, bh, acc2[ct], 0,0,0);
      acc2[ct] = __builtin_amdgcn_mfma_f32_16x16x32_bf16(ah0, bl, acc2[ct], 0,0,0);
    }
    __syncthreads();
  }

  if (og == 0){
    #pragma unroll
    for (int ct=0;ct<8;ct++){
      int col = ct*16 + n;
      float bv = B2[col];
      #pragma unroll
      for (int reg=0;reg<4;reg++){
        int row = wrow + quad*4 + reg;
        size_t idx = (size_t)row*128 + col;
        s2[idx] = s_in[idx] + acc2[ct][reg] + bv;
      }
    }
  } else {
    #pragma unroll
    for (int ct=0;ct<8;ct++){
      int col = ct*16 + n;
      float bv = B2[col];
      #pragma unroll
      for (int reg=0;reg<4;reg++){
        int row = wrow + quad*4 + reg;
        size_t idx = (size_t)row*128 + col;
        float g = sigmoid_f(acc2[ct][reg] + bv);
        v_out[idx]                    += g*aggv[idx];
        v_out[(size_t)N_*128 + idx]   += g*aggv[(size_t)N_*128 + idx];
        v_out[(size_t)N_*256 + idx]   += g*aggv[(size_t)N_*256 + idx];
      }
    }
  }
}

// ---------------- generic fp32 row-MLP GEMM (node_in only) ----------------
__launch_bounds__(128)
__global__ void k_gemm(const float* __restrict__ A,
                       const float* __restrict__ W,
                       const float* __restrict__ bias,
                       float* __restrict__ C, int R, int K)
{
  __shared__ float ws[CW*128];
  __shared__ float as[RB][CW];
  const int tid = threadIdx.x;
  const int nchunk = (K + CW - 1) / CW;

  for (int rb = blockIdx.x*RB; rb < R; rb += gridDim.x*RB){
    float acc[RB];
    #pragma unroll
    for (int r=0;r<RB;r++) acc[r] = 0.f;

    for (int c=0;c<nchunk;c++){
      const int k0 = c*CW;
      for (int i=tid; i<CW*128; i+=128){
        int kk = i >> 7, col = i & 127;
        int k = k0 + kk;
        ws[i] = (k < K) ? W[k*128 + col] : 0.f;
      }
      for (int i=tid; i<RB*CW; i+=128){
        int r  = i >> 6, kk = i & 63;
        int k  = k0 + kk;
        as[r][kk] = (k < K) ? A[(long)(rb+r)*K + k] : 0.f;
      }
      __syncthreads();
      #pragma unroll 4
      for (int kq2=0; kq2<CW/4; kq2++){
        float w0 = ws[(4*kq2+0)*128 + tid];
        float w1 = ws[(4*kq2+1)*128 + tid];
        float w2 = ws[(4*kq2+2)*128 + tid];
        float w3 = ws[(4*kq2+3)*128 + tid];
        #pragma unroll
        for (int r=0;r<RB;r++){
          const float4 av = *reinterpret_cast<const float4*>(&as[r][4*kq2]);
          acc[r] = fmaf(av.x, w0, acc[r]);
          acc[r] = fmaf(av.y, w1, acc[r]);
          acc[r] = fmaf(av.z, w2, acc[r]);
          acc[r] = fmaf(av.w, w3, acc[r]);
        }
      }
      __syncthreads();
    }

    const float bv = bias[tid];
    #pragma unroll
    for (int r=0;r<RB;r++)
      C[(long)(rb+r)*128 + tid] = acc[r] + bv;
  }
}

// ---------------- small fused kernels ----------------

// G x 128 2-layer MLP, row-parallel: grid 8 blocks x 4 rows each.
__launch_bounds__(256)
__global__ void k_small_mlp2(const float* __restrict__ in,
                             const float* __restrict__ w1, const float* __restrict__ b1,
                             const float* __restrict__ w2, const float* __restrict__ b2,
                             float* __restrict__ outp, int accumulate){
  __shared__ float a[4][128];
  __shared__ float h[4][128];
  int tid = threadIdx.x;
  int rbase = blockIdx.x*4;
  for (int i=tid;i<4*128;i+=256) a[i>>7][i&127] = in[(rbase + (i>>7))*128 + (i&127)];
  __syncthreads();
  int col = tid & 127, rg = tid >> 7;   // rg 0..1 -> rows rg*2, rg*2+1
  float acc0=0.f, acc1=0.f;
  for (int k=0;k<128;k++){
    float w = w1[k*128+col];
    acc0 = fmaf(a[rg*2+0][k], w, acc0);
    acc1 = fmaf(a[rg*2+1][k], w, acc1);
  }
  {
    float bv = b1[col];
    h[rg*2+0][col] = silu_f(acc0+bv);
    h[rg*2+1][col] = silu_f(acc1+bv);
  }
  __syncthreads();
  acc0=0.f; acc1=0.f;
  for (int k=0;k<128;k++){
    float w = w2[k*128+col];
    acc0 = fmaf(h[rg*2+0][k], w, acc0);
    acc1 = fmaf(h[rg*2+1][k], w, acc1);
  }
  {
    float bv = b2[col];
    int idx0 = (rbase+rg*2+0)*128+col;
    int idx1 = (rbase+rg*2+1)*128+col;
    float v0 = acc0+bv, v1 = acc1+bv;
    outp[idx0] = accumulate ? outp[idx0]+v0 : v0;
    outp[idx1] = accumulate ? outp[idx1]+v1 : v1;
  }
}

__global__ void k_head(const float* __restrict__ gbuf,
                       const float* __restrict__ w1, const float* __restrict__ b1,
                       const float* __restrict__ w2, const float* __restrict__ b2,
                       float* __restrict__ outp){
  __shared__ float red[128];
  int g = blockIdx.x, tid = threadIdx.x;
  float acc = 0.f;
  for (int k=0;k<640;k++) acc = fmaf(gbuf[g*640+k], w1[k*128+tid], acc);
  float h = silu_f(acc + b1[tid]);
  red[tid] = h * w2[tid];
  __syncthreads();
  for (int o=64;o>0;o>>=1){ if (tid<o) red[tid]+=red[tid+o]; __syncthreads(); }
  if (tid == 0) outp[g] = red[0] + b2[0];
}

// ---------------- elementwise / reduction kernels ----------------

__global__ void k_sadd_batch(float* __restrict__ s, const float* __restrict__ t2,
                             const int* __restrict__ batch, ushort_t* __restrict__ s16){
  int i = blockIdx.x*256 + threadIdx.x;
  if (i >= N_*H_) return;
  int n = i >> 7, h = i & 127;
  float v = s[i] + t2[batch[n]*128 + h];
  s[i] = v;
  s16[i] = f2bf(v);
}

// LN + silu (no atomics)
__global__ void k_ln_silu(const float* __restrict__ in, float* __restrict__ outp,
                          const float* __restrict__ g, const float* __restrict__ b){
  __shared__ float red[128];
  int n = blockIdx.x, tid = threadIdx.x;
  float x = in[n*128 + tid];
  red[tid] = x; __syncthreads();
  for (int o=64;o>0;o>>=1){ if (tid<o) red[tid]+=red[tid+o]; __syncthreads(); }
  float mu = red[0] * (1.f/128.f);
  __syncthreads();
  float dx = x - mu;
  red[tid] = dx*dx; __syncthreads();
  for (int o=64;o>0;o>>=1){ if (tid<o) red[tid]+=red[tid+o]; __syncthreads(); }
  float var = red[0] * (1.f/128.f);
  float y = dx * rsqrtf(var + 1e-5f) * g[tid] + b[tid];
  outp[n*128 + tid] = silu_f(y);
}

// batch CSR segment-sum of s into ssum (ssum pre-zeroed)
__global__ void k_ssum_csr(const float* __restrict__ s, const int* __restrict__ bends,
                           float* __restrict__ ssum){
  int g = blockIdx.x, c = blockIdx.y, tid = threadIdx.x;
  int s0 = g ? bends[g-1] : 0;
  int e0 = bends[g];
  long len = e0 - s0;
  int lo = s0 + (int)((len*c) >> 3);
  int hi = s0 + (int)((len*(c+1)) >> 3);
  float a = 0.f;
  for (int n=lo; n<hi; n++) a += s[(size_t)n*128 + tid];
  if (hi > lo) atomicAdd(&ssum[g*128 + tid], a);
}

// readout scatter: per-block segmented accumulation over 32 sorted nodes
__global__ void k_scatter_nf2(const float* __restrict__ s, const float* __restrict__ v /*[3][N][128]*/,
                              const int* __restrict__ batch, float* __restrict__ addp){
  int j = threadIdx.x;            // 0..255 (col in the 256-wide nf row)
  int base = blockIdx.x*32;
  float acc = 0.f;
  int prev = batch[base];
  for (int r=0;r<32;r++){
    int nn = base + r;
    int b = batch[nn];
    if (b != prev){ atomicAdd(&addp[prev*256 + j], acc); acc = 0.f; prev = b; }
    float val;
    if (j < 128){
      val = s[(size_t)nn*128 + j];
    } else {
      size_t idx = (size_t)nn*128 + (j - 128);
      float v0 = v[idx], v1 = v[(size_t)N_*128 + idx], v2 = v[(size_t)N_*256 + idx];
      val = sqrtf(v0*v0 + v1*v1 + v2*v2 + 1e-12f);
    }
    acc += val;
  }
  atomicAdd(&addp[prev*256 + j], acc);
}

// counts derived from bends (no atomics)
__global__ void k_build_g(const float* __restrict__ addp, const int* __restrict__ bends,
                          const float* __restrict__ vn, float* __restrict__ gbuf){
  int i = blockIdx.x*256 + threadIdx.x;
  if (i >= G_*640) return;
  int g = i / 640, j = i % 640;
  float cnt = (float)(bends[g] - (g ? bends[g-1] : 0));
  float val;
  if (j < 256)       val = addp[g*256 + j];
  else if (j < 512)  val = addp[g*256 + (j-256)] / fmaxf(cnt, 1.f);
  else               val = vn[g*128 + (j-512)];
  gbuf[i] = val;
}

// ---------------- host launcher ----------------

extern "C" void kernel_launch(void* const* d_in, const int* in_sizes, int n_in,
                              void* d_out, int out_size, void* d_ws, size_t ws_size,
                              hipStream_t stream)
{
  const float* x         = (const float*)d_in[0];
  const float* pos       = (const float*)d_in[1];
  const float* edist     = (const float*)d_in[2];
  const float* node_in_w = (const float*)d_in[3];
  const float* node_in_b = (const float*)d_in[4];
  const float* tm_w1 = (const float*)d_in[5];
  const float* tm_b1 = (const float*)d_in[6];
  const float* tm_w2 = (const float*)d_in[7];
  const float* tm_b2 = (const float*)d_in[8];
  const float* mm_w1 = (const float*)d_in[9];
  const float* mm_b1 = (const float*)d_in[10];
  const float* mm_w2 = (const float*)d_in[11];
  const float* mm_b2 = (const float*)d_in[12];
  const float* us_w1 = (const float*)d_in[13];
  const float* us_b1 = (const float*)d_in[14];
  const float* us_w2 = (const float*)d_in[15];
  const float* us_b2 = (const float*)d_in[16];
  const float* gv_w1 = (const float*)d_in[17];
  const float* gv_b1 = (const float*)d_in[18];
  const float* gv_w2 = (const float*)d_in[19];
  const float* gv_b2 = (const float*)d_in[20];
  const float* ln_g  = (const float*)d_in[21];
  const float* ln_b  = (const float*)d_in[22];
  const float* vn_init = (const float*)d_in[23];
  const float* v2n_w1 = (const float*)d_in[24];
  const float* v2n_b1 = (const float*)d_in[25];
  const float* v2n_w2 = (const float*)d_in[26];
  const float* v2n_b2 = (const float*)d_in[27];
  const float* n2v_w1 = (const float*)d_in[28];
  const float* n2v_b1 = (const float*)d_in[29];
  const float* n2v_w2 = (const float*)d_in[30];
  const float* n2v_b2 = (const float*)d_in[31];
  const float* head_w1 = (const float*)d_in[32];
  const float* head_b1 = (const float*)d_in[33];
  const float* head_w2 = (const float*)d_in[34];
  const float* head_b2 = (const float*)d_in[35];
  const int* ei    = (const int*)d_in[36];
  const int* t_kj  = (const int*)d_in[37];
  const int* t_ji  = (const int*)d_in[38];
  const int* batch = (const int*)d_in[39];
  float* out = (float*)d_out;

  // ---- workspace layout (~150 MiB) ----
  float* f = (float*)d_ws;
  size_t off = 0;
  auto alloc = [&](size_t n){ n = (n + 3) & ~(size_t)3; float* p = f + off; off += n; return p; };
  float*    vec    = alloc((size_t)E_*3);    // aliased: perm_t + perm_e after k_angle
  float*    dir    = alloc((size_t)E_*3);
  ushort_t* rbf16  = (ushort_t*)alloc((size_t)E_*16);
  float*    angle  = alloc((size_t)T_);
  float*    tmsg_f = alloc((size_t)E_*128);  // triplet hidden T*128 bf16 / edge hidden E*128 bf16
  float*    eagg2_f= alloc((size_t)E_*64);   // eagg bf16 (E*128); later: moments + node scratch
  float*    dir_s  = alloc((size_t)E_*3);    // sorted dir
  float*    tends_f= alloc((size_t)E_ + 1024); // triplet CSR ends (E ints) + scan sums
  float*    eends_f= alloc((size_t)N_ + 1024); // edge CSR ends (N ints) + scan sums
  float*    bends_f= alloc((size_t)G_);      // batch CSR ends (G ints)
  float*    s      = alloc((size_t)N_*128);
  ushort_t* s16    = (ushort_t*)alloc((size_t)N_*64);
  float*    v      = alloc((size_t)N_*384);  // PLANAR [3][N][128]
  float*    aggv   = alloc((size_t)N_*384);  // PLANAR [3][N][128]
  float*    rank_f = alloc((size_t)E_);      // rank_e (E ints)
  float*    wtbuf_f= alloc((size_t)376832);  // bf16 transposed weights (hi + node-lo)
  float*    vn     = alloc((size_t)G_*128);
  float*    tg2    = alloc((size_t)G_*128);
  float*    ssum   = alloc((size_t)G_*128);
  float*    addp   = alloc((size_t)G_*256);
  float*    gbuf   = alloc((size_t)G_*640);

  if (off * sizeof(float) > ws_size){
    k_sentinel<<<1, 64, 0, stream>>>(out, G_);
    return;
  }

  // aliases
  int* perm_t = (int*)vec;
  int* perm_e = perm_t + T_;
  int* rank_e = (int*)rank_f;
  int* tends  = (int*)tends_f;
  int* eends  = (int*)eends_f;
  int* bends  = (int*)bends_f;
  ushort_t* tmsg   = (ushort_t*)tmsg_f;   // T*128 bf16 (triplet hidden)
  ushort_t* ehid   = (ushort_t*)tmsg_f;   // E*128 bf16 (edge hidden; tmsg dead by then)
  ushort_t* eagg2  = (ushort_t*)eagg2_f;  // E*128 bf16
  // edge moments + node scratch inside eagg2_f (eagg2 dead after edge MLP reads it)
  float*    mom  = eagg2_f;                              // [4][N][128] fp32 + sumdir [N][4]
  ushort_t* a16h = (ushort_t*)(eagg2_f + 4227072);       // 4*N*128 + 4*N region
  ushort_t* a16l = a16h + (size_t)N_*128;
  ushort_t* vnh  = a16l + (size_t)N_*128;
  ushort_t* vnl  = vnh  + (size_t)N_*128;
  float*    s2   = (float*)(vnl + (size_t)N_*128);       // N*128 fp32

  ushort_t* wtbuf = (ushort_t*)wtbuf_f;
  auto WT = [&](int l, size_t o){ return wtbuf + (size_t)l*376832 + o; };

  auto zero = [&](float* p, long n){
    int blocks = (int)((n/4 + 255)/256); if (blocks > 16384) blocks = 16384; if (blocks < 1) blocks = 1;
    k_zero<<<blocks, 256, 0, stream>>>(p, n);
  };
  auto csort = [&](const int* keys, const int* map, int M, int B, int* perm, int* ends){
    int nb = (B+1023)/1024;
    zero((float*)ends, B + nb);
    if (map) k_hist2<<<(M+255)/256, 256, 0, stream>>>(keys, map, M, ends);
    else     k_hist <<<(M+255)/256, 256, 0, stream>>>(keys, M, ends);
    k_scan1<<<nb, 256, 0, stream>>>(ends, ends, ends + B, B);
    k_scan2<<<1, 64, 0, stream>>>(ends + B, nb);
    k_scan3<<<(B+255)/256, 256, 0, stream>>>(ends, ends + B, B);
    if (map) k_fill2<<<(M+255)/256, 256, 0, stream>>>(keys, map, M, ends, perm);
    else     k_fill <<<(M+255)/256, 256, 0, stream>>>(keys, M, ends, perm);
    // post-fill: ends[b] == segment end offset for bin b
  };

  // ---- prologue ----
  zero(v, (long)N_*384);
  k_init_vn<<<(G_*H_ + 255)/256, 256, 0, stream>>>(vn, vn_init);
  k_geom<<<(E_ + 255)/256, 256, 0, stream>>>(pos, edist, ei, vec, dir, rbf16);
  k_angle<<<(T_ + 255)/256, 256, 0, stream>>>(vec, t_kj, t_ji, angle);
  csort(ei+E_, nullptr, E_, N_, perm_e, eends);
  k_invert<<<(E_+255)/256, 256, 0, stream>>>(perm_e, rank_e, E_);
  k_dirs<<<(E_+255)/256, 256, 0, stream>>>(dir, perm_e, dir_s);
  csort(t_ji, rank_e, T_, E_, perm_t, tends);
  // batch CSR ends: binary search over sorted batch (no atomics)
  k_bends<<<1, 64, 0, stream>>>(batch, bends);
  k_wt_all<<<dim3(960, 2), 256, 0, stream>>>(tm_w1, tm_w2, mm_w1, mm_w2,
                                             us_w1, us_w2, gv_w1, gv_w2, wtbuf);
  k_gemm<<<512, 128, 0, stream>>>(x, node_in_w, node_in_b, s, N_, IND_);

  for (int l=0; l<L_; l++){
    // 1) s += v2n_mlp(vn)[batch]  (snapshots s16)
    k_small_mlp2<<<8, 256, 0, stream>>>(vn, v2n_w1, v2n_b1, v2n_w2, v2n_b2, tg2, 0);
    k_sadd_batch<<<(N_*H_ + 255)/256, 256, 0, stream>>>(s, tg2, batch, s16);

    // 2) triplet: hidden MLP (4-wave, 16 rows/wave, gather-first) -> tmsg; fused CSR+W2 -> eagg2
    k_mlp1<1,96><<<T_/64, 256, 0, stream>>>(perm_t, t_kj, t_ji,
        rbf16, angle, s16, eagg2, WT(l,0), tm_b1 + l*128, tmsg);
    k_aggemm_t<<<E_/MROWS, 64, 0, stream>>>(tmsg, tends, WT(l,12288), tm_b2 + l*128, eagg2);

    // 3) edge: hidden MLP (4-wave, 16 rows/wave, gather-first) -> ehid; moment reduce; W2 GEMMs
    k_mlp1<2,416><<<E_/64, 256, 0, stream>>>(perm_e, ei, ei + E_,
        rbf16, angle, s16, eagg2, WT(l,28672), mm_b1 + l*128, ehid);
    k_agg_e<<<(N_*64)/256, 256, 0, stream>>>(ehid, eends, dir_s, mom);
    k_gemm_e<<<dim3(N_/MROWS, 4), 64, 0, stream>>>(mom, eends, WT(l,81920), mm_b2 + l*256,
        v, a16h, a16l, vnh, vnl, aggv);

    // 5+6) node update (4-wave blocks, LDS-shared weights): s2 = s + us_mlp; gated v update
    k_node_mfma<<<dim3(N_/64, 2), 256, 0, stream>>>(s, a16h, a16l, vnh, vnl, s2, v, aggv,
        WT(l,114688), WT(l,163840), us_b1 + l*128, WT(l,212992), WT(l,229376), us_b2 + l*128,
        WT(l,245760), WT(l,294912), gv_b1 + l*128, WT(l,344064), WT(l,360448), gv_b2 + l*128);

    // 7) s = silu(LN(s2)); 8) vn += n2v_mlp(batch-CSR segment sum of s)
    k_ln_silu<<<N_, 128, 0, stream>>>(s2, s, ln_g + l*128, ln_b + l*128);
    zero(ssum, (long)G_*128);
    k_ssum_csr<<<dim3(G_, 8), 128, 0, stream>>>(s, bends, ssum);
    k_small_mlp2<<<8, 256, 0, stream>>>(ssum, n2v_w1, n2v_b1, n2v_w2, n2v_b2, vn, 1);
  }

  // ---- readout ----
  zero(addp, (long)G_*256);
  k_scatter_nf2<<<N_/32, 256, 0, stream>>>(s, v, batch, addp);
  k_build_g<<<(G_*640 + 255)/256, 256, 0, stream>>>(addp, bends, vn, gbuf);
  k_head<<<G_, 128, 0, stream>>>(gbuf, head_w1, head_b1, head_w2, head_b2, out);
}